// Round 2
// baseline (1392.190 us; speedup 1.0000x reference)
//
#include <hip/hip_runtime.h>
#include <hip/hip_bf16.h>

typedef unsigned short u16;
typedef short short8 __attribute__((ext_vector_type(8)));
typedef float f32x4 __attribute__((ext_vector_type(4)));

#define T_TOK 25088   // 128*196
#define NTOK 196

__device__ __forceinline__ u16 bfbits(float v) {
  __hip_bfloat16 h = __float2bfloat16(v);
  return *reinterpret_cast<u16*>(&h);
}
__device__ __forceinline__ float b2f(u16 u) {
  __hip_bfloat16 h = *reinterpret_cast<__hip_bfloat16*>(&u);
  return __bfloat162float(h);
}
// near-fp32 as hi+lo bf16 pair (Ootomo split)
__device__ __forceinline__ void fsplit(float v, u16& hi, u16& lo) {
  hi = bfbits(v);
  lo = bfbits(v - b2f(hi));
}

// ---------------------------------------------------------------------------
// Split-bf16 MFMA GEMM: C[M,N] = (Ah+Al)[M,K] @ (Bh+Bl)[N,K]^T + bias
// 128x128 tile, BK=32, 256 threads (4 waves 2x2), 3 MFMA per fragment pair.
// EPI: 0 ->f32 | 1 +pos->f32 | 2 +resid->f32+split | 3 gelu->split | 4 gate-acc->f32
// ---------------------------------------------------------------------------
template<int EPI>
__global__ __launch_bounds__(256) void gemm_split(
    const u16* __restrict__ Ah, const u16* __restrict__ Al,
    const u16* __restrict__ Bh, const u16* __restrict__ Bl,
    int M, int N, int K,
    const float* __restrict__ bias, const float* __restrict__ extra,
    float* __restrict__ outf, u16* __restrict__ obh, u16* __restrict__ obl)
{
  __shared__ u16 Ash[128][40], Asl[128][40], Bsh[128][40], Bsl[128][40];
  const int tid = threadIdx.x;
  const int lane = tid & 63, wave = tid >> 6;
  const int wm = wave >> 1, wn = wave & 1;
  const int row0 = blockIdx.x * 128, col0 = blockIdx.y * 128;

  f32x4 acc[4][4];
  const f32x4 zero = {0.f, 0.f, 0.f, 0.f};
#pragma unroll
  for (int i = 0; i < 4; ++i)
#pragma unroll
    for (int j = 0; j < 4; ++j) acc[i][j] = zero;

  const int rsel = lane & 15, ksel = (lane >> 4) * 8;

  for (int k0 = 0; k0 < K; k0 += 32) {
    __syncthreads();
#pragma unroll
    for (int c = 0; c < 2; ++c) {
      int chunk = tid + c * 256;            // 512 chunks of 8 bf16 (16B)
      int r = chunk >> 2, co = (chunk & 3) * 8;
      size_t ga = (size_t)(row0 + r) * K + k0 + co;
      size_t gb = (size_t)(col0 + r) * K + k0 + co;
      *(short8*)&Ash[r][co] = *(const short8*)(Ah + ga);
      *(short8*)&Asl[r][co] = *(const short8*)(Al + ga);
      *(short8*)&Bsh[r][co] = *(const short8*)(Bh + gb);
      *(short8*)&Bsl[r][co] = *(const short8*)(Bl + gb);
    }
    __syncthreads();
    short8 ah[4], al[4], bh[4], bl[4];
#pragma unroll
    for (int i = 0; i < 4; ++i) {
      ah[i] = *(const short8*)&Ash[wm * 64 + i * 16 + rsel][ksel];
      al[i] = *(const short8*)&Asl[wm * 64 + i * 16 + rsel][ksel];
    }
#pragma unroll
    for (int j = 0; j < 4; ++j) {
      bh[j] = *(const short8*)&Bsh[wn * 64 + j * 16 + rsel][ksel];
      bl[j] = *(const short8*)&Bsl[wn * 64 + j * 16 + rsel][ksel];
    }
#pragma unroll
    for (int i = 0; i < 4; ++i)
#pragma unroll
      for (int j = 0; j < 4; ++j) {
        acc[i][j] = __builtin_amdgcn_mfma_f32_16x16x32_bf16(ah[i], bh[j], acc[i][j], 0, 0, 0);
        acc[i][j] = __builtin_amdgcn_mfma_f32_16x16x32_bf16(al[i], bh[j], acc[i][j], 0, 0, 0);
        acc[i][j] = __builtin_amdgcn_mfma_f32_16x16x32_bf16(ah[i], bl[j], acc[i][j], 0, 0, 0);
      }
  }

#pragma unroll
  for (int i = 0; i < 4; ++i) {
#pragma unroll
    for (int j = 0; j < 4; ++j) {
#pragma unroll
      for (int r = 0; r < 4; ++r) {
        int grow = row0 + wm * 64 + i * 16 + (lane >> 4) * 4 + r;   // token
        int gcol = col0 + wn * 64 + j * 16 + (lane & 15);           // feature
        float v = acc[i][j][r] + bias[gcol];
        size_t oi = (size_t)grow * N + gcol;
        if constexpr (EPI == 1) {
          v += extra[(size_t)(grow % NTOK) * N + gcol];   // pos_embed
          outf[oi] = v;
        } else if constexpr (EPI == 2) {
          v += extra[oi];                                  // residual
          outf[oi] = v;
          u16 h, l; fsplit(v, h, l); obh[oi] = h; obl[oi] = l;
        } else if constexpr (EPI == 3) {
          float g = 0.5f * v * (1.f + erff(v * 0.70710678118654752f));
          u16 h, l; fsplit(g, h, l); obh[oi] = h; obl[oi] = l;
        } else if constexpr (EPI == 4) {
          outf[oi] += extra[(size_t)grow * 6] * v;         // extra = gates + e
        } else {
          outf[oi] = v;
        }
      }
    }
  }
}

// ---------------------------------------------------------------------------
// im2col + split: x[B,3,224,224] f32 -> A_patch hi/lo [T,768]
// ---------------------------------------------------------------------------
__global__ void im2col_split(const float* __restrict__ x,
                             u16* __restrict__ Aph, u16* __restrict__ Apl) {
  int id = blockIdx.x * 256 + threadIdx.x;          // T*192 items of 4 elems
  if (id >= T_TOK * 192) return;
  int t = id / 192, kk = id - t * 192;
  int k4 = kk * 4;
  int c = k4 >> 8, rem = k4 & 255, p = rem >> 4, q = rem & 15;
  int b = t / 196, n = t - b * 196, gh = n / 14, gw = n - gh * 14;
  const float4 v = *(const float4*)(x + ((size_t)(b * 3 + c) * 224 + gh * 16 + p) * 224 + gw * 16 + q);
  u16 h0, l0, h1, l1, h2, l2, h3, l3;
  fsplit(v.x, h0, l0); fsplit(v.y, h1, l1); fsplit(v.z, h2, l2); fsplit(v.w, h3, l3);
  *(ushort4*)(Aph + (size_t)t * 768 + k4) = make_ushort4(h0, h1, h2, h3);
  *(ushort4*)(Apl + (size_t)t * 768 + k4) = make_ushort4(l0, l1, l2, l3);
}

// ---------------------------------------------------------------------------
// LayerNorm over E=256: wave per token; SPLIT_OUT -> hi/lo bf16, else f32
// ---------------------------------------------------------------------------
template<bool SPLIT_OUT>
__global__ __launch_bounds__(256) void ln_kernel(const float* __restrict__ in,
    const float* __restrict__ g, const float* __restrict__ b,
    u16* __restrict__ oh, u16* __restrict__ ol, float* __restrict__ outf)
{
  const int lane = threadIdx.x & 63;
  const int t = blockIdx.x * 4 + (threadIdx.x >> 6);
  const float4 v = *(const float4*)(in + (size_t)t * 256 + lane * 4);
  float s = v.x + v.y + v.z + v.w;
  float sq = v.x * v.x + v.y * v.y + v.z * v.z + v.w * v.w;
#pragma unroll
  for (int o = 32; o >= 1; o >>= 1) {
    s  += __shfl_xor(s,  o, 64);
    sq += __shfl_xor(sq, o, 64);
  }
  float mu = s * (1.f / 256.f);
  float var = sq * (1.f / 256.f) - mu * mu;
  float rstd = rsqrtf(var + 1e-5f);
  const float4 gv = *(const float4*)(g + lane * 4);
  const float4 bv = *(const float4*)(b + lane * 4);
  float o0 = (v.x - mu) * rstd * gv.x + bv.x;
  float o1 = (v.y - mu) * rstd * gv.y + bv.y;
  float o2 = (v.z - mu) * rstd * gv.z + bv.z;
  float o3 = (v.w - mu) * rstd * gv.w + bv.w;
  if constexpr (SPLIT_OUT) {
    u16 h0, l0, h1, l1, h2, l2, h3, l3;
    fsplit(o0, h0, l0); fsplit(o1, h1, l1); fsplit(o2, h2, l2); fsplit(o3, h3, l3);
    *(ushort4*)(oh + (size_t)t * 256 + lane * 4) = make_ushort4(h0, h1, h2, h3);
    *(ushort4*)(ol + (size_t)t * 256 + lane * 4) = make_ushort4(l0, l1, l2, l3);
  } else {
    *(float4*)(outf + (size_t)t * 256 + lane * 4) = make_float4(o0, o1, o2, o3);
  }
}

// ---------------------------------------------------------------------------
// Attention: block per (b,h); K,V in LDS; thread = one q row, online softmax.
// Reads f32 qkv, writes ao hi/lo.
// ---------------------------------------------------------------------------
__global__ __launch_bounds__(256) void attn_kernel(const float* __restrict__ qkv,
                                                   u16* __restrict__ aoh, u16* __restrict__ aol) {
  const int bh = blockIdx.x;
  const int b = bh >> 3, h = bh & 7;
  __shared__ float Ks[196][32];
  __shared__ float Vs[196][32];
  const int tid = threadIdx.x;
  const size_t base = (size_t)b * 196 * 768;
  for (int idx = tid; idx < 196 * 8; idx += 256) {
    int r = idx >> 3, c = (idx & 7) * 4;
    *(float4*)&Ks[r][c] = *(const float4*)(qkv + base + (size_t)r * 768 + 256 + h * 32 + c);
    *(float4*)&Vs[r][c] = *(const float4*)(qkv + base + (size_t)r * 768 + 512 + h * 32 + c);
  }
  __syncthreads();
  if (tid >= 196) return;
  float q[32];
#pragma unroll
  for (int c = 0; c < 8; ++c) {
    float4 t4 = *(const float4*)(qkv + base + (size_t)tid * 768 + h * 32 + c * 4);
    q[c * 4 + 0] = t4.x; q[c * 4 + 1] = t4.y; q[c * 4 + 2] = t4.z; q[c * 4 + 3] = t4.w;
  }
  float m = -1e30f, l = 0.f;
  float acc[32];
#pragma unroll
  for (int d = 0; d < 32; ++d) acc[d] = 0.f;
  for (int j = 0; j < 196; ++j) {
    float s = 0.f;
#pragma unroll
    for (int d = 0; d < 32; ++d) s += q[d] * Ks[j][d];
    s *= 0.17677669529663687f;       // 1/sqrt(32)
    if (s > m) {
      float corr = __expf(m - s);
      l *= corr;
#pragma unroll
      for (int d = 0; d < 32; ++d) acc[d] *= corr;
      m = s;
    }
    float p = __expf(s - m);
    l += p;
#pragma unroll
    for (int d = 0; d < 32; ++d) acc[d] += p * Vs[j][d];
  }
  float inv = 1.f / l;
  size_t ob = ((size_t)b * 196 + tid) * 256 + h * 32;
#pragma unroll
  for (int c = 0; c < 8; ++c) {
    u16 h0, l0, h1, l1, h2, l2, h3, l3;
    fsplit(acc[c * 4 + 0] * inv, h0, l0); fsplit(acc[c * 4 + 1] * inv, h1, l1);
    fsplit(acc[c * 4 + 2] * inv, h2, l2); fsplit(acc[c * 4 + 3] * inv, h3, l3);
    *(ushort4*)(aoh + ob + c * 4) = make_ushort4(h0, h1, h2, h3);
    *(ushort4*)(aol + ob + c * 4) = make_ushort4(l0, l1, l2, l3);
  }
}

// ---------------------------------------------------------------------------
// Router: wave per token; 6 logits, softmax, top-2 -> dense gates [T,6]
// ---------------------------------------------------------------------------
__global__ __launch_bounds__(256) void router_kernel(const float* __restrict__ x1,
    const float* __restrict__ rw, const float* __restrict__ rb, float* __restrict__ gates)
{
  const int lane = threadIdx.x & 63;
  const int t = blockIdx.x * 4 + (threadIdx.x >> 6);
  const float4 xv = *(const float4*)(x1 + (size_t)t * 256 + lane * 4);
  float logit[6];
#pragma unroll
  for (int e = 0; e < 6; ++e) {
    const float4 wv = *(const float4*)(rw + e * 256 + lane * 4);
    float p = xv.x * wv.x + xv.y * wv.y + xv.z * wv.z + xv.w * wv.w;
#pragma unroll
    for (int o = 32; o >= 1; o >>= 1) p += __shfl_xor(p, o, 64);
    logit[e] = p + rb[e];
  }
  float mx = logit[0];
#pragma unroll
  for (int e = 1; e < 6; ++e) mx = fmaxf(mx, logit[e]);
  float pe[6], sum = 0.f;
#pragma unroll
  for (int e = 0; e < 6; ++e) { pe[e] = __expf(logit[e] - mx); sum += pe[e]; }
  float inv = 1.f / sum;
  int i1 = 0; float p1 = pe[0];
#pragma unroll
  for (int e = 1; e < 6; ++e) if (pe[e] > p1) { p1 = pe[e]; i1 = e; }
  int i2 = -1; float p2 = -1.f;
#pragma unroll
  for (int e = 0; e < 6; ++e) if (e != i1 && pe[e] > p2) { p2 = pe[e]; i2 = e; }
  if (lane < 6)
    gates[(size_t)t * 6 + lane] = (lane == i1) ? p1 * inv : ((lane == i2) ? p2 * inv : 0.f);
}

// ---------------------------------------------------------------------------
// Mean-pool over tokens, then classifier head (fp32)
// ---------------------------------------------------------------------------
__global__ __launch_bounds__(256) void pool_kernel(const float* __restrict__ x2, float* __restrict__ pooled) {
  int b = blockIdx.x, e = threadIdx.x;
  float s = 0.f;
  for (int n = 0; n < 196; ++n) s += x2[((size_t)b * 196 + n) * 256 + e];
  pooled[(size_t)b * 256 + e] = s * (1.f / 196.f);
}

__global__ __launch_bounds__(256) void head_kernel(const float* __restrict__ pooled,
    const float* __restrict__ hw, const float* __restrict__ hb, float* __restrict__ out) {
  __shared__ float p[256];
  int b = blockIdx.x;
  p[threadIdx.x] = pooled[(size_t)b * 256 + threadIdx.x];
  __syncthreads();
  for (int cls = threadIdx.x; cls < 1000; cls += 256) {
    const float* w = hw + (size_t)cls * 256;
    float s = hb[cls];
    for (int k = 0; k < 256; k += 4)
      s += p[k] * w[k] + p[k + 1] * w[k + 1] + p[k + 2] * w[k + 2] + p[k + 3] * w[k + 3];
    out[(size_t)b * 1000 + cls] = s;
  }
}

// ---------------------------------------------------------------------------
// Weight prep: f32 -> hi/lo bf16; batched transpose+split ([R,C] -> [C,R])
// ---------------------------------------------------------------------------
__global__ void cast_split_kernel(const float* __restrict__ in,
                                  u16* __restrict__ oh, u16* __restrict__ ol, int n4) {
  int id = blockIdx.x * 256 + threadIdx.x;
  if (id >= n4) return;
  float4 v = ((const float4*)in)[id];
  u16 h0, l0, h1, l1, h2, l2, h3, l3;
  fsplit(v.x, h0, l0); fsplit(v.y, h1, l1); fsplit(v.z, h2, l2); fsplit(v.w, h3, l3);
  ((ushort4*)oh)[id] = make_ushort4(h0, h1, h2, h3);
  ((ushort4*)ol)[id] = make_ushort4(l0, l1, l2, l3);
}

__global__ __launch_bounds__(256) void transpose_split(const float* __restrict__ in,
    u16* __restrict__ oh, u16* __restrict__ ol, int R, int C) {
  __shared__ float tile[32][33];
  const int e = blockIdx.z;
  const int bc = blockIdx.x * 32, br = blockIdx.y * 32;
  const int tx = threadIdx.x & 31, ty = threadIdx.x >> 5;
  const float* src = in + (size_t)e * R * C;
#pragma unroll
  for (int i = 0; i < 32; i += 8)
    tile[ty + i][tx] = src[(size_t)(br + ty + i) * C + bc + tx];
  __syncthreads();
#pragma unroll
  for (int i = 0; i < 32; i += 8) {
    float v = tile[tx][ty + i];
    u16 h, l; fsplit(v, h, l);
    size_t di = (size_t)e * R * C + (size_t)(bc + ty + i) * R + br + tx;
    oh[di] = h; ol[di] = l;
  }
}

// ---------------------------------------------------------------------------
extern "C" void kernel_launch(void* const* d_in, const int* in_sizes, int n_in,
                              void* d_out, int out_size, void* d_ws, size_t ws_size,
                              hipStream_t stream) {
  (void)in_sizes; (void)n_in; (void)out_size; (void)ws_size;
  const float* x      = (const float*)d_in[0];
  const float* conv_w = (const float*)d_in[1];
  const float* conv_b = (const float*)d_in[2];
  const float* pos    = (const float*)d_in[3];
  const float* ln1_g  = (const float*)d_in[4];
  const float* ln1_b  = (const float*)d_in[5];
  const float* wqkv   = (const float*)d_in[6];
  const float* bqkv   = (const float*)d_in[7];
  const float* wo     = (const float*)d_in[8];
  const float* bo     = (const float*)d_in[9];
  const float* rw     = (const float*)d_in[10];
  const float* rb     = (const float*)d_in[11];
  const float* w1     = (const float*)d_in[12];
  const float* b1     = (const float*)d_in[13];
  const float* w2     = (const float*)d_in[14];
  const float* b2     = (const float*)d_in[15];
  const float* ln2_g  = (const float*)d_in[16];
  const float* ln2_b  = (const float*)d_in[17];
  const float* hw     = (const float*)d_in[18];
  const float* hb     = (const float*)d_in[19];
  float* out = (float*)d_out;

  const int T = T_TOK, E = 256, HID = 1024;
  char* ws = (char*)d_ws;
  size_t off = 0;
  auto alloc = [&](size_t bytes) -> void* {
    void* p = ws + off;
    off += (bytes + 255) & ~(size_t)255;
    return p;
  };
  u16*   Aph    = (u16*)  alloc((size_t)T * 768 * 2);   // --- region reused by hbuf ---
  u16*   Apl    = (u16*)  alloc((size_t)T * 768 * 2);
  float* tok    = (float*)alloc((size_t)T * 256 * 4);   // --- end hbuf region (exact fit) ---
  u16*   xnh    = (u16*)  alloc((size_t)T * 256 * 2);
  u16*   xnl    = (u16*)  alloc((size_t)T * 256 * 2);
  float* qkv    = (float*)alloc((size_t)T * 768 * 4);   // reused by x2
  u16*   aoh    = (u16*)  alloc((size_t)T * 256 * 2);
  u16*   aol    = (u16*)  alloc((size_t)T * 256 * 2);
  float* x1f    = (float*)alloc((size_t)T * 256 * 4);   // reused by moe accum
  u16*   x1h    = (u16*)  alloc((size_t)T * 256 * 2);
  u16*   x1l    = (u16*)  alloc((size_t)T * 256 * 2);
  float* gates  = (float*)alloc((size_t)T * 6 * 4);
  float* pooled = (float*)alloc((size_t)128 * 256 * 4);
  u16*   cwh    = (u16*)  alloc((size_t)196608 * 2);
  u16*   cwl    = (u16*)  alloc((size_t)196608 * 2);
  u16*   wqh    = (u16*)  alloc((size_t)196608 * 2);
  u16*   wql    = (u16*)  alloc((size_t)196608 * 2);
  u16*   woh    = (u16*)  alloc((size_t)65536 * 2);
  u16*   wol    = (u16*)  alloc((size_t)65536 * 2);
  u16*   w1th   = (u16*)  alloc((size_t)6 * 262144 * 2);
  u16*   w1tl   = (u16*)  alloc((size_t)6 * 262144 * 2);
  u16*   w2th   = (u16*)  alloc((size_t)6 * 262144 * 2);
  u16*   w2tl   = (u16*)  alloc((size_t)6 * 262144 * 2);
  // aliases (lifetimes disjoint):
  u16*   hbh = (u16*)ws;                          // [T,1024] hi — over Aph/Apl/tok
  u16*   hbl = hbh + (size_t)T * 1024;            // [T,1024] lo (exactly fills region)
  float* x2  = (float*)qkv;                       // [T,256] f32
  float* moe = x1f;                               // [T,256] f32 accumulator

  // --- weight prep ---
  cast_split_kernel<<<192, 256, 0, stream>>>(conv_w, cwh, cwl, 49152);
  cast_split_kernel<<<192, 256, 0, stream>>>(wqkv, wqh, wql, 49152);
  cast_split_kernel<<<64, 256, 0, stream>>>(wo, woh, wol, 16384);
  transpose_split<<<dim3(32, 8, 6), 256, 0, stream>>>(w1, w1th, w1tl, 256, 1024);  // [e][n][k]
  transpose_split<<<dim3(8, 32, 6), 256, 0, stream>>>(w2, w2th, w2tl, 1024, 256);  // [e][n][k]

  // --- patch embedding ---
  im2col_split<<<18816, 256, 0, stream>>>(x, Aph, Apl);
  gemm_split<1><<<dim3(196, 2), 256, 0, stream>>>(Aph, Apl, cwh, cwl, T, 256, 768,
                                                  conv_b, pos, tok, nullptr, nullptr);

  // --- attention block ---
  ln_kernel<true><<<6272, 256, 0, stream>>>(tok, ln1_g, ln1_b, xnh, xnl, nullptr);
  gemm_split<0><<<dim3(196, 6), 256, 0, stream>>>(xnh, xnl, wqh, wql, T, 768, 256,
                                                  bqkv, nullptr, qkv, nullptr, nullptr);
  attn_kernel<<<1024, 256, 0, stream>>>(qkv, aoh, aol);
  gemm_split<2><<<dim3(196, 2), 256, 0, stream>>>(aoh, aol, woh, wol, T, 256, 256,
                                                  bo, tok, x1f, x1h, x1l);

  // --- MoE (dense over experts, gate-weighted accumulate) ---
  router_kernel<<<6272, 256, 0, stream>>>(x1f, rw, rb, gates);
  hipMemsetAsync(moe, 0, (size_t)T * 256 * 4, stream);   // x1f dead after router
  for (int e = 0; e < 6; ++e) {
    gemm_split<3><<<dim3(196, 8), 256, 0, stream>>>(x1h, x1l,
        w1th + (size_t)e * HID * E, w1tl + (size_t)e * HID * E, T, 1024, 256,
        b1 + e * 1024, nullptr, nullptr, hbh, hbl);
    gemm_split<4><<<dim3(196, 2), 256, 0, stream>>>(hbh, hbl,
        w2th + (size_t)e * E * HID, w2tl + (size_t)e * E * HID, T, 256, 1024,
        b2 + e * 256, gates + e, moe, nullptr, nullptr);
  }

  // --- final norm, pool, head ---
  ln_kernel<false><<<6272, 256, 0, stream>>>(moe, ln2_g, ln2_b, nullptr, nullptr, x2);
  pool_kernel<<<128, 256, 0, stream>>>(x2, pooled);
  head_kernel<<<128, 256, 0, stream>>>(pooled, hw, hb, out);
}

// Round 3
// 1033.016 us; speedup vs baseline: 1.3477x; 1.3477x over previous
//
#include <hip/hip_runtime.h>
#include <hip/hip_bf16.h>

typedef unsigned short u16;
typedef short short8 __attribute__((ext_vector_type(8)));
typedef float f32x4 __attribute__((ext_vector_type(4)));

#define T_TOK 25088   // 128*196
#define NTOK 196

__device__ __forceinline__ u16 bfbits(float v) {
  __hip_bfloat16 h = __float2bfloat16(v);
  return *reinterpret_cast<u16*>(&h);
}
__device__ __forceinline__ float b2f(u16 u) {
  __hip_bfloat16 h = *reinterpret_cast<__hip_bfloat16*>(&u);
  return __bfloat162float(h);
}
// near-fp32 as hi+lo bf16 pair (Ootomo split)
__device__ __forceinline__ void fsplit(float v, u16& hi, u16& lo) {
  hi = bfbits(v);
  lo = bfbits(v - b2f(hi));
}

// ---------------------------------------------------------------------------
// Split-bf16 MFMA GEMM: C[M,N] = (Ah+Al)[M,K] @ (Bh+Bl)[N,K]^T + bias
// 128x128 tile, BK=32, 256 threads (4 waves 2x2), 3 MFMA per fragment pair.
// EPI: 1 +pos->f32 | 2 +resid->f32+split | 3 gelu->split | 4 gate-scatter-acc | 5 ->bf16 hi
// MODE: 0 dense | 1 gather-A rows via gidx, M=*cntp | 2 M=*cntp, scatter epilogue
// ---------------------------------------------------------------------------
template<int EPI, int MODE>
__global__ __launch_bounds__(256) void gemm_split(
    const u16* __restrict__ Ah, const u16* __restrict__ Al,
    const u16* __restrict__ Bh, const u16* __restrict__ Bl,
    int M, int N, int K,
    const float* __restrict__ bias, const float* __restrict__ extra,
    float* __restrict__ outf, u16* __restrict__ obh, u16* __restrict__ obl,
    const int* __restrict__ gidx, const int* __restrict__ cntp)
{
  int Meff = M;
  if constexpr (MODE != 0) {
    Meff = *cntp;
    if ((int)blockIdx.x * 128 >= Meff) return;
  }
  __shared__ u16 Ash[128][40], Asl[128][40], Bsh[128][40], Bsl[128][40];
  const int tid = threadIdx.x;
  const int lane = tid & 63, wave = tid >> 6;
  const int wm = wave >> 1, wn = wave & 1;
  const int row0 = blockIdx.x * 128, col0 = blockIdx.y * 128;

  // staging row assignment (fixed across k-loop)
  const int r0 = tid >> 2, r1 = r0 + 64, co = (tid & 3) * 8;
  int ar0, ar1;
  if constexpr (MODE == 1) {
    ar0 = (row0 + r0 < Meff) ? gidx[row0 + r0] : 0;
    ar1 = (row0 + r1 < Meff) ? gidx[row0 + r1] : 0;
  } else {
    ar0 = row0 + r0; ar1 = row0 + r1;
  }

  f32x4 acc[4][4];
  const f32x4 zero = {0.f, 0.f, 0.f, 0.f};
#pragma unroll
  for (int i = 0; i < 4; ++i)
#pragma unroll
    for (int j = 0; j < 4; ++j) acc[i][j] = zero;

  const int rsel = lane & 15, ksel = (lane >> 4) * 8;

  for (int k0 = 0; k0 < K; k0 += 32) {
    __syncthreads();
    *(short8*)&Ash[r0][co] = *(const short8*)(Ah + (size_t)ar0 * K + k0 + co);
    *(short8*)&Asl[r0][co] = *(const short8*)(Al + (size_t)ar0 * K + k0 + co);
    *(short8*)&Ash[r1][co] = *(const short8*)(Ah + (size_t)ar1 * K + k0 + co);
    *(short8*)&Asl[r1][co] = *(const short8*)(Al + (size_t)ar1 * K + k0 + co);
    *(short8*)&Bsh[r0][co] = *(const short8*)(Bh + (size_t)(col0 + r0) * K + k0 + co);
    *(short8*)&Bsl[r0][co] = *(const short8*)(Bl + (size_t)(col0 + r0) * K + k0 + co);
    *(short8*)&Bsh[r1][co] = *(const short8*)(Bh + (size_t)(col0 + r1) * K + k0 + co);
    *(short8*)&Bsl[r1][co] = *(const short8*)(Bl + (size_t)(col0 + r1) * K + k0 + co);
    __syncthreads();
    short8 ah[4], al[4], bh[4], bl[4];
#pragma unroll
    for (int i = 0; i < 4; ++i) {
      ah[i] = *(const short8*)&Ash[wm * 64 + i * 16 + rsel][ksel];
      al[i] = *(const short8*)&Asl[wm * 64 + i * 16 + rsel][ksel];
    }
#pragma unroll
    for (int j = 0; j < 4; ++j) {
      bh[j] = *(const short8*)&Bsh[wn * 64 + j * 16 + rsel][ksel];
      bl[j] = *(const short8*)&Bsl[wn * 64 + j * 16 + rsel][ksel];
    }
#pragma unroll
    for (int i = 0; i < 4; ++i)
#pragma unroll
      for (int j = 0; j < 4; ++j) {
        acc[i][j] = __builtin_amdgcn_mfma_f32_16x16x32_bf16(ah[i], bh[j], acc[i][j], 0, 0, 0);
        acc[i][j] = __builtin_amdgcn_mfma_f32_16x16x32_bf16(al[i], bh[j], acc[i][j], 0, 0, 0);
        acc[i][j] = __builtin_amdgcn_mfma_f32_16x16x32_bf16(ah[i], bl[j], acc[i][j], 0, 0, 0);
      }
  }

#pragma unroll
  for (int i = 0; i < 4; ++i) {
#pragma unroll
    for (int j = 0; j < 4; ++j) {
#pragma unroll
      for (int r = 0; r < 4; ++r) {
        int grow = row0 + wm * 64 + i * 16 + (lane >> 4) * 4 + r;   // token / row
        int gcol = col0 + wn * 64 + j * 16 + (lane & 15);           // feature
        float v = acc[i][j][r] + bias[gcol];
        size_t oi = (size_t)grow * N + gcol;
        if constexpr (EPI == 1) {
          v += extra[(size_t)(grow % NTOK) * N + gcol];   // pos_embed
          outf[oi] = v;
        } else if constexpr (EPI == 2) {
          v += extra[oi];                                  // residual
          outf[oi] = v;
          u16 h, l; fsplit(v, h, l); obh[oi] = h; obl[oi] = l;
        } else if constexpr (EPI == 3) {
          float g = 0.5f * v * (1.f + erff(v * 0.70710678118654752f));
          u16 h, l; fsplit(g, h, l); obh[oi] = h; obl[oi] = l;
        } else if constexpr (EPI == 4) {
          if (grow < Meff) {
            int tok = gidx[grow];
            atomicAdd(&outf[(size_t)tok * N + gcol], extra[(size_t)tok * 6] * v);
          }
        } else if constexpr (EPI == 5) {
          obh[oi] = bfbits(v);
        }
      }
    }
  }
}

// ---------------------------------------------------------------------------
// im2col + split: x[B,3,224,224] f32 -> A_patch hi/lo [T,768]
// ---------------------------------------------------------------------------
__global__ void im2col_split(const float* __restrict__ x,
                             u16* __restrict__ Aph, u16* __restrict__ Apl) {
  int id = blockIdx.x * 256 + threadIdx.x;          // T*192 items of 4 elems
  if (id >= T_TOK * 192) return;
  int t = id / 192, kk = id - t * 192;
  int k4 = kk * 4;
  int c = k4 >> 8, rem = k4 & 255, p = rem >> 4, q = rem & 15;
  int b = t / 196, n = t - b * 196, gh = n / 14, gw = n - gh * 14;
  const float4 v = *(const float4*)(x + ((size_t)(b * 3 + c) * 224 + gh * 16 + p) * 224 + gw * 16 + q);
  u16 h0, l0, h1, l1, h2, l2, h3, l3;
  fsplit(v.x, h0, l0); fsplit(v.y, h1, l1); fsplit(v.z, h2, l2); fsplit(v.w, h3, l3);
  *(ushort4*)(Aph + (size_t)t * 768 + k4) = make_ushort4(h0, h1, h2, h3);
  *(ushort4*)(Apl + (size_t)t * 768 + k4) = make_ushort4(l0, l1, l2, l3);
}

// ---------------------------------------------------------------------------
// LayerNorm over E=256: wave per token; SPLIT_OUT -> hi/lo bf16, else f32
// ---------------------------------------------------------------------------
template<bool SPLIT_OUT>
__global__ __launch_bounds__(256) void ln_kernel(const float* __restrict__ in,
    const float* __restrict__ g, const float* __restrict__ b,
    u16* __restrict__ oh, u16* __restrict__ ol, float* __restrict__ outf)
{
  const int lane = threadIdx.x & 63;
  const int t = blockIdx.x * 4 + (threadIdx.x >> 6);
  const float4 v = *(const float4*)(in + (size_t)t * 256 + lane * 4);
  float s = v.x + v.y + v.z + v.w;
  float sq = v.x * v.x + v.y * v.y + v.z * v.z + v.w * v.w;
#pragma unroll
  for (int o = 32; o >= 1; o >>= 1) {
    s  += __shfl_xor(s,  o, 64);
    sq += __shfl_xor(sq, o, 64);
  }
  float mu = s * (1.f / 256.f);
  float var = sq * (1.f / 256.f) - mu * mu;
  float rstd = rsqrtf(var + 1e-5f);
  const float4 gv = *(const float4*)(g + lane * 4);
  const float4 bv = *(const float4*)(b + lane * 4);
  float o0 = (v.x - mu) * rstd * gv.x + bv.x;
  float o1 = (v.y - mu) * rstd * gv.y + bv.y;
  float o2 = (v.z - mu) * rstd * gv.z + bv.z;
  float o3 = (v.w - mu) * rstd * gv.w + bv.w;
  if constexpr (SPLIT_OUT) {
    u16 h0, l0, h1, l1, h2, l2, h3, l3;
    fsplit(o0, h0, l0); fsplit(o1, h1, l1); fsplit(o2, h2, l2); fsplit(o3, h3, l3);
    *(ushort4*)(oh + (size_t)t * 256 + lane * 4) = make_ushort4(h0, h1, h2, h3);
    *(ushort4*)(ol + (size_t)t * 256 + lane * 4) = make_ushort4(l0, l1, l2, l3);
  } else {
    *(float4*)(outf + (size_t)t * 256 + lane * 4) = make_float4(o0, o1, o2, o3);
  }
}

// ---------------------------------------------------------------------------
// MFMA attention: one block per (b,h), 4 waves, 13 m-tiles of 16 q-rows.
// qkvb is bf16 [T,768] (Q|K|V). S=QK^T via 16x16x32 (K=32, one step),
// masked in-register softmax, P->LDS(bf16)->PV with swizzled V^T.
// ---------------------------------------------------------------------------
__global__ __launch_bounds__(256) void attn_mfma(const u16* __restrict__ qkvb,
                                                 u16* __restrict__ aoh, u16* __restrict__ aol) {
  __shared__ u16 Qs[208][40];       // rows 196..207 zero; stride 80B (bank spread)
  __shared__ u16 Ks[208][40];
  __shared__ u16 Vt[32][256];       // V^T, col XOR-swizzled by ((d&7)<<3); keys>=196 zero
  __shared__ u16 Ps[4][16][232];    // per-wave P tile; cols 208..223 zero
  const int tid = threadIdx.x, lane = tid & 63, wave = tid >> 6;
  const int b = blockIdx.x >> 3, h = blockIdx.x & 7;
  const size_t base = (size_t)b * 196 * 768 + h * 32;
  const short8 z8 = {0, 0, 0, 0, 0, 0, 0, 0};

  for (int idx = tid; idx < 832; idx += 256) {        // Q,K: 208 rows x 4 chunks
    int r = idx >> 2, c = (idx & 3) * 8;
    short8 q = z8, k = z8;
    if (r < 196) {
      q = *(const short8*)(qkvb + base + (size_t)r * 768 + c);
      k = *(const short8*)(qkvb + base + (size_t)r * 768 + 256 + c);
    }
    *(short8*)&Qs[r][c] = q;
    *(short8*)&Ks[r][c] = k;
  }
  for (int idx = tid; idx < 32 * 224; idx += 256) {   // V^T with swizzle
    int c = idx & 31, k = idx >> 5;
    u16 v = 0;
    if (k < 196) v = qkvb[base + (size_t)k * 768 + 512 + c];
    Vt[c][k ^ ((c & 7) << 3)] = v;
  }
  {                                                    // P pad cols [208,224) = 0
    int r = lane >> 2, c0 = 208 + (lane & 3) * 4;
    Ps[wave][r][c0] = 0; Ps[wave][r][c0 + 1] = 0; Ps[wave][r][c0 + 2] = 0; Ps[wave][r][c0 + 3] = 0;
  }
  __syncthreads();

  const int rsel = lane & 15, ksel = (lane >> 4) * 8;
  const f32x4 zero = {0.f, 0.f, 0.f, 0.f};

  for (int mt = wave; mt < 13; mt += 4) {
    short8 aq = *(const short8*)&Qs[mt * 16 + rsel][ksel];
    f32x4 sacc[13];
#pragma unroll
    for (int n = 0; n < 13; ++n)
      sacc[n] = __builtin_amdgcn_mfma_f32_16x16x32_bf16(
          aq, *(const short8*)&Ks[n * 16 + rsel][ksel], zero, 0, 0, 0);

    // softmax: lane holds rows (lane>>4)*4+r, col = n*16 + rsel (mask >=196)
#pragma unroll
    for (int r = 0; r < 4; ++r) {
      float mv = -1e30f;
#pragma unroll
      for (int n = 0; n < 13; ++n) {
        float sv = sacc[n][r] * 0.17677669529663687f;   // 1/sqrt(32)
        sacc[n][r] = sv;
        if (n * 16 + rsel < 196) mv = fmaxf(mv, sv);
      }
      mv = fmaxf(mv, __shfl_xor(mv, 1, 64));
      mv = fmaxf(mv, __shfl_xor(mv, 2, 64));
      mv = fmaxf(mv, __shfl_xor(mv, 4, 64));
      mv = fmaxf(mv, __shfl_xor(mv, 8, 64));
      float sm = 0.f;
#pragma unroll
      for (int n = 0; n < 13; ++n) {
        float p = (n * 16 + rsel < 196) ? __expf(sacc[n][r] - mv) : 0.f;
        sacc[n][r] = p;
        sm += p;
      }
      sm += __shfl_xor(sm, 1, 64);
      sm += __shfl_xor(sm, 2, 64);
      sm += __shfl_xor(sm, 4, 64);
      sm += __shfl_xor(sm, 8, 64);
      float inv = 1.f / sm;
      int prow = (lane >> 4) * 4 + r;
#pragma unroll
      for (int n = 0; n < 13; ++n)
        Ps[wave][prow][n * 16 + rsel] = bfbits(sacc[n][r] * inv);
    }

    // PV: A = P[16][224], B = V^T[d][k] (swizzled)
    f32x4 oacc[2] = {zero, zero};
#pragma unroll
    for (int kk = 0; kk < 7; ++kk) {
      short8 ap = *(const short8*)&Ps[wave][rsel][kk * 32 + ksel];
#pragma unroll
      for (int nt = 0; nt < 2; ++nt) {
        int d = nt * 16 + rsel;
        short8 bv = *(const short8*)&Vt[d][(kk * 32 + ksel) ^ ((d & 7) << 3)];
        oacc[nt] = __builtin_amdgcn_mfma_f32_16x16x32_bf16(ap, bv, oacc[nt], 0, 0, 0);
      }
    }
#pragma unroll
    for (int nt = 0; nt < 2; ++nt) {
#pragma unroll
      for (int r = 0; r < 4; ++r) {
        int row = mt * 16 + (lane >> 4) * 4 + r;
        if (row < 196) {
          size_t oi = ((size_t)b * 196 + row) * 256 + h * 32 + nt * 16 + rsel;
          u16 hh, ll; fsplit(oacc[nt][r], hh, ll);
          aoh[oi] = hh; aol[oi] = ll;
        }
      }
    }
  }
}

// ---------------------------------------------------------------------------
// Router: wave per token; 6 logits, softmax, top-2 -> dense gates [T,6]
// ---------------------------------------------------------------------------
__global__ __launch_bounds__(256) void router_kernel(const float* __restrict__ x1,
    const float* __restrict__ rw, const float* __restrict__ rb, float* __restrict__ gates)
{
  const int lane = threadIdx.x & 63;
  const int t = blockIdx.x * 4 + (threadIdx.x >> 6);
  const float4 xv = *(const float4*)(x1 + (size_t)t * 256 + lane * 4);
  float logit[6];
#pragma unroll
  for (int e = 0; e < 6; ++e) {
    const float4 wv = *(const float4*)(rw + e * 256 + lane * 4);
    float p = xv.x * wv.x + xv.y * wv.y + xv.z * wv.z + xv.w * wv.w;
#pragma unroll
    for (int o = 32; o >= 1; o >>= 1) p += __shfl_xor(p, o, 64);
    logit[e] = p + rb[e];
  }
  float mx = logit[0];
#pragma unroll
  for (int e = 1; e < 6; ++e) mx = fmaxf(mx, logit[e]);
  float pe[6], sum = 0.f;
#pragma unroll
  for (int e = 0; e < 6; ++e) { pe[e] = __expf(logit[e] - mx); sum += pe[e]; }
  float inv = 1.f / sum;
  int i1 = 0; float p1 = pe[0];
#pragma unroll
  for (int e = 1; e < 6; ++e) if (pe[e] > p1) { p1 = pe[e]; i1 = e; }
  int i2 = -1; float p2 = -1.f;
#pragma unroll
  for (int e = 0; e < 6; ++e) if (e != i1 && pe[e] > p2) { p2 = pe[e]; i2 = e; }
  if (lane < 6)
    gates[(size_t)t * 6 + lane] = (lane == i1) ? p1 * inv : ((lane == i2) ? p2 * inv : 0.f);
}

// ---------------------------------------------------------------------------
// Scatter: build per-expert token lists (block-aggregated atomics)
// ---------------------------------------------------------------------------
__global__ __launch_bounds__(256) void scatter_kernel(const float* __restrict__ gates,
                                                      int* __restrict__ cnt, int* __restrict__ idx) {
  __shared__ int lcnt[6], lbase[6];
  const int t = blockIdx.x * 256 + threadIdx.x;
  if (threadIdx.x < 6) lcnt[threadIdx.x] = 0;
  __syncthreads();
  float g[6]; int lpos[6];
#pragma unroll
  for (int e = 0; e < 6; ++e) {
    g[e] = gates[(size_t)t * 6 + e];
    if (g[e] > 0.f) lpos[e] = atomicAdd(&lcnt[e], 1);
  }
  __syncthreads();
  if (threadIdx.x < 6) lbase[threadIdx.x] = atomicAdd(&cnt[threadIdx.x], lcnt[threadIdx.x]);
  __syncthreads();
#pragma unroll
  for (int e = 0; e < 6; ++e)
    if (g[e] > 0.f) idx[(size_t)e * T_TOK + lbase[e] + lpos[e]] = t;
}

// ---------------------------------------------------------------------------
// Mean-pool over tokens, then classifier head (fp32)
// ---------------------------------------------------------------------------
__global__ __launch_bounds__(256) void pool_kernel(const float* __restrict__ x2, float* __restrict__ pooled) {
  int b = blockIdx.x, e = threadIdx.x;
  float s = 0.f;
  for (int n = 0; n < 196; ++n) s += x2[((size_t)b * 196 + n) * 256 + e];
  pooled[(size_t)b * 256 + e] = s * (1.f / 196.f);
}

__global__ __launch_bounds__(256) void head_kernel(const float* __restrict__ pooled,
    const float* __restrict__ hw, const float* __restrict__ hb, float* __restrict__ out) {
  __shared__ float p[256];
  int b = blockIdx.x;
  p[threadIdx.x] = pooled[(size_t)b * 256 + threadIdx.x];
  __syncthreads();
  for (int cls = threadIdx.x; cls < 1000; cls += 256) {
    const float* w = hw + (size_t)cls * 256;
    float s = hb[cls];
    for (int k = 0; k < 256; k += 4)
      s += p[k] * w[k] + p[k + 1] * w[k + 1] + p[k + 2] * w[k + 2] + p[k + 3] * w[k + 3];
    out[(size_t)b * 1000 + cls] = s;
  }
}

// ---------------------------------------------------------------------------
// Weight prep: f32 -> hi/lo bf16; batched transpose+split ([R,C] -> [C,R])
// ---------------------------------------------------------------------------
__global__ void cast_split_kernel(const float* __restrict__ in,
                                  u16* __restrict__ oh, u16* __restrict__ ol, int n4) {
  int id = blockIdx.x * 256 + threadIdx.x;
  if (id >= n4) return;
  float4 v = ((const float4*)in)[id];
  u16 h0, l0, h1, l1, h2, l2, h3, l3;
  fsplit(v.x, h0, l0); fsplit(v.y, h1, l1); fsplit(v.z, h2, l2); fsplit(v.w, h3, l3);
  ((ushort4*)oh)[id] = make_ushort4(h0, h1, h2, h3);
  ((ushort4*)ol)[id] = make_ushort4(l0, l1, l2, l3);
}

__global__ __launch_bounds__(256) void transpose_split(const float* __restrict__ in,
    u16* __restrict__ oh, u16* __restrict__ ol, int R, int C) {
  __shared__ float tile[32][33];
  const int e = blockIdx.z;
  const int bc = blockIdx.x * 32, br = blockIdx.y * 32;
  const int tx = threadIdx.x & 31, ty = threadIdx.x >> 5;
  const float* src = in + (size_t)e * R * C;
#pragma unroll
  for (int i = 0; i < 32; i += 8)
    tile[ty + i][tx] = src[(size_t)(br + ty + i) * C + bc + tx];
  __syncthreads();
#pragma unroll
  for (int i = 0; i < 32; i += 8) {
    float v = tile[tx][ty + i];
    u16 h, l; fsplit(v, h, l);
    size_t di = (size_t)e * R * C + (size_t)(bc + ty + i) * R + br + tx;
    oh[di] = h; ol[di] = l;
  }
}

// ---------------------------------------------------------------------------
extern "C" void kernel_launch(void* const* d_in, const int* in_sizes, int n_in,
                              void* d_out, int out_size, void* d_ws, size_t ws_size,
                              hipStream_t stream) {
  (void)in_sizes; (void)n_in; (void)out_size; (void)ws_size;
  const float* x      = (const float*)d_in[0];
  const float* conv_w = (const float*)d_in[1];
  const float* conv_b = (const float*)d_in[2];
  const float* pos    = (const float*)d_in[3];
  const float* ln1_g  = (const float*)d_in[4];
  const float* ln1_b  = (const float*)d_in[5];
  const float* wqkv   = (const float*)d_in[6];
  const float* bqkv   = (const float*)d_in[7];
  const float* wo     = (const float*)d_in[8];
  const float* bo     = (const float*)d_in[9];
  const float* rw     = (const float*)d_in[10];
  const float* rb     = (const float*)d_in[11];
  const float* w1     = (const float*)d_in[12];
  const float* b1     = (const float*)d_in[13];
  const float* w2     = (const float*)d_in[14];
  const float* b2     = (const float*)d_in[15];
  const float* ln2_g  = (const float*)d_in[16];
  const float* ln2_b  = (const float*)d_in[17];
  const float* hw     = (const float*)d_in[18];
  const float* hb     = (const float*)d_in[19];
  float* out = (float*)d_out;

  const int T = T_TOK, E = 256, HID = 1024;
  char* ws = (char*)d_ws;
  size_t off = 0;
  auto alloc = [&](size_t bytes) -> void* {
    void* p = ws + off;
    off += (bytes + 255) & ~(size_t)255;
    return p;
  };
  u16*   Aph    = (u16*)  alloc((size_t)T * 768 * 2);   // --- region reused by hbuf ---
  u16*   Apl    = (u16*)  alloc((size_t)T * 768 * 2);
  float* tok    = (float*)alloc((size_t)T * 256 * 4);   // --- end hbuf region (exact fit) ---
  u16*   xnh    = (u16*)  alloc((size_t)T * 256 * 2);
  u16*   xnl    = (u16*)  alloc((size_t)T * 256 * 2);
  u16*   qkvb   = (u16*)  alloc((size_t)T * 768 * 2);   // bf16 hi only; reused by x2
  u16*   aoh    = (u16*)  alloc((size_t)T * 256 * 2);
  u16*   aol    = (u16*)  alloc((size_t)T * 256 * 2);
  float* x1f    = (float*)alloc((size_t)T * 256 * 4);   // reused by moe accum
  u16*   x1h    = (u16*)  alloc((size_t)T * 256 * 2);
  u16*   x1l    = (u16*)  alloc((size_t)T * 256 * 2);
  float* gates  = (float*)alloc((size_t)T * 6 * 4);
  int*   idx    = (int*)  alloc((size_t)6 * T * 4);
  int*   cnt    = (int*)  alloc(256);
  float* pooled = (float*)alloc((size_t)128 * 256 * 4);
  u16*   cwh    = (u16*)  alloc((size_t)196608 * 2);
  u16*   cwl    = (u16*)  alloc((size_t)196608 * 2);
  u16*   wqh    = (u16*)  alloc((size_t)196608 * 2);
  u16*   wql    = (u16*)  alloc((size_t)196608 * 2);
  u16*   woh    = (u16*)  alloc((size_t)65536 * 2);
  u16*   wol    = (u16*)  alloc((size_t)65536 * 2);
  u16*   w1th   = (u16*)  alloc((size_t)6 * 262144 * 2);
  u16*   w1tl   = (u16*)  alloc((size_t)6 * 262144 * 2);
  u16*   w2th   = (u16*)  alloc((size_t)6 * 262144 * 2);
  u16*   w2tl   = (u16*)  alloc((size_t)6 * 262144 * 2);
  // aliases (lifetimes disjoint):
  u16*   hbh = (u16*)ws;                          // [T,1024] hi — over Aph/Apl/tok
  u16*   hbl = hbh + (size_t)T * 1024;            // [T,1024] lo (exactly fills region)
  float* x2  = (float*)qkvb;                      // [T,256] f32
  float* moe = x1f;                               // [T,256] f32 accumulator

  // --- weight prep ---
  cast_split_kernel<<<192, 256, 0, stream>>>(conv_w, cwh, cwl, 49152);
  cast_split_kernel<<<192, 256, 0, stream>>>(wqkv, wqh, wql, 49152);
  cast_split_kernel<<<64, 256, 0, stream>>>(wo, woh, wol, 16384);
  transpose_split<<<dim3(32, 8, 6), 256, 0, stream>>>(w1, w1th, w1tl, 256, 1024);  // [e][n][k]
  transpose_split<<<dim3(8, 32, 6), 256, 0, stream>>>(w2, w2th, w2tl, 1024, 256);  // [e][n][k]

  // --- patch embedding ---
  im2col_split<<<18816, 256, 0, stream>>>(x, Aph, Apl);
  gemm_split<1, 0><<<dim3(196, 2), 256, 0, stream>>>(Aph, Apl, cwh, cwl, T, 256, 768,
      conv_b, pos, tok, nullptr, nullptr, nullptr, nullptr);

  // --- attention block ---
  ln_kernel<true><<<6272, 256, 0, stream>>>(tok, ln1_g, ln1_b, xnh, xnl, nullptr);
  gemm_split<5, 0><<<dim3(196, 6), 256, 0, stream>>>(xnh, xnl, wqh, wql, T, 768, 256,
      bqkv, nullptr, nullptr, qkvb, nullptr, nullptr, nullptr);
  attn_mfma<<<1024, 256, 0, stream>>>(qkvb, aoh, aol);
  gemm_split<2, 0><<<dim3(196, 2), 256, 0, stream>>>(aoh, aol, woh, wol, T, 256, 256,
      bo, tok, x1f, x1h, x1l, nullptr, nullptr);

  // --- MoE (top-2 sparse: gather tokens per expert, scatter-accumulate) ---
  router_kernel<<<6272, 256, 0, stream>>>(x1f, rw, rb, gates);
  hipMemsetAsync(cnt, 0, 256, stream);
  scatter_kernel<<<98, 256, 0, stream>>>(gates, cnt, idx);
  hipMemsetAsync(moe, 0, (size_t)T * 256 * 4, stream);   // x1f dead after router
  for (int e = 0; e < 6; ++e) {
    gemm_split<3, 1><<<dim3(196, 8), 256, 0, stream>>>(x1h, x1l,
        w1th + (size_t)e * HID * E, w1tl + (size_t)e * HID * E, T, 1024, 256,
        b1 + e * 1024, nullptr, nullptr, hbh, hbl, idx + (size_t)e * T, cnt + e);
    gemm_split<4, 2><<<dim3(196, 2), 256, 0, stream>>>(hbh, hbl,
        w2th + (size_t)e * E * HID, w2tl + (size_t)e * E * HID, T, 256, 1024,
        b2 + e * 256, gates + e, moe, nullptr, nullptr, idx + (size_t)e * T, cnt + e);
  }

  // --- final norm, pool, head ---
  ln_kernel<false><<<6272, 256, 0, stream>>>(moe, ln2_g, ln2_b, nullptr, nullptr, x2);
  pool_kernel<<<128, 256, 0, stream>>>(x2, pooled);
  head_kernel<<<128, 256, 0, stream>>>(pooled, hw, hb, out);
}

// Round 4
// 618.213 us; speedup vs baseline: 2.2520x; 1.6710x over previous
//
#include <hip/hip_runtime.h>
#include <hip/hip_bf16.h>

typedef unsigned short u16;
typedef short short8 __attribute__((ext_vector_type(8)));
typedef float f32x4 __attribute__((ext_vector_type(4)));

#define T_TOK 25088   // 128*196
#define NTOK 196

__device__ __forceinline__ u16 bfbits(float v) {
  __hip_bfloat16 h = __float2bfloat16(v);
  return *reinterpret_cast<u16*>(&h);
}
__device__ __forceinline__ float b2f(u16 u) {
  __hip_bfloat16 h = *reinterpret_cast<__hip_bfloat16*>(&u);
  return __bfloat162float(h);
}
// near-fp32 as hi+lo bf16 pair (Ootomo split)
__device__ __forceinline__ void fsplit(float v, u16& hi, u16& lo) {
  hi = bfbits(v);
  lo = bfbits(v - b2f(hi));
}

// ---------------------------------------------------------------------------
// Split-bf16 MFMA GEMM: C[M,N] = A[M,K] @ (Bh+Bl)[N,K]^T + bias
// A is split (Ah+Al, 3 MFMA) when SPLITA, else bf16-only (2 MFMA).
// 128x128 tile, BK=32, 256 threads (4 waves 2x2).
// EPI: 1 +pos->f32 | 2 +resid->f32+split | 3 gelu->bf16(h-seg) | 4 gate-scatter-acc | 5 ->bf16
// MODE: 0 dense | 1 expert-gather A rows via idx (z=expert) | 2 expert h-seg A, scatter out
// ---------------------------------------------------------------------------
template<int EPI, int MODE, bool SPLITA>
__global__ __launch_bounds__(256) void gemm_split(
    const u16* __restrict__ Ah, const u16* __restrict__ Al,
    const u16* __restrict__ Bh, const u16* __restrict__ Bl,
    int M, int N, int K,
    const float* __restrict__ bias, const float* __restrict__ extra,
    float* __restrict__ outf, u16* __restrict__ obh, u16* __restrict__ obl,
    const int* __restrict__ idx_all, const int* __restrict__ cnt_all,
    const int* __restrict__ base_all, size_t wstride, int bstride)
{
  int Meff = M, hbase = 0;
  const int* gidx = idx_all;
  if constexpr (MODE != 0) {
    const int e = blockIdx.z;
    Meff = cnt_all[e];
    if ((int)blockIdx.x * 128 >= Meff) return;
    gidx = idx_all + (size_t)e * T_TOK;
    hbase = base_all[e];
    Bh += (size_t)e * wstride;
    Bl += (size_t)e * wstride;
    bias += (size_t)e * bstride;
  }
  __shared__ u16 Ash[128][40];
  __shared__ u16 Asl[SPLITA ? 128 : 1][40];
  __shared__ u16 Bsh[128][40], Bsl[128][40];
  const int tid = threadIdx.x;
  const int lane = tid & 63, wave = tid >> 6;
  const int wm = wave >> 1, wn = wave & 1;
  const int row0 = blockIdx.x * 128, col0 = blockIdx.y * 128;

  // staging row assignment (fixed across k-loop)
  const int r0 = tid >> 2, r1 = r0 + 64, co = (tid & 3) * 8;
  int ar0, ar1;
  if constexpr (MODE == 1) {
    ar0 = gidx[min(row0 + r0, Meff - 1)];
    ar1 = gidx[min(row0 + r1, Meff - 1)];
  } else if constexpr (MODE == 2) {
    ar0 = hbase + min(row0 + r0, Meff - 1);
    ar1 = hbase + min(row0 + r1, Meff - 1);
  } else {
    ar0 = row0 + r0; ar1 = row0 + r1;
  }

  f32x4 acc[4][4];
  const f32x4 zero = {0.f, 0.f, 0.f, 0.f};
#pragma unroll
  for (int i = 0; i < 4; ++i)
#pragma unroll
    for (int j = 0; j < 4; ++j) acc[i][j] = zero;

  const int rsel = lane & 15, ksel = (lane >> 4) * 8;

  for (int k0 = 0; k0 < K; k0 += 32) {
    __syncthreads();
    *(short8*)&Ash[r0][co] = *(const short8*)(Ah + (size_t)ar0 * K + k0 + co);
    *(short8*)&Ash[r1][co] = *(const short8*)(Ah + (size_t)ar1 * K + k0 + co);
    if constexpr (SPLITA) {
      *(short8*)&Asl[r0][co] = *(const short8*)(Al + (size_t)ar0 * K + k0 + co);
      *(short8*)&Asl[r1][co] = *(const short8*)(Al + (size_t)ar1 * K + k0 + co);
    }
    *(short8*)&Bsh[r0][co] = *(const short8*)(Bh + (size_t)(col0 + r0) * K + k0 + co);
    *(short8*)&Bsl[r0][co] = *(const short8*)(Bl + (size_t)(col0 + r0) * K + k0 + co);
    *(short8*)&Bsh[r1][co] = *(const short8*)(Bh + (size_t)(col0 + r1) * K + k0 + co);
    *(short8*)&Bsl[r1][co] = *(const short8*)(Bl + (size_t)(col0 + r1) * K + k0 + co);
    __syncthreads();
    short8 ah[4], al[4], bh[4], bl[4];
#pragma unroll
    for (int i = 0; i < 4; ++i) {
      ah[i] = *(const short8*)&Ash[wm * 64 + i * 16 + rsel][ksel];
      if constexpr (SPLITA) al[i] = *(const short8*)&Asl[wm * 64 + i * 16 + rsel][ksel];
    }
#pragma unroll
    for (int j = 0; j < 4; ++j) {
      bh[j] = *(const short8*)&Bsh[wn * 64 + j * 16 + rsel][ksel];
      bl[j] = *(const short8*)&Bsl[wn * 64 + j * 16 + rsel][ksel];
    }
#pragma unroll
    for (int i = 0; i < 4; ++i)
#pragma unroll
      for (int j = 0; j < 4; ++j) {
        acc[i][j] = __builtin_amdgcn_mfma_f32_16x16x32_bf16(ah[i], bh[j], acc[i][j], 0, 0, 0);
        if constexpr (SPLITA)
          acc[i][j] = __builtin_amdgcn_mfma_f32_16x16x32_bf16(al[i], bh[j], acc[i][j], 0, 0, 0);
        acc[i][j] = __builtin_amdgcn_mfma_f32_16x16x32_bf16(ah[i], bl[j], acc[i][j], 0, 0, 0);
      }
  }

#pragma unroll
  for (int i = 0; i < 4; ++i) {
#pragma unroll
    for (int j = 0; j < 4; ++j) {
#pragma unroll
      for (int r = 0; r < 4; ++r) {
        int grow = row0 + wm * 64 + i * 16 + (lane >> 4) * 4 + r;   // token / row
        int gcol = col0 + wn * 64 + j * 16 + (lane & 15);           // feature
        float v = acc[i][j][r] + bias[gcol];
        size_t oi = (size_t)grow * N + gcol;
        if constexpr (EPI == 1) {
          v += extra[(size_t)(grow % NTOK) * N + gcol];   // pos_embed
          outf[oi] = v;
        } else if constexpr (EPI == 2) {
          v += extra[oi];                                  // residual
          outf[oi] = v;
          u16 h, l; fsplit(v, h, l); obh[oi] = h; obl[oi] = l;
        } else if constexpr (EPI == 3) {
          if (grow < Meff) {
            float g = 0.5f * v * (1.f + erff(v * 0.70710678118654752f));
            obh[(size_t)(hbase + grow) * N + gcol] = bfbits(g);
          }
        } else if constexpr (EPI == 4) {
          if (grow < Meff) {
            int tk = gidx[grow];
            atomicAdd(&outf[(size_t)tk * N + gcol], extra[(size_t)tk * 6 + blockIdx.z] * v);
          }
        } else if constexpr (EPI == 5) {
          obh[oi] = bfbits(v);
        }
      }
    }
  }
}

// ---------------------------------------------------------------------------
// im2col + split: x[B,3,224,224] f32 -> A_patch hi/lo [T,768]
// ---------------------------------------------------------------------------
__global__ void im2col_split(const float* __restrict__ x,
                             u16* __restrict__ Aph, u16* __restrict__ Apl) {
  int id = blockIdx.x * 256 + threadIdx.x;          // T*192 items of 4 elems
  if (id >= T_TOK * 192) return;
  int t = id / 192, kk = id - t * 192;
  int k4 = kk * 4;
  int c = k4 >> 8, rem = k4 & 255, p = rem >> 4, q = rem & 15;
  int b = t / 196, n = t - b * 196, gh = n / 14, gw = n - gh * 14;
  const float4 v = *(const float4*)(x + ((size_t)(b * 3 + c) * 224 + gh * 16 + p) * 224 + gw * 16 + q);
  u16 h0, l0, h1, l1, h2, l2, h3, l3;
  fsplit(v.x, h0, l0); fsplit(v.y, h1, l1); fsplit(v.z, h2, l2); fsplit(v.w, h3, l3);
  *(ushort4*)(Aph + (size_t)t * 768 + k4) = make_ushort4(h0, h1, h2, h3);
  *(ushort4*)(Apl + (size_t)t * 768 + k4) = make_ushort4(l0, l1, l2, l3);
}

// ---------------------------------------------------------------------------
// LayerNorm over E=256: wave per token; SPLIT_OUT -> hi/lo bf16, else f32
// ---------------------------------------------------------------------------
template<bool SPLIT_OUT>
__global__ __launch_bounds__(256) void ln_kernel(const float* __restrict__ in,
    const float* __restrict__ g, const float* __restrict__ b,
    u16* __restrict__ oh, u16* __restrict__ ol, float* __restrict__ outf)
{
  const int lane = threadIdx.x & 63;
  const int t = blockIdx.x * 4 + (threadIdx.x >> 6);
  const float4 v = *(const float4*)(in + (size_t)t * 256 + lane * 4);
  float s = v.x + v.y + v.z + v.w;
  float sq = v.x * v.x + v.y * v.y + v.z * v.z + v.w * v.w;
#pragma unroll
  for (int o = 32; o >= 1; o >>= 1) {
    s  += __shfl_xor(s,  o, 64);
    sq += __shfl_xor(sq, o, 64);
  }
  float mu = s * (1.f / 256.f);
  float var = sq * (1.f / 256.f) - mu * mu;
  float rstd = rsqrtf(var + 1e-5f);
  const float4 gv = *(const float4*)(g + lane * 4);
  const float4 bv = *(const float4*)(b + lane * 4);
  float o0 = (v.x - mu) * rstd * gv.x + bv.x;
  float o1 = (v.y - mu) * rstd * gv.y + bv.y;
  float o2 = (v.z - mu) * rstd * gv.z + bv.z;
  float o3 = (v.w - mu) * rstd * gv.w + bv.w;
  if constexpr (SPLIT_OUT) {
    u16 h0, l0, h1, l1, h2, l2, h3, l3;
    fsplit(o0, h0, l0); fsplit(o1, h1, l1); fsplit(o2, h2, l2); fsplit(o3, h3, l3);
    *(ushort4*)(oh + (size_t)t * 256 + lane * 4) = make_ushort4(h0, h1, h2, h3);
    *(ushort4*)(ol + (size_t)t * 256 + lane * 4) = make_ushort4(l0, l1, l2, l3);
  } else {
    *(float4*)(outf + (size_t)t * 256 + lane * 4) = make_float4(o0, o1, o2, o3);
  }
}

// ---------------------------------------------------------------------------
// MFMA attention: one block per (b,h), 4 waves, 13 m-tiles of 16 q-rows.
// ---------------------------------------------------------------------------
__global__ __launch_bounds__(256) void attn_mfma(const u16* __restrict__ qkvb,
                                                 u16* __restrict__ aoh, u16* __restrict__ aol) {
  __shared__ u16 Qs[208][40];       // rows 196..207 zero; stride 80B (bank spread)
  __shared__ u16 Ks[208][40];
  __shared__ u16 Vt[32][256];       // V^T, col XOR-swizzled by ((d&7)<<3); keys>=196 zero
  __shared__ u16 Ps[4][16][232];    // per-wave P tile; cols 208..223 zero
  const int tid = threadIdx.x, lane = tid & 63, wave = tid >> 6;
  const int b = blockIdx.x >> 3, h = blockIdx.x & 7;
  const size_t base = (size_t)b * 196 * 768 + h * 32;
  const short8 z8 = {0, 0, 0, 0, 0, 0, 0, 0};

  for (int idx = tid; idx < 832; idx += 256) {        // Q,K: 208 rows x 4 chunks
    int r = idx >> 2, c = (idx & 3) * 8;
    short8 q = z8, k = z8;
    if (r < 196) {
      q = *(const short8*)(qkvb + base + (size_t)r * 768 + c);
      k = *(const short8*)(qkvb + base + (size_t)r * 768 + 256 + c);
    }
    *(short8*)&Qs[r][c] = q;
    *(short8*)&Ks[r][c] = k;
  }
  for (int idx = tid; idx < 32 * 224; idx += 256) {   // V^T with swizzle
    int c = idx & 31, k = idx >> 5;
    u16 v = 0;
    if (k < 196) v = qkvb[base + (size_t)k * 768 + 512 + c];
    Vt[c][k ^ ((c & 7) << 3)] = v;
  }
  {                                                    // P pad cols [208,224) = 0
    int r = lane >> 2, c0 = 208 + (lane & 3) * 4;
    Ps[wave][r][c0] = 0; Ps[wave][r][c0 + 1] = 0; Ps[wave][r][c0 + 2] = 0; Ps[wave][r][c0 + 3] = 0;
  }
  __syncthreads();

  const int rsel = lane & 15, ksel = (lane >> 4) * 8;
  const f32x4 zero = {0.f, 0.f, 0.f, 0.f};

  for (int mt = wave; mt < 13; mt += 4) {
    short8 aq = *(const short8*)&Qs[mt * 16 + rsel][ksel];
    f32x4 sacc[13];
#pragma unroll
    for (int n = 0; n < 13; ++n)
      sacc[n] = __builtin_amdgcn_mfma_f32_16x16x32_bf16(
          aq, *(const short8*)&Ks[n * 16 + rsel][ksel], zero, 0, 0, 0);

#pragma unroll
    for (int r = 0; r < 4; ++r) {
      float mv = -1e30f;
#pragma unroll
      for (int n = 0; n < 13; ++n) {
        float sv = sacc[n][r] * 0.17677669529663687f;   // 1/sqrt(32)
        sacc[n][r] = sv;
        if (n * 16 + rsel < 196) mv = fmaxf(mv, sv);
      }
      mv = fmaxf(mv, __shfl_xor(mv, 1, 64));
      mv = fmaxf(mv, __shfl_xor(mv, 2, 64));
      mv = fmaxf(mv, __shfl_xor(mv, 4, 64));
      mv = fmaxf(mv, __shfl_xor(mv, 8, 64));
      float sm = 0.f;
#pragma unroll
      for (int n = 0; n < 13; ++n) {
        float p = (n * 16 + rsel < 196) ? __expf(sacc[n][r] - mv) : 0.f;
        sacc[n][r] = p;
        sm += p;
      }
      sm += __shfl_xor(sm, 1, 64);
      sm += __shfl_xor(sm, 2, 64);
      sm += __shfl_xor(sm, 4, 64);
      sm += __shfl_xor(sm, 8, 64);
      float inv = 1.f / sm;
      int prow = (lane >> 4) * 4 + r;
#pragma unroll
      for (int n = 0; n < 13; ++n)
        Ps[wave][prow][n * 16 + rsel] = bfbits(sacc[n][r] * inv);
    }

    f32x4 oacc[2] = {zero, zero};
#pragma unroll
    for (int kk = 0; kk < 7; ++kk) {
      short8 ap = *(const short8*)&Ps[wave][rsel][kk * 32 + ksel];
#pragma unroll
      for (int nt = 0; nt < 2; ++nt) {
        int d = nt * 16 + rsel;
        short8 bv = *(const short8*)&Vt[d][(kk * 32 + ksel) ^ ((d & 7) << 3)];
        oacc[nt] = __builtin_amdgcn_mfma_f32_16x16x32_bf16(ap, bv, oacc[nt], 0, 0, 0);
      }
    }
#pragma unroll
    for (int nt = 0; nt < 2; ++nt) {
#pragma unroll
      for (int r = 0; r < 4; ++r) {
        int row = mt * 16 + (lane >> 4) * 4 + r;
        if (row < 196) {
          size_t oi = ((size_t)b * 196 + row) * 256 + h * 32 + nt * 16 + rsel;
          u16 hh, ll; fsplit(oacc[nt][r], hh, ll);
          aoh[oi] = hh; aol[oi] = ll;
        }
      }
    }
  }
}

// ---------------------------------------------------------------------------
// Router: wave per token; 6 logits, softmax, top-2 -> dense gates [T,6]
// ---------------------------------------------------------------------------
__global__ __launch_bounds__(256) void router_kernel(const float* __restrict__ x1,
    const float* __restrict__ rw, const float* __restrict__ rb, float* __restrict__ gates)
{
  const int lane = threadIdx.x & 63;
  const int t = blockIdx.x * 4 + (threadIdx.x >> 6);
  const float4 xv = *(const float4*)(x1 + (size_t)t * 256 + lane * 4);
  float logit[6];
#pragma unroll
  for (int e = 0; e < 6; ++e) {
    const float4 wv = *(const float4*)(rw + e * 256 + lane * 4);
    float p = xv.x * wv.x + xv.y * wv.y + xv.z * wv.z + xv.w * wv.w;
#pragma unroll
    for (int o = 32; o >= 1; o >>= 1) p += __shfl_xor(p, o, 64);
    logit[e] = p + rb[e];
  }
  float mx = logit[0];
#pragma unroll
  for (int e = 1; e < 6; ++e) mx = fmaxf(mx, logit[e]);
  float pe[6], sum = 0.f;
#pragma unroll
  for (int e = 0; e < 6; ++e) { pe[e] = __expf(logit[e] - mx); sum += pe[e]; }
  float inv = 1.f / sum;
  int i1 = 0; float p1 = pe[0];
#pragma unroll
  for (int e = 1; e < 6; ++e) if (pe[e] > p1) { p1 = pe[e]; i1 = e; }
  int i2 = -1; float p2 = -1.f;
#pragma unroll
  for (int e = 0; e < 6; ++e) if (e != i1 && pe[e] > p2) { p2 = pe[e]; i2 = e; }
  if (lane < 6)
    gates[(size_t)t * 6 + lane] = (lane == i1) ? p1 * inv : ((lane == i2) ? p2 * inv : 0.f);
}

// ---------------------------------------------------------------------------
// Scatter: build per-expert token lists (block-aggregated atomics)
// ---------------------------------------------------------------------------
__global__ __launch_bounds__(256) void scatter_kernel(const float* __restrict__ gates,
                                                      int* __restrict__ cnt, int* __restrict__ idx) {
  __shared__ int lcnt[6], lbase[6];
  const int t = blockIdx.x * 256 + threadIdx.x;
  if (threadIdx.x < 6) lcnt[threadIdx.x] = 0;
  __syncthreads();
  float g[6]; int lpos[6];
#pragma unroll
  for (int e = 0; e < 6; ++e) {
    g[e] = gates[(size_t)t * 6 + e];
    if (g[e] > 0.f) lpos[e] = atomicAdd(&lcnt[e], 1);
  }
  __syncthreads();
  if (threadIdx.x < 6) lbase[threadIdx.x] = atomicAdd(&cnt[threadIdx.x], lcnt[threadIdx.x]);
  __syncthreads();
#pragma unroll
  for (int e = 0; e < 6; ++e)
    if (g[e] > 0.f) idx[(size_t)e * T_TOK + lbase[e] + lpos[e]] = t;
}

// exclusive prefix over the 6 expert counts -> segment bases in h buffer
__global__ void prefix6_kernel(const int* __restrict__ cnt, int* __restrict__ base) {
  if (threadIdx.x == 0) {
    int s = 0;
#pragma unroll
    for (int e = 0; e < 6; ++e) { base[e] = s; s += cnt[e]; }
  }
}

// ---------------------------------------------------------------------------
// Mean-pool over tokens, then classifier head (fp32)
// ---------------------------------------------------------------------------
__global__ __launch_bounds__(256) void pool_kernel(const float* __restrict__ x2, float* __restrict__ pooled) {
  int b = blockIdx.x, e = threadIdx.x;
  float s = 0.f;
  for (int n = 0; n < 196; ++n) s += x2[((size_t)b * 196 + n) * 256 + e];
  pooled[(size_t)b * 256 + e] = s * (1.f / 196.f);
}

__global__ __launch_bounds__(256) void head_kernel(const float* __restrict__ pooled,
    const float* __restrict__ hw, const float* __restrict__ hb, float* __restrict__ out) {
  __shared__ float p[256];
  int b = blockIdx.x;
  p[threadIdx.x] = pooled[(size_t)b * 256 + threadIdx.x];
  __syncthreads();
  for (int cls = threadIdx.x; cls < 1000; cls += 256) {
    const float* w = hw + (size_t)cls * 256;
    float s = hb[cls];
    for (int k = 0; k < 256; k += 4)
      s += p[k] * w[k] + p[k + 1] * w[k + 1] + p[k + 2] * w[k + 2] + p[k + 3] * w[k + 3];
    out[(size_t)b * 1000 + cls] = s;
  }
}

// ---------------------------------------------------------------------------
// Weight prep: f32 -> hi/lo bf16; batched transpose+split ([R,C] -> [C,R])
// ---------------------------------------------------------------------------
__global__ void cast_split_kernel(const float* __restrict__ in,
                                  u16* __restrict__ oh, u16* __restrict__ ol, int n4) {
  int id = blockIdx.x * 256 + threadIdx.x;
  if (id >= n4) return;
  float4 v = ((const float4*)in)[id];
  u16 h0, l0, h1, l1, h2, l2, h3, l3;
  fsplit(v.x, h0, l0); fsplit(v.y, h1, l1); fsplit(v.z, h2, l2); fsplit(v.w, h3, l3);
  ((ushort4*)oh)[id] = make_ushort4(h0, h1, h2, h3);
  ((ushort4*)ol)[id] = make_ushort4(l0, l1, l2, l3);
}

__global__ __launch_bounds__(256) void transpose_split(const float* __restrict__ in,
    u16* __restrict__ oh, u16* __restrict__ ol, int R, int C) {
  __shared__ float tile[32][33];
  const int e = blockIdx.z;
  const int bc = blockIdx.x * 32, br = blockIdx.y * 32;
  const int tx = threadIdx.x & 31, ty = threadIdx.x >> 5;
  const float* src = in + (size_t)e * R * C;
#pragma unroll
  for (int i = 0; i < 32; i += 8)
    tile[ty + i][tx] = src[(size_t)(br + ty + i) * C + bc + tx];
  __syncthreads();
#pragma unroll
  for (int i = 0; i < 32; i += 8) {
    float v = tile[tx][ty + i];
    u16 h, l; fsplit(v, h, l);
    size_t di = (size_t)e * R * C + (size_t)(bc + ty + i) * R + br + tx;
    oh[di] = h; ol[di] = l;
  }
}

// ---------------------------------------------------------------------------
extern "C" void kernel_launch(void* const* d_in, const int* in_sizes, int n_in,
                              void* d_out, int out_size, void* d_ws, size_t ws_size,
                              hipStream_t stream) {
  (void)in_sizes; (void)n_in; (void)out_size; (void)ws_size;
  const float* x      = (const float*)d_in[0];
  const float* conv_w = (const float*)d_in[1];
  const float* conv_b = (const float*)d_in[2];
  const float* pos    = (const float*)d_in[3];
  const float* ln1_g  = (const float*)d_in[4];
  const float* ln1_b  = (const float*)d_in[5];
  const float* wqkv   = (const float*)d_in[6];
  const float* bqkv   = (const float*)d_in[7];
  const float* wo     = (const float*)d_in[8];
  const float* bo     = (const float*)d_in[9];
  const float* rw     = (const float*)d_in[10];
  const float* rb     = (const float*)d_in[11];
  const float* w1     = (const float*)d_in[12];
  const float* b1     = (const float*)d_in[13];
  const float* w2     = (const float*)d_in[14];
  const float* b2     = (const float*)d_in[15];
  const float* ln2_g  = (const float*)d_in[16];
  const float* ln2_b  = (const float*)d_in[17];
  const float* hw     = (const float*)d_in[18];
  const float* hb     = (const float*)d_in[19];
  float* out = (float*)d_out;

  const int T = T_TOK, E = 256, HID = 1024;
  char* ws = (char*)d_ws;
  size_t off = 0;
  auto alloc = [&](size_t bytes) -> void* {
    void* p = ws + off;
    off += (bytes + 255) & ~(size_t)255;
    return p;
  };
  // region 0: Aph+Apl+tok == exactly [2T,1024] bf16 -> reused as expert h buffer
  u16*   Aph    = (u16*)  alloc((size_t)T * 768 * 2);
  u16*   Apl    = (u16*)  alloc((size_t)T * 768 * 2);
  float* tok    = (float*)alloc((size_t)T * 256 * 4);
  u16*   xnh    = (u16*)  alloc((size_t)T * 256 * 2);
  u16*   xnl    = (u16*)  alloc((size_t)T * 256 * 2);
  u16*   qkvb   = (u16*)  alloc((size_t)T * 768 * 2);   // bf16 hi only; reused by x2
  u16*   aoh    = (u16*)  alloc((size_t)T * 256 * 2);
  u16*   aol    = (u16*)  alloc((size_t)T * 256 * 2);
  float* x1f    = (float*)alloc((size_t)T * 256 * 4);   // reused by moe accum
  u16*   x1h    = (u16*)  alloc((size_t)T * 256 * 2);
  u16*   x1l    = (u16*)  alloc((size_t)T * 256 * 2);
  float* gates  = (float*)alloc((size_t)T * 6 * 4);
  int*   idx    = (int*)  alloc((size_t)6 * T * 4);
  int*   cnt    = (int*)  alloc(256);
  int*   base   = (int*)  alloc(256);
  float* pooled = (float*)alloc((size_t)128 * 256 * 4);
  u16*   cwh    = (u16*)  alloc((size_t)196608 * 2);
  u16*   cwl    = (u16*)  alloc((size_t)196608 * 2);
  u16*   wqh    = (u16*)  alloc((size_t)196608 * 2);
  u16*   wql    = (u16*)  alloc((size_t)196608 * 2);
  u16*   woh    = (u16*)  alloc((size_t)65536 * 2);
  u16*   wol    = (u16*)  alloc((size_t)65536 * 2);
  u16*   w1th   = (u16*)  alloc((size_t)6 * 262144 * 2);
  u16*   w1tl   = (u16*)  alloc((size_t)6 * 262144 * 2);
  u16*   w2th   = (u16*)  alloc((size_t)6 * 262144 * 2);
  u16*   w2tl   = (u16*)  alloc((size_t)6 * 262144 * 2);
  // aliases (lifetimes disjoint):
  u16*   hbuf = (u16*)ws;                         // [2T,1024] bf16 expert h (over Aph/Apl/tok)
  float* x2   = (float*)qkvb;                     // [T,256] f32
  float* moe  = x1f;                              // [T,256] f32 accumulator

  // --- weight prep ---
  cast_split_kernel<<<192, 256, 0, stream>>>(conv_w, cwh, cwl, 49152);
  cast_split_kernel<<<192, 256, 0, stream>>>(wqkv, wqh, wql, 49152);
  cast_split_kernel<<<64, 256, 0, stream>>>(wo, woh, wol, 16384);
  transpose_split<<<dim3(32, 8, 6), 256, 0, stream>>>(w1, w1th, w1tl, 256, 1024);  // [e][n][k]
  transpose_split<<<dim3(8, 32, 6), 256, 0, stream>>>(w2, w2th, w2tl, 1024, 256);  // [e][n][k]

  // --- patch embedding ---
  im2col_split<<<18816, 256, 0, stream>>>(x, Aph, Apl);
  gemm_split<1, 0, true><<<dim3(196, 2), 256, 0, stream>>>(Aph, Apl, cwh, cwl, T, 256, 768,
      conv_b, pos, tok, nullptr, nullptr, nullptr, nullptr, nullptr, 0, 0);

  // --- attention block ---
  ln_kernel<true><<<6272, 256, 0, stream>>>(tok, ln1_g, ln1_b, xnh, xnl, nullptr);
  gemm_split<5, 0, true><<<dim3(196, 6), 256, 0, stream>>>(xnh, xnl, wqh, wql, T, 768, 256,
      bqkv, nullptr, nullptr, qkvb, nullptr, nullptr, nullptr, nullptr, 0, 0);
  attn_mfma<<<1024, 256, 0, stream>>>(qkvb, aoh, aol);
  gemm_split<2, 0, true><<<dim3(196, 2), 256, 0, stream>>>(aoh, aol, woh, wol, T, 256, 256,
      bo, tok, x1f, x1h, x1l, nullptr, nullptr, nullptr, 0, 0);

  // --- MoE (top-2 sparse, all experts batched in one dispatch via grid.z) ---
  router_kernel<<<6272, 256, 0, stream>>>(x1f, rw, rb, gates);
  hipMemsetAsync(cnt, 0, 256, stream);
  scatter_kernel<<<98, 256, 0, stream>>>(gates, cnt, idx);
  prefix6_kernel<<<1, 64, 0, stream>>>(cnt, base);
  hipMemsetAsync(moe, 0, (size_t)T * 256 * 4, stream);   // x1f dead after router
  gemm_split<3, 1, true><<<dim3(196, 8, 6), 256, 0, stream>>>(x1h, x1l, w1th, w1tl,
      T, 1024, 256, b1, nullptr, nullptr, hbuf, nullptr, idx, cnt, base, (size_t)262144, 1024);
  gemm_split<4, 2, false><<<dim3(196, 2, 6), 256, 0, stream>>>(hbuf, nullptr, w2th, w2tl,
      T, 256, 1024, b2, gates, moe, nullptr, nullptr, idx, cnt, base, (size_t)262144, 256);

  // --- final norm, pool, head ---
  ln_kernel<false><<<6272, 256, 0, stream>>>(moe, ln2_g, ln2_b, nullptr, nullptr, x2);
  pool_kernel<<<128, 256, 0, stream>>>(x2, pooled);
  head_kernel<<<128, 256, 0, stream>>>(pooled, hw, hb, out);
}

// Round 5
// 607.874 us; speedup vs baseline: 2.2903x; 1.0170x over previous
//
#include <hip/hip_runtime.h>
#include <hip/hip_bf16.h>

typedef unsigned short u16;
typedef short short8 __attribute__((ext_vector_type(8)));
typedef float f32x4 __attribute__((ext_vector_type(4)));

#define T_TOK 25088   // 128*196
#define NTOK 196

__device__ __forceinline__ u16 bfbits(float v) {
  __hip_bfloat16 h = __float2bfloat16(v);
  return *reinterpret_cast<u16*>(&h);
}
__device__ __forceinline__ float b2f(u16 u) {
  __hip_bfloat16 h = *reinterpret_cast<__hip_bfloat16*>(&u);
  return __bfloat162float(h);
}
// near-fp32 as hi+lo bf16 pair (Ootomo split)
__device__ __forceinline__ void fsplit(float v, u16& hi, u16& lo) {
  hi = bfbits(v);
  lo = bfbits(v - b2f(hi));
}

// ---------------------------------------------------------------------------
// Split-bf16 MFMA GEMM, reg-staged pipelined k-loop (issue k+1 loads before
// computing k; ds_write after barrier).  C[M,N] = A[M,K] @ (Bh+Bl)[N,K]^T + bias
// A split (3 MFMA) when SPLITA, else bf16-only (2 MFMA).
// 128x128 tile, BK=32, 256 threads (4 waves 2x2).
// EPI: 1 +pos->f32 | 2 +resid->f32+split | 3 gelu->bf16(h-seg) | 4 gate->slot | 5 ->bf16
// MODE: 0 dense | 1 expert-gather A rows via idx (z=expert) | 2 expert h-seg A, slot out
// ---------------------------------------------------------------------------
template<int EPI, int MODE, bool SPLITA>
__global__ __launch_bounds__(256) void gemm_split(
    const u16* __restrict__ Ah, const u16* __restrict__ Al,
    const u16* __restrict__ Bh, const u16* __restrict__ Bl,
    int M, int N, int K,
    const float* __restrict__ bias, const float* __restrict__ extra,
    float* __restrict__ outf, u16* __restrict__ obh, u16* __restrict__ obl,
    const int* __restrict__ idx_all, const int* __restrict__ cnt_all,
    const int* __restrict__ base_all, size_t wstride, int bstride)
{
  int Meff = M, hbase = 0;
  const int* gidx = idx_all;
  if constexpr (MODE != 0) {
    const int e = blockIdx.z;
    Meff = cnt_all[e];
    if ((int)blockIdx.x * 128 >= Meff) return;
    gidx = idx_all + (size_t)e * T_TOK;
    hbase = base_all[e];
    Bh += (size_t)e * wstride;
    Bl += (size_t)e * wstride;
    bias += (size_t)e * bstride;
  }
  __shared__ u16 Ash[128][40];
  __shared__ u16 Asl[SPLITA ? 128 : 1][40];
  __shared__ u16 Bsh[128][40], Bsl[128][40];
  const int tid = threadIdx.x;
  const int lane = tid & 63, wave = tid >> 6;
  const int wm = wave >> 1, wn = wave & 1;
  const int row0 = blockIdx.x * 128, col0 = blockIdx.y * 128;

  // staging row assignment (fixed across k-loop)
  const int r0 = tid >> 2, r1 = r0 + 64, co = (tid & 3) * 8;
  int ar0, ar1;
  if constexpr (MODE == 1) {
    ar0 = gidx[min(row0 + r0, Meff - 1)];
    ar1 = gidx[min(row0 + r1, Meff - 1)];
  } else if constexpr (MODE == 2) {
    ar0 = hbase + min(row0 + r0, Meff - 1);
    ar1 = hbase + min(row0 + r1, Meff - 1);
  } else {
    ar0 = row0 + r0; ar1 = row0 + r1;
  }

  f32x4 acc[4][4];
  const f32x4 zero = {0.f, 0.f, 0.f, 0.f};
#pragma unroll
  for (int i = 0; i < 4; ++i)
#pragma unroll
    for (int j = 0; j < 4; ++j) acc[i][j] = zero;

  const int rsel = lane & 15, ksel = (lane >> 4) * 8;

  // pipeline registers
  short8 ra0, ra1, rl0, rl1, rb0, rb1, rc0, rc1;
  auto issue = [&](int k0) {
    ra0 = *(const short8*)(Ah + (size_t)ar0 * K + k0 + co);
    ra1 = *(const short8*)(Ah + (size_t)ar1 * K + k0 + co);
    if constexpr (SPLITA) {
      rl0 = *(const short8*)(Al + (size_t)ar0 * K + k0 + co);
      rl1 = *(const short8*)(Al + (size_t)ar1 * K + k0 + co);
    }
    rb0 = *(const short8*)(Bh + (size_t)(col0 + r0) * K + k0 + co);
    rb1 = *(const short8*)(Bh + (size_t)(col0 + r1) * K + k0 + co);
    rc0 = *(const short8*)(Bl + (size_t)(col0 + r0) * K + k0 + co);
    rc1 = *(const short8*)(Bl + (size_t)(col0 + r1) * K + k0 + co);
  };
  auto commit = [&]() {
    *(short8*)&Ash[r0][co] = ra0;
    *(short8*)&Ash[r1][co] = ra1;
    if constexpr (SPLITA) {
      *(short8*)&Asl[r0][co] = rl0;
      *(short8*)&Asl[r1][co] = rl1;
    }
    *(short8*)&Bsh[r0][co] = rb0;
    *(short8*)&Bsh[r1][co] = rb1;
    *(short8*)&Bsl[r0][co] = rc0;
    *(short8*)&Bsl[r1][co] = rc1;
  };

  issue(0);
  commit();
  __syncthreads();

  for (int k0 = 0;;) {
    const bool more = (k0 + 32 < K);
    if (more) issue(k0 + 32);      // loads for next step overlap this step's MFMAs
    short8 ah[4], al[4], bh[4], bl[4];
#pragma unroll
    for (int i = 0; i < 4; ++i) {
      ah[i] = *(const short8*)&Ash[wm * 64 + i * 16 + rsel][ksel];
      if constexpr (SPLITA) al[i] = *(const short8*)&Asl[wm * 64 + i * 16 + rsel][ksel];
    }
#pragma unroll
    for (int j = 0; j < 4; ++j) {
      bh[j] = *(const short8*)&Bsh[wn * 64 + j * 16 + rsel][ksel];
      bl[j] = *(const short8*)&Bsl[wn * 64 + j * 16 + rsel][ksel];
    }
#pragma unroll
    for (int i = 0; i < 4; ++i)
#pragma unroll
      for (int j = 0; j < 4; ++j) {
        acc[i][j] = __builtin_amdgcn_mfma_f32_16x16x32_bf16(ah[i], bh[j], acc[i][j], 0, 0, 0);
        if constexpr (SPLITA)
          acc[i][j] = __builtin_amdgcn_mfma_f32_16x16x32_bf16(al[i], bh[j], acc[i][j], 0, 0, 0);
        acc[i][j] = __builtin_amdgcn_mfma_f32_16x16x32_bf16(ah[i], bl[j], acc[i][j], 0, 0, 0);
      }
    k0 += 32;
    if (!more) break;
    __syncthreads();   // all waves done reading LDS for step k
    commit();          // write prefetched step k+1 (compiler inserts vmcnt)
    __syncthreads();
  }

#pragma unroll
  for (int i = 0; i < 4; ++i) {
#pragma unroll
    for (int j = 0; j < 4; ++j) {
#pragma unroll
      for (int r = 0; r < 4; ++r) {
        int grow = row0 + wm * 64 + i * 16 + (lane >> 4) * 4 + r;   // token / row
        int gcol = col0 + wn * 64 + j * 16 + (lane & 15);           // feature
        float v = acc[i][j][r] + bias[gcol];
        size_t oi = (size_t)grow * N + gcol;
        if constexpr (EPI == 1) {
          v += extra[(size_t)(grow % NTOK) * N + gcol];   // pos_embed
          outf[oi] = v;
        } else if constexpr (EPI == 2) {
          v += extra[oi];                                  // residual
          outf[oi] = v;
          u16 h, l; fsplit(v, h, l); obh[oi] = h; obl[oi] = l;
        } else if constexpr (EPI == 3) {
          if (grow < Meff) {
            float g = 0.5f * v * (1.f + erff(v * 0.70710678118654752f));
            obh[(size_t)(hbase + grow) * N + gcol] = bfbits(g);
          }
        } else if constexpr (EPI == 4) {
          if (grow < Meff) {
            int tk = gidx[grow];
            outf[(size_t)(hbase + grow) * N + gcol] =
                extra[(size_t)tk * 6 + blockIdx.z] * v;    // gate * y -> slot buffer
          }
        } else if constexpr (EPI == 5) {
          obh[oi] = bfbits(v);
        }
      }
    }
  }
}

// ---------------------------------------------------------------------------
// im2col + split: x[B,3,224,224] f32 -> A_patch hi/lo [T,768]
// ---------------------------------------------------------------------------
__global__ void im2col_split(const float* __restrict__ x,
                             u16* __restrict__ Aph, u16* __restrict__ Apl) {
  int id = blockIdx.x * 256 + threadIdx.x;          // T*192 items of 4 elems
  if (id >= T_TOK * 192) return;
  int t = id / 192, kk = id - t * 192;
  int k4 = kk * 4;
  int c = k4 >> 8, rem = k4 & 255, p = rem >> 4, q = rem & 15;
  int b = t / 196, n = t - b * 196, gh = n / 14, gw = n - gh * 14;
  const float4 v = *(const float4*)(x + ((size_t)(b * 3 + c) * 224 + gh * 16 + p) * 224 + gw * 16 + q);
  u16 h0, l0, h1, l1, h2, l2, h3, l3;
  fsplit(v.x, h0, l0); fsplit(v.y, h1, l1); fsplit(v.z, h2, l2); fsplit(v.w, h3, l3);
  *(ushort4*)(Aph + (size_t)t * 768 + k4) = make_ushort4(h0, h1, h2, h3);
  *(ushort4*)(Apl + (size_t)t * 768 + k4) = make_ushort4(l0, l1, l2, l3);
}

// ---------------------------------------------------------------------------
// LayerNorm over E=256 (split bf16 out) — used after attention-input residual
// ---------------------------------------------------------------------------
__global__ __launch_bounds__(256) void ln_kernel(const float* __restrict__ in,
    const float* __restrict__ g, const float* __restrict__ b,
    u16* __restrict__ oh, u16* __restrict__ ol)
{
  const int lane = threadIdx.x & 63;
  const int t = blockIdx.x * 4 + (threadIdx.x >> 6);
  const float4 v = *(const float4*)(in + (size_t)t * 256 + lane * 4);
  float s = v.x + v.y + v.z + v.w;
  float sq = v.x * v.x + v.y * v.y + v.z * v.z + v.w * v.w;
#pragma unroll
  for (int o = 32; o >= 1; o >>= 1) {
    s  += __shfl_xor(s,  o, 64);
    sq += __shfl_xor(sq, o, 64);
  }
  float mu = s * (1.f / 256.f);
  float var = sq * (1.f / 256.f) - mu * mu;
  float rstd = rsqrtf(var + 1e-5f);
  const float4 gv = *(const float4*)(g + lane * 4);
  const float4 bv = *(const float4*)(b + lane * 4);
  float o0 = (v.x - mu) * rstd * gv.x + bv.x;
  float o1 = (v.y - mu) * rstd * gv.y + bv.y;
  float o2 = (v.z - mu) * rstd * gv.z + bv.z;
  float o3 = (v.w - mu) * rstd * gv.w + bv.w;
  u16 h0, l0, h1, l1, h2, l2, h3, l3;
  fsplit(o0, h0, l0); fsplit(o1, h1, l1); fsplit(o2, h2, l2); fsplit(o3, h3, l3);
  *(ushort4*)(oh + (size_t)t * 256 + lane * 4) = make_ushort4(h0, h1, h2, h3);
  *(ushort4*)(ol + (size_t)t * 256 + lane * 4) = make_ushort4(l0, l1, l2, l3);
}

// ---------------------------------------------------------------------------
// Fused slot-combine + LayerNorm: moe[t] = yslot[s0] + yslot[s1]; x2 = LN(moe)
// ---------------------------------------------------------------------------
__global__ __launch_bounds__(256) void ln2_combine(const float* __restrict__ yslot,
    const int* __restrict__ invslot,
    const float* __restrict__ g, const float* __restrict__ b, float* __restrict__ outf)
{
  const int lane = threadIdx.x & 63;
  const int t = blockIdx.x * 4 + (threadIdx.x >> 6);
  const int s0 = invslot[t * 2], s1 = invslot[t * 2 + 1];
  const float4 a = *(const float4*)(yslot + (size_t)s0 * 256 + lane * 4);
  const float4 c = *(const float4*)(yslot + (size_t)s1 * 256 + lane * 4);
  float4 v = make_float4(a.x + c.x, a.y + c.y, a.z + c.z, a.w + c.w);
  float s = v.x + v.y + v.z + v.w;
  float sq = v.x * v.x + v.y * v.y + v.z * v.z + v.w * v.w;
#pragma unroll
  for (int o = 32; o >= 1; o >>= 1) {
    s  += __shfl_xor(s,  o, 64);
    sq += __shfl_xor(sq, o, 64);
  }
  float mu = s * (1.f / 256.f);
  float var = sq * (1.f / 256.f) - mu * mu;
  float rstd = rsqrtf(var + 1e-5f);
  const float4 gv = *(const float4*)(g + lane * 4);
  const float4 bv = *(const float4*)(b + lane * 4);
  *(float4*)(outf + (size_t)t * 256 + lane * 4) = make_float4(
      (v.x - mu) * rstd * gv.x + bv.x, (v.y - mu) * rstd * gv.y + bv.y,
      (v.z - mu) * rstd * gv.z + bv.z, (v.w - mu) * rstd * gv.w + bv.w);
}

// ---------------------------------------------------------------------------
// MFMA attention: one block per (b,h), 4 waves, 13 m-tiles of 16 q-rows.
// ---------------------------------------------------------------------------
__global__ __launch_bounds__(256) void attn_mfma(const u16* __restrict__ qkvb,
                                                 u16* __restrict__ aoh, u16* __restrict__ aol) {
  __shared__ u16 Qs[208][40];       // rows 196..207 zero; stride 80B (bank spread)
  __shared__ u16 Ks[208][40];
  __shared__ u16 Vt[32][256];       // V^T, col XOR-swizzled by ((d&7)<<3); keys>=196 zero
  __shared__ u16 Ps[4][16][232];    // per-wave P tile; cols 208..223 zero
  const int tid = threadIdx.x, lane = tid & 63, wave = tid >> 6;
  const int b = blockIdx.x >> 3, h = blockIdx.x & 7;
  const size_t base = (size_t)b * 196 * 768 + h * 32;
  const short8 z8 = {0, 0, 0, 0, 0, 0, 0, 0};

  for (int idx = tid; idx < 832; idx += 256) {        // Q,K: 208 rows x 4 chunks
    int r = idx >> 2, c = (idx & 3) * 8;
    short8 q = z8, k = z8;
    if (r < 196) {
      q = *(const short8*)(qkvb + base + (size_t)r * 768 + c);
      k = *(const short8*)(qkvb + base + (size_t)r * 768 + 256 + c);
    }
    *(short8*)&Qs[r][c] = q;
    *(short8*)&Ks[r][c] = k;
  }
  for (int idx = tid; idx < 32 * 224; idx += 256) {   // V^T with swizzle
    int c = idx & 31, k = idx >> 5;
    u16 v = 0;
    if (k < 196) v = qkvb[base + (size_t)k * 768 + 512 + c];
    Vt[c][k ^ ((c & 7) << 3)] = v;
  }
  {                                                    // P pad cols [208,224) = 0
    int r = lane >> 2, c0 = 208 + (lane & 3) * 4;
    Ps[wave][r][c0] = 0; Ps[wave][r][c0 + 1] = 0; Ps[wave][r][c0 + 2] = 0; Ps[wave][r][c0 + 3] = 0;
  }
  __syncthreads();

  const int rsel = lane & 15, ksel = (lane >> 4) * 8;
  const f32x4 zero = {0.f, 0.f, 0.f, 0.f};

  for (int mt = wave; mt < 13; mt += 4) {
    short8 aq = *(const short8*)&Qs[mt * 16 + rsel][ksel];
    f32x4 sacc[13];
#pragma unroll
    for (int n = 0; n < 13; ++n)
      sacc[n] = __builtin_amdgcn_mfma_f32_16x16x32_bf16(
          aq, *(const short8*)&Ks[n * 16 + rsel][ksel], zero, 0, 0, 0);

#pragma unroll
    for (int r = 0; r < 4; ++r) {
      float mv = -1e30f;
#pragma unroll
      for (int n = 0; n < 13; ++n) {
        float sv = sacc[n][r] * 0.17677669529663687f;   // 1/sqrt(32)
        sacc[n][r] = sv;
        if (n * 16 + rsel < 196) mv = fmaxf(mv, sv);
      }
      mv = fmaxf(mv, __shfl_xor(mv, 1, 64));
      mv = fmaxf(mv, __shfl_xor(mv, 2, 64));
      mv = fmaxf(mv, __shfl_xor(mv, 4, 64));
      mv = fmaxf(mv, __shfl_xor(mv, 8, 64));
      float sm = 0.f;
#pragma unroll
      for (int n = 0; n < 13; ++n) {
        float p = (n * 16 + rsel < 196) ? __expf(sacc[n][r] - mv) : 0.f;
        sacc[n][r] = p;
        sm += p;
      }
      sm += __shfl_xor(sm, 1, 64);
      sm += __shfl_xor(sm, 2, 64);
      sm += __shfl_xor(sm, 4, 64);
      sm += __shfl_xor(sm, 8, 64);
      float inv = 1.f / sm;
      int prow = (lane >> 4) * 4 + r;
#pragma unroll
      for (int n = 0; n < 13; ++n)
        Ps[wave][prow][n * 16 + rsel] = bfbits(sacc[n][r] * inv);
    }

    f32x4 oacc[2] = {zero, zero};
#pragma unroll
    for (int kk = 0; kk < 7; ++kk) {
      short8 ap = *(const short8*)&Ps[wave][rsel][kk * 32 + ksel];
#pragma unroll
      for (int nt = 0; nt < 2; ++nt) {
        int d = nt * 16 + rsel;
        short8 bv = *(const short8*)&Vt[d][(kk * 32 + ksel) ^ ((d & 7) << 3)];
        oacc[nt] = __builtin_amdgcn_mfma_f32_16x16x32_bf16(ap, bv, oacc[nt], 0, 0, 0);
      }
    }
#pragma unroll
    for (int nt = 0; nt < 2; ++nt) {
#pragma unroll
      for (int r = 0; r < 4; ++r) {
        int row = mt * 16 + (lane >> 4) * 4 + r;
        if (row < 196) {
          size_t oi = ((size_t)b * 196 + row) * 256 + h * 32 + nt * 16 + rsel;
          u16 hh, ll; fsplit(oacc[nt][r], hh, ll);
          aoh[oi] = hh; aol[oi] = ll;
        }
      }
    }
  }
}

// ---------------------------------------------------------------------------
// Router: wave per token; 6 logits, softmax, top-2 -> dense gates [T,6]
// ---------------------------------------------------------------------------
__global__ __launch_bounds__(256) void router_kernel(const float* __restrict__ x1,
    const float* __restrict__ rw, const float* __restrict__ rb, float* __restrict__ gates)
{
  const int lane = threadIdx.x & 63;
  const int t = blockIdx.x * 4 + (threadIdx.x >> 6);
  const float4 xv = *(const float4*)(x1 + (size_t)t * 256 + lane * 4);
  float logit[6];
#pragma unroll
  for (int e = 0; e < 6; ++e) {
    const float4 wv = *(const float4*)(rw + e * 256 + lane * 4);
    float p = xv.x * wv.x + xv.y * wv.y + xv.z * wv.z + xv.w * wv.w;
#pragma unroll
    for (int o = 32; o >= 1; o >>= 1) p += __shfl_xor(p, o, 64);
    logit[e] = p + rb[e];
  }
  float mx = logit[0];
#pragma unroll
  for (int e = 1; e < 6; ++e) mx = fmaxf(mx, logit[e]);
  float pe[6], sum = 0.f;
#pragma unroll
  for (int e = 0; e < 6; ++e) { pe[e] = __expf(logit[e] - mx); sum += pe[e]; }
  float inv = 1.f / sum;
  int i1 = 0; float p1 = pe[0];
#pragma unroll
  for (int e = 1; e < 6; ++e) if (pe[e] > p1) { p1 = pe[e]; i1 = e; }
  int i2 = -1; float p2 = -1.f;
#pragma unroll
  for (int e = 0; e < 6; ++e) if (e != i1 && pe[e] > p2) { p2 = pe[e]; i2 = e; }
  if (lane < 6)
    gates[(size_t)t * 6 + lane] = (lane == i1) ? p1 * inv : ((lane == i2) ? p2 * inv : 0.f);
}

// ---------------------------------------------------------------------------
// Scatter: build per-expert token lists (block-aggregated atomics)
// ---------------------------------------------------------------------------
__global__ __launch_bounds__(256) void scatter_kernel(const float* __restrict__ gates,
                                                      int* __restrict__ cnt, int* __restrict__ idx) {
  __shared__ int lcnt[6], lbase[6];
  const int t = blockIdx.x * 256 + threadIdx.x;
  if (threadIdx.x < 6) lcnt[threadIdx.x] = 0;
  __syncthreads();
  float g[6]; int lpos[6];
#pragma unroll
  for (int e = 0; e < 6; ++e) {
    g[e] = gates[(size_t)t * 6 + e];
    if (g[e] > 0.f) lpos[e] = atomicAdd(&lcnt[e], 1);
  }
  __syncthreads();
  if (threadIdx.x < 6) lbase[threadIdx.x] = atomicAdd(&cnt[threadIdx.x], lcnt[threadIdx.x]);
  __syncthreads();
#pragma unroll
  for (int e = 0; e < 6; ++e)
    if (g[e] > 0.f) idx[(size_t)e * T_TOK + lbase[e] + lpos[e]] = t;
}

// exclusive prefix over the 6 expert counts -> segment bases in h/slot buffer
__global__ void prefix6_kernel(const int* __restrict__ cnt, int* __restrict__ base) {
  if (threadIdx.x == 0) {
    int s = 0;
#pragma unroll
    for (int e = 0; e < 6; ++e) { base[e] = s; s += cnt[e]; }
  }
}

// token -> its 2 slot positions in the concatenated expert segments
__global__ __launch_bounds__(256) void slotmap_kernel(const int* __restrict__ idx,
    const int* __restrict__ cnt, const int* __restrict__ base,
    int* __restrict__ nslot, int* __restrict__ invslot) {
  const int e = blockIdx.y;
  const int p = blockIdx.x * 256 + threadIdx.x;
  if (p < cnt[e]) {
    int t = idx[(size_t)e * T_TOK + p];
    int j = atomicAdd(&nslot[t], 1);
    invslot[(size_t)t * 2 + j] = base[e] + p;
  }
}

// ---------------------------------------------------------------------------
// Mean-pool over tokens, then classifier head (fp32)
// ---------------------------------------------------------------------------
__global__ __launch_bounds__(256) void pool_kernel(const float* __restrict__ x2, float* __restrict__ pooled) {
  int b = blockIdx.x, e = threadIdx.x;
  float s = 0.f;
  for (int n = 0; n < 196; ++n) s += x2[((size_t)b * 196 + n) * 256 + e];
  pooled[(size_t)b * 256 + e] = s * (1.f / 196.f);
}

__global__ __launch_bounds__(256) void head_kernel(const float* __restrict__ pooled,
    const float* __restrict__ hw, const float* __restrict__ hb, float* __restrict__ out) {
  __shared__ float p[256];
  int b = blockIdx.x;
  p[threadIdx.x] = pooled[(size_t)b * 256 + threadIdx.x];
  __syncthreads();
  for (int cls = threadIdx.x; cls < 1000; cls += 256) {
    const float* w = hw + (size_t)cls * 256;
    float s = hb[cls];
    for (int k = 0; k < 256; k += 4)
      s += p[k] * w[k] + p[k + 1] * w[k + 1] + p[k + 2] * w[k + 2] + p[k + 3] * w[k + 3];
    out[(size_t)b * 1000 + cls] = s;
  }
}

// ---------------------------------------------------------------------------
// Weight prep: f32 -> hi/lo bf16; batched transpose+split ([R,C] -> [C,R])
// ---------------------------------------------------------------------------
__global__ void cast_split_kernel(const float* __restrict__ in,
                                  u16* __restrict__ oh, u16* __restrict__ ol, int n4) {
  int id = blockIdx.x * 256 + threadIdx.x;
  if (id >= n4) return;
  float4 v = ((const float4*)in)[id];
  u16 h0, l0, h1, l1, h2, l2, h3, l3;
  fsplit(v.x, h0, l0); fsplit(v.y, h1, l1); fsplit(v.z, h2, l2); fsplit(v.w, h3, l3);
  ((ushort4*)oh)[id] = make_ushort4(h0, h1, h2, h3);
  ((ushort4*)ol)[id] = make_ushort4(l0, l1, l2, l3);
}

__global__ __launch_bounds__(256) void transpose_split(const float* __restrict__ in,
    u16* __restrict__ oh, u16* __restrict__ ol, int R, int C) {
  __shared__ float tile[32][33];
  const int e = blockIdx.z;
  const int bc = blockIdx.x * 32, br = blockIdx.y * 32;
  const int tx = threadIdx.x & 31, ty = threadIdx.x >> 5;
  const float* src = in + (size_t)e * R * C;
#pragma unroll
  for (int i = 0; i < 32; i += 8)
    tile[ty + i][tx] = src[(size_t)(br + ty + i) * C + bc + tx];
  __syncthreads();
#pragma unroll
  for (int i = 0; i < 32; i += 8) {
    float v = tile[tx][ty + i];
    u16 h, l; fsplit(v, h, l);
    size_t di = (size_t)e * R * C + (size_t)(bc + ty + i) * R + br + tx;
    oh[di] = h; ol[di] = l;
  }
}

// ---------------------------------------------------------------------------
extern "C" void kernel_launch(void* const* d_in, const int* in_sizes, int n_in,
                              void* d_out, int out_size, void* d_ws, size_t ws_size,
                              hipStream_t stream) {
  (void)in_sizes; (void)n_in; (void)out_size; (void)ws_size;
  const float* x      = (const float*)d_in[0];
  const float* conv_w = (const float*)d_in[1];
  const float* conv_b = (const float*)d_in[2];
  const float* pos    = (const float*)d_in[3];
  const float* ln1_g  = (const float*)d_in[4];
  const float* ln1_b  = (const float*)d_in[5];
  const float* wqkv   = (const float*)d_in[6];
  const float* bqkv   = (const float*)d_in[7];
  const float* wo     = (const float*)d_in[8];
  const float* bo     = (const float*)d_in[9];
  const float* rw     = (const float*)d_in[10];
  const float* rb     = (const float*)d_in[11];
  const float* w1     = (const float*)d_in[12];
  const float* b1     = (const float*)d_in[13];
  const float* w2     = (const float*)d_in[14];
  const float* b2     = (const float*)d_in[15];
  const float* ln2_g  = (const float*)d_in[16];
  const float* ln2_b  = (const float*)d_in[17];
  const float* hw     = (const float*)d_in[18];
  const float* hb     = (const float*)d_in[19];
  float* out = (float*)d_out;

  const int T = T_TOK, E = 256, HID = 1024;
  char* ws = (char*)d_ws;
  size_t off = 0;
  auto alloc = [&](size_t bytes) -> void* {
    void* p = ws + off;
    off += (bytes + 255) & ~(size_t)255;
    return p;
  };
  // region 0: Aph+Apl+tok == exactly [2T,1024] bf16 -> reused as expert h buffer
  u16*   Aph    = (u16*)  alloc((size_t)T * 768 * 2);
  u16*   Apl    = (u16*)  alloc((size_t)T * 768 * 2);
  float* tok    = (float*)alloc((size_t)T * 256 * 4);
  u16*   xnh    = (u16*)  alloc((size_t)T * 256 * 2);
  u16*   xnl    = (u16*)  alloc((size_t)T * 256 * 2);
  u16*   qkvb   = (u16*)  alloc((size_t)T * 768 * 2);   // bf16 hi only; reused by x2
  // region 1: aoh+aol+x1f == exactly [2T,256] f32 -> reused as yslot buffer
  u16*   aoh    = (u16*)  alloc((size_t)T * 256 * 2);
  u16*   aol    = (u16*)  alloc((size_t)T * 256 * 2);
  float* x1f    = (float*)alloc((size_t)T * 256 * 4);
  u16*   x1h    = (u16*)  alloc((size_t)T * 256 * 2);
  u16*   x1l    = (u16*)  alloc((size_t)T * 256 * 2);
  float* gates  = (float*)alloc((size_t)T * 6 * 4);
  int*   idx    = (int*)  alloc((size_t)6 * T * 4);
  int*   cnt    = (int*)  alloc(256);
  int*   base   = (int*)  alloc(256);
  int*   nslot  = (int*)  alloc((size_t)T * 4);
  int*   invslot= (int*)  alloc((size_t)2 * T * 4);
  float* pooled = (float*)alloc((size_t)128 * 256 * 4);
  u16*   cwh    = (u16*)  alloc((size_t)196608 * 2);
  u16*   cwl    = (u16*)  alloc((size_t)196608 * 2);
  u16*   wqh    = (u16*)  alloc((size_t)196608 * 2);
  u16*   wql    = (u16*)  alloc((size_t)196608 * 2);
  u16*   woh    = (u16*)  alloc((size_t)65536 * 2);
  u16*   wol    = (u16*)  alloc((size_t)65536 * 2);
  u16*   w1th   = (u16*)  alloc((size_t)6 * 262144 * 2);
  u16*   w1tl   = (u16*)  alloc((size_t)6 * 262144 * 2);
  u16*   w2th   = (u16*)  alloc((size_t)6 * 262144 * 2);
  u16*   w2tl   = (u16*)  alloc((size_t)6 * 262144 * 2);
  // aliases (lifetimes disjoint):
  u16*   hbuf  = (u16*)ws;                        // [2T,1024] bf16 expert h (over Aph/Apl/tok)
  float* x2    = (float*)qkvb;                    // [T,256] f32
  float* yslot = (float*)aoh;                     // [2T,256] f32 (over aoh/aol/x1f)

  // --- weight prep ---
  cast_split_kernel<<<192, 256, 0, stream>>>(conv_w, cwh, cwl, 49152);
  cast_split_kernel<<<192, 256, 0, stream>>>(wqkv, wqh, wql, 49152);
  cast_split_kernel<<<64, 256, 0, stream>>>(wo, woh, wol, 16384);
  transpose_split<<<dim3(32, 8, 6), 256, 0, stream>>>(w1, w1th, w1tl, 256, 1024);  // [e][n][k]
  transpose_split<<<dim3(8, 32, 6), 256, 0, stream>>>(w2, w2th, w2tl, 1024, 256);  // [e][n][k]

  // --- patch embedding ---
  im2col_split<<<18816, 256, 0, stream>>>(x, Aph, Apl);
  gemm_split<1, 0, true><<<dim3(196, 2), 256, 0, stream>>>(Aph, Apl, cwh, cwl, T, 256, 768,
      conv_b, pos, tok, nullptr, nullptr, nullptr, nullptr, nullptr, 0, 0);

  // --- attention block ---
  ln_kernel<<<6272, 256, 0, stream>>>(tok, ln1_g, ln1_b, xnh, xnl);
  gemm_split<5, 0, true><<<dim3(196, 6), 256, 0, stream>>>(xnh, xnl, wqh, wql, T, 768, 256,
      bqkv, nullptr, nullptr, qkvb, nullptr, nullptr, nullptr, nullptr, 0, 0);
  attn_mfma<<<1024, 256, 0, stream>>>(qkvb, aoh, aol);
  gemm_split<2, 0, true><<<dim3(196, 2), 256, 0, stream>>>(aoh, aol, woh, wol, T, 256, 256,
      bo, tok, x1f, x1h, x1l, nullptr, nullptr, nullptr, 0, 0);

  // --- MoE (top-2 sparse, experts batched via grid.z, atomic-free slot combine) ---
  router_kernel<<<6272, 256, 0, stream>>>(x1f, rw, rb, gates);
  hipMemsetAsync(cnt, 0, 256, stream);
  scatter_kernel<<<98, 256, 0, stream>>>(gates, cnt, idx);
  prefix6_kernel<<<1, 64, 0, stream>>>(cnt, base);
  hipMemsetAsync(nslot, 0, (size_t)T * 4, stream);
  slotmap_kernel<<<dim3(98, 6), 256, 0, stream>>>(idx, cnt, base, nslot, invslot);
  gemm_split<3, 1, true><<<dim3(196, 8, 6), 256, 0, stream>>>(x1h, x1l, w1th, w1tl,
      T, 1024, 256, b1, nullptr, nullptr, hbuf, nullptr, idx, cnt, base, (size_t)262144, 1024);
  gemm_split<4, 2, false><<<dim3(196, 2, 6), 256, 0, stream>>>(hbuf, nullptr, w2th, w2tl,
      T, 256, 1024, b2, gates, yslot, nullptr, nullptr, idx, cnt, base, (size_t)262144, 256);

  // --- final norm (fused slot combine), pool, head ---
  ln2_combine<<<6272, 256, 0, stream>>>(yslot, invslot, ln2_g, ln2_b, x2);
  pool_kernel<<<128, 256, 0, stream>>>(x2, pooled);
  head_kernel<<<128, 256, 0, stream>>>(pooled, hw, hb, out);
}

// Round 7
// 578.293 us; speedup vs baseline: 2.4074x; 1.0512x over previous
//
#include <hip/hip_runtime.h>
#include <hip/hip_bf16.h>

typedef unsigned short u16;
typedef short short8 __attribute__((ext_vector_type(8)));
typedef float f32x4 __attribute__((ext_vector_type(4)));

#define T_TOK 25088   // 128*196
#define NTOK 196

__device__ __forceinline__ u16 bfbits(float v) {
  __hip_bfloat16 h = __float2bfloat16(v);
  return *reinterpret_cast<u16*>(&h);
}
__device__ __forceinline__ float b2f(u16 u) {
  __hip_bfloat16 h = *reinterpret_cast<__hip_bfloat16*>(&u);
  return __bfloat162float(h);
}
// near-fp32 as hi+lo bf16 pair (Ootomo split)
__device__ __forceinline__ void fsplit(float v, u16& hi, u16& lo) {
  hi = bfbits(v);
  lo = bfbits(v - b2f(hi));
}

// ---------------------------------------------------------------------------
// GEMM: C[M,N] = A[M,K] @ (Bh+Bl)[N,K]^T + bias.
// A split (Ah+Al, 3 MFMA/frag) when SPLITA — used ONLY on the router-input
// path (patch, wo) where x1f precision controls gate flips; else 2 MFMA.
// 128x128 tile, BK=32, 256 threads (4 waves 2x2), reg-staged 1-deep prefetch.
// EPI: 1 +pos->f32 | 2 +resid->f32+bf16 | 3 gelu->bf16(h-seg) | 4 gate->slot | 5 ->bf16
// MODE: 0 dense | 1 expert-gather A rows via idx (z=expert) | 2 expert h-seg A, slot out
// ---------------------------------------------------------------------------
template<int EPI, int MODE, bool SPLITA>
__global__ __launch_bounds__(256) void gemm_bs(
    const u16* __restrict__ A, const u16* __restrict__ Al,
    const u16* __restrict__ Bh, const u16* __restrict__ Bl,
    int M, int N, int K,
    const float* __restrict__ bias, const float* __restrict__ extra,
    float* __restrict__ outf, u16* __restrict__ obh,
    const int* __restrict__ idx_all, const int* __restrict__ cnt_all,
    const int* __restrict__ base_all, size_t wstride, int bstride)
{
  int Meff = M, hbase = 0;
  const int* gidx = idx_all;
  if constexpr (MODE != 0) {
    const int e = blockIdx.z;
    Meff = cnt_all[e];
    if ((int)blockIdx.x * 128 >= Meff) return;
    gidx = idx_all + (size_t)e * T_TOK;
    hbase = base_all[e];
    Bh += (size_t)e * wstride;
    Bl += (size_t)e * wstride;
    bias += (size_t)e * bstride;
  }
  __shared__ u16 As[128][40];                      // +8 pad: 2-way banks
  __shared__ u16 Asl[SPLITA ? 128 : 1][40];
  __shared__ u16 Bsh[128][40], Bsl[128][40];
  const int tid = threadIdx.x;
  const int lane = tid & 63, wave = tid >> 6;
  const int wm = wave >> 1, wn = wave & 1;
  const int row0 = blockIdx.x * 128, col0 = blockIdx.y * 128;

  // staging row assignment (fixed across k-loop)
  const int r0 = tid >> 2, r1 = r0 + 64, co = (tid & 3) * 8;
  int ar0, ar1;
  if constexpr (MODE == 1) {
    ar0 = gidx[min(row0 + r0, Meff - 1)];
    ar1 = gidx[min(row0 + r1, Meff - 1)];
  } else if constexpr (MODE == 2) {
    ar0 = hbase + min(row0 + r0, Meff - 1);
    ar1 = hbase + min(row0 + r1, Meff - 1);
  } else {
    ar0 = row0 + r0; ar1 = row0 + r1;
  }

  f32x4 acc[4][4];
  const f32x4 zero = {0.f, 0.f, 0.f, 0.f};
#pragma unroll
  for (int i = 0; i < 4; ++i)
#pragma unroll
    for (int j = 0; j < 4; ++j) acc[i][j] = zero;

  const int rsel = lane & 15, ksel = (lane >> 4) * 8;

  // pipeline registers (1-deep prefetch)
  short8 ra0, ra1, rl0, rl1, rb0, rb1, rc0, rc1;
  auto issue = [&](int k0) {
    ra0 = *(const short8*)(A + (size_t)ar0 * K + k0 + co);
    ra1 = *(const short8*)(A + (size_t)ar1 * K + k0 + co);
    if constexpr (SPLITA) {
      rl0 = *(const short8*)(Al + (size_t)ar0 * K + k0 + co);
      rl1 = *(const short8*)(Al + (size_t)ar1 * K + k0 + co);
    }
    rb0 = *(const short8*)(Bh + (size_t)(col0 + r0) * K + k0 + co);
    rb1 = *(const short8*)(Bh + (size_t)(col0 + r1) * K + k0 + co);
    rc0 = *(const short8*)(Bl + (size_t)(col0 + r0) * K + k0 + co);
    rc1 = *(const short8*)(Bl + (size_t)(col0 + r1) * K + k0 + co);
  };
  auto commit = [&]() {
    *(short8*)&As[r0][co] = ra0;
    *(short8*)&As[r1][co] = ra1;
    if constexpr (SPLITA) {
      *(short8*)&Asl[r0][co] = rl0;
      *(short8*)&Asl[r1][co] = rl1;
    }
    *(short8*)&Bsh[r0][co] = rb0;
    *(short8*)&Bsh[r1][co] = rb1;
    *(short8*)&Bsl[r0][co] = rc0;
    *(short8*)&Bsl[r1][co] = rc1;
  };

  issue(0);
  commit();
  __syncthreads();

  for (int k0 = 0;;) {
    const bool more = (k0 + 32 < K);
    if (more) issue(k0 + 32);      // next-step loads overlap this step's MFMAs
    short8 af[4], al4[4], bh4[4], bl4[4];
#pragma unroll
    for (int i = 0; i < 4; ++i) {
      af[i] = *(const short8*)&As[wm * 64 + i * 16 + rsel][ksel];
      if constexpr (SPLITA) al4[i] = *(const short8*)&Asl[wm * 64 + i * 16 + rsel][ksel];
    }
#pragma unroll
    for (int j = 0; j < 4; ++j) {
      bh4[j] = *(const short8*)&Bsh[wn * 64 + j * 16 + rsel][ksel];
      bl4[j] = *(const short8*)&Bsl[wn * 64 + j * 16 + rsel][ksel];
    }
#pragma unroll
    for (int i = 0; i < 4; ++i)
#pragma unroll
      for (int j = 0; j < 4; ++j) {
        acc[i][j] = __builtin_amdgcn_mfma_f32_16x16x32_bf16(af[i], bh4[j], acc[i][j], 0, 0, 0);
        if constexpr (SPLITA)
          acc[i][j] = __builtin_amdgcn_mfma_f32_16x16x32_bf16(al4[i], bh4[j], acc[i][j], 0, 0, 0);
        acc[i][j] = __builtin_amdgcn_mfma_f32_16x16x32_bf16(af[i], bl4[j], acc[i][j], 0, 0, 0);
      }
    k0 += 32;
    if (!more) break;
    __syncthreads();
    commit();
    __syncthreads();
  }

#pragma unroll
  for (int i = 0; i < 4; ++i) {
#pragma unroll
    for (int j = 0; j < 4; ++j) {
#pragma unroll
      for (int r = 0; r < 4; ++r) {
        int grow = row0 + wm * 64 + i * 16 + (lane >> 4) * 4 + r;   // token / row
        int gcol = col0 + wn * 64 + j * 16 + (lane & 15);           // feature
        float v = acc[i][j][r] + bias[gcol];
        size_t oi = (size_t)grow * N + gcol;
        if constexpr (EPI == 1) {
          v += extra[(size_t)(grow % NTOK) * N + gcol];   // pos_embed
          outf[oi] = v;
        } else if constexpr (EPI == 2) {
          v += extra[oi];                                  // residual
          outf[oi] = v;
          obh[oi] = bfbits(v);
        } else if constexpr (EPI == 3) {
          if (grow < Meff) {
            float g = 0.5f * v * (1.f + erff(v * 0.70710678118654752f));
            obh[(size_t)(hbase + grow) * N + gcol] = bfbits(g);
          }
        } else if constexpr (EPI == 4) {
          if (grow < Meff) {
            int tk = gidx[grow];
            outf[(size_t)(hbase + grow) * N + gcol] =
                extra[(size_t)tk * 6 + blockIdx.z] * v;    // gate * y -> slot buffer
          }
        } else if constexpr (EPI == 5) {
          obh[oi] = bfbits(v);
        }
      }
    }
  }
}

// ---------------------------------------------------------------------------
// im2col + split: x[B,3,224,224] f32 -> A_patch hi/lo [T,768]
// (x feeds the router-input path; its split is required — see r6 post-mortem)
// ---------------------------------------------------------------------------
__global__ void im2col_split(const float* __restrict__ x,
                             u16* __restrict__ Aph, u16* __restrict__ Apl) {
  int id = blockIdx.x * 256 + threadIdx.x;          // T*192 items of 4 elems
  if (id >= T_TOK * 192) return;
  int t = id / 192, kk = id - t * 192;
  int k4 = kk * 4;
  int c = k4 >> 8, rem = k4 & 255, p = rem >> 4, q = rem & 15;
  int b = t / 196, n = t - b * 196, gh = n / 14, gw = n - gh * 14;
  const float4 v = *(const float4*)(x + ((size_t)(b * 3 + c) * 224 + gh * 16 + p) * 224 + gw * 16 + q);
  u16 h0, l0, h1, l1, h2, l2, h3, l3;
  fsplit(v.x, h0, l0); fsplit(v.y, h1, l1); fsplit(v.z, h2, l2); fsplit(v.w, h3, l3);
  *(ushort4*)(Aph + (size_t)t * 768 + k4) = make_ushort4(h0, h1, h2, h3);
  *(ushort4*)(Apl + (size_t)t * 768 + k4) = make_ushort4(l0, l1, l2, l3);
}

// ---------------------------------------------------------------------------
// LayerNorm over E=256: wave per token; bf16 out
// ---------------------------------------------------------------------------
__global__ __launch_bounds__(256) void ln_kernel(const float* __restrict__ in,
    const float* __restrict__ g, const float* __restrict__ b, u16* __restrict__ oh)
{
  const int lane = threadIdx.x & 63;
  const int t = blockIdx.x * 4 + (threadIdx.x >> 6);
  const float4 v = *(const float4*)(in + (size_t)t * 256 + lane * 4);
  float s = v.x + v.y + v.z + v.w;
  float sq = v.x * v.x + v.y * v.y + v.z * v.z + v.w * v.w;
#pragma unroll
  for (int o = 32; o >= 1; o >>= 1) {
    s  += __shfl_xor(s,  o, 64);
    sq += __shfl_xor(sq, o, 64);
  }
  float mu = s * (1.f / 256.f);
  float var = sq * (1.f / 256.f) - mu * mu;
  float rstd = rsqrtf(var + 1e-5f);
  const float4 gv = *(const float4*)(g + lane * 4);
  const float4 bv = *(const float4*)(b + lane * 4);
  *(ushort4*)(oh + (size_t)t * 256 + lane * 4) = make_ushort4(
      bfbits((v.x - mu) * rstd * gv.x + bv.x), bfbits((v.y - mu) * rstd * gv.y + bv.y),
      bfbits((v.z - mu) * rstd * gv.z + bv.z), bfbits((v.w - mu) * rstd * gv.w + bv.w));
}

// ---------------------------------------------------------------------------
// Fused slot-combine + LayerNorm: moe[t] = yslot[s0]+yslot[s1]; x2 = LN(moe)
// ---------------------------------------------------------------------------
__global__ __launch_bounds__(256) void ln2_combine(const float* __restrict__ yslot,
    const int* __restrict__ invslot,
    const float* __restrict__ g, const float* __restrict__ b, float* __restrict__ outf)
{
  const int lane = threadIdx.x & 63;
  const int t = blockIdx.x * 4 + (threadIdx.x >> 6);
  const int s0 = invslot[t * 2], s1 = invslot[t * 2 + 1];
  const float4 a = *(const float4*)(yslot + (size_t)s0 * 256 + lane * 4);
  const float4 c = *(const float4*)(yslot + (size_t)s1 * 256 + lane * 4);
  float4 v = make_float4(a.x + c.x, a.y + c.y, a.z + c.z, a.w + c.w);
  float s = v.x + v.y + v.z + v.w;
  float sq = v.x * v.x + v.y * v.y + v.z * v.z + v.w * v.w;
#pragma unroll
  for (int o = 32; o >= 1; o >>= 1) {
    s  += __shfl_xor(s,  o, 64);
    sq += __shfl_xor(sq, o, 64);
  }
  float mu = s * (1.f / 256.f);
  float var = sq * (1.f / 256.f) - mu * mu;
  float rstd = rsqrtf(var + 1e-5f);
  const float4 gv = *(const float4*)(g + lane * 4);
  const float4 bv = *(const float4*)(b + lane * 4);
  *(float4*)(outf + (size_t)t * 256 + lane * 4) = make_float4(
      (v.x - mu) * rstd * gv.x + bv.x, (v.y - mu) * rstd * gv.y + bv.y,
      (v.z - mu) * rstd * gv.z + bv.z, (v.w - mu) * rstd * gv.w + bv.w);
}

// ---------------------------------------------------------------------------
// MFMA attention: one block per (b,h), 4 waves, 13 m-tiles of 16 q-rows.
// ao is written split (hi+lo): it feeds wo -> x1f -> router (gate precision).
// ---------------------------------------------------------------------------
__global__ __launch_bounds__(256) void attn_mfma(const u16* __restrict__ qkvb,
                                                 u16* __restrict__ aoh, u16* __restrict__ aol) {
  __shared__ u16 Qs[208][40];       // rows 196..207 zero; stride 80B (bank spread)
  __shared__ u16 Ks[208][40];
  __shared__ u16 Vt[32][256];       // V^T, col XOR-swizzled by ((d&7)<<3); keys>=196 zero
  __shared__ u16 Ps[4][16][232];    // per-wave P tile; cols 208..223 zero
  const int tid = threadIdx.x, lane = tid & 63, wave = tid >> 6;
  const int b = blockIdx.x >> 3, h = blockIdx.x & 7;
  const size_t base = (size_t)b * 196 * 768 + h * 32;
  const short8 z8 = {0, 0, 0, 0, 0, 0, 0, 0};

  for (int idx = tid; idx < 832; idx += 256) {        // Q,K: 208 rows x 4 chunks
    int r = idx >> 2, c = (idx & 3) * 8;
    short8 q = z8, k = z8;
    if (r < 196) {
      q = *(const short8*)(qkvb + base + (size_t)r * 768 + c);
      k = *(const short8*)(qkvb + base + (size_t)r * 768 + 256 + c);
    }
    *(short8*)&Qs[r][c] = q;
    *(short8*)&Ks[r][c] = k;
  }
  for (int idx = tid; idx < 32 * 224; idx += 256) {   // V^T with swizzle
    int c = idx & 31, k = idx >> 5;
    u16 v = 0;
    if (k < 196) v = qkvb[base + (size_t)k * 768 + 512 + c];
    Vt[c][k ^ ((c & 7) << 3)] = v;
  }
  {                                                    // P pad cols [208,224) = 0
    int r = lane >> 2, c0 = 208 + (lane & 3) * 4;
    Ps[wave][r][c0] = 0; Ps[wave][r][c0 + 1] = 0; Ps[wave][r][c0 + 2] = 0; Ps[wave][r][c0 + 3] = 0;
  }
  __syncthreads();

  const int rsel = lane & 15, ksel = (lane >> 4) * 8;
  const f32x4 zero = {0.f, 0.f, 0.f, 0.f};

  for (int mt = wave; mt < 13; mt += 4) {
    short8 aq = *(const short8*)&Qs[mt * 16 + rsel][ksel];
    f32x4 sacc[13];
#pragma unroll
    for (int n = 0; n < 13; ++n)
      sacc[n] = __builtin_amdgcn_mfma_f32_16x16x32_bf16(
          aq, *(const short8*)&Ks[n * 16 + rsel][ksel], zero, 0, 0, 0);

#pragma unroll
    for (int r = 0; r < 4; ++r) {
      float mv = -1e30f;
#pragma unroll
      for (int n = 0; n < 13; ++n) {
        float sv = sacc[n][r] * 0.17677669529663687f;   // 1/sqrt(32)
        sacc[n][r] = sv;
        if (n * 16 + rsel < 196) mv = fmaxf(mv, sv);
      }
      mv = fmaxf(mv, __shfl_xor(mv, 1, 64));
      mv = fmaxf(mv, __shfl_xor(mv, 2, 64));
      mv = fmaxf(mv, __shfl_xor(mv, 4, 64));
      mv = fmaxf(mv, __shfl_xor(mv, 8, 64));
      float sm = 0.f;
#pragma unroll
      for (int n = 0; n < 13; ++n) {
        float p = (n * 16 + rsel < 196) ? __expf(sacc[n][r] - mv) : 0.f;
        sacc[n][r] = p;
        sm += p;
      }
      sm += __shfl_xor(sm, 1, 64);
      sm += __shfl_xor(sm, 2, 64);
      sm += __shfl_xor(sm, 4, 64);
      sm += __shfl_xor(sm, 8, 64);
      float inv = 1.f / sm;
      int prow = (lane >> 4) * 4 + r;
#pragma unroll
      for (int n = 0; n < 13; ++n)
        Ps[wave][prow][n * 16 + rsel] = bfbits(sacc[n][r] * inv);
    }

    f32x4 oacc[2] = {zero, zero};
#pragma unroll
    for (int kk = 0; kk < 7; ++kk) {
      short8 ap = *(const short8*)&Ps[wave][rsel][kk * 32 + ksel];
#pragma unroll
      for (int nt = 0; nt < 2; ++nt) {
        int d = nt * 16 + rsel;
        short8 bv = *(const short8*)&Vt[d][(kk * 32 + ksel) ^ ((d & 7) << 3)];
        oacc[nt] = __builtin_amdgcn_mfma_f32_16x16x32_bf16(ap, bv, oacc[nt], 0, 0, 0);
      }
    }
#pragma unroll
    for (int nt = 0; nt < 2; ++nt) {
#pragma unroll
      for (int r = 0; r < 4; ++r) {
        int row = mt * 16 + (lane >> 4) * 4 + r;
        if (row < 196) {
          size_t oi = ((size_t)b * 196 + row) * 256 + h * 32 + nt * 16 + rsel;
          u16 hh, ll; fsplit(oacc[nt][r], hh, ll);
          aoh[oi] = hh; aol[oi] = ll;
        }
      }
    }
  }
}

// ---------------------------------------------------------------------------
// Router: wave per token; 6 logits, softmax, top-2 -> dense gates [T,6]
// ---------------------------------------------------------------------------
__global__ __launch_bounds__(256) void router_kernel(const float* __restrict__ x1,
    const float* __restrict__ rw, const float* __restrict__ rb, float* __restrict__ gates)
{
  const int lane = threadIdx.x & 63;
  const int t = blockIdx.x * 4 + (threadIdx.x >> 6);
  const float4 xv = *(const float4*)(x1 + (size_t)t * 256 + lane * 4);
  float logit[6];
#pragma unroll
  for (int e = 0; e < 6; ++e) {
    const float4 wv = *(const float4*)(rw + e * 256 + lane * 4);
    float p = xv.x * wv.x + xv.y * wv.y + xv.z * wv.z + xv.w * wv.w;
#pragma unroll
    for (int o = 32; o >= 1; o >>= 1) p += __shfl_xor(p, o, 64);
    logit[e] = p + rb[e];
  }
  float mx = logit[0];
#pragma unroll
  for (int e = 1; e < 6; ++e) mx = fmaxf(mx, logit[e]);
  float pe[6], sum = 0.f;
#pragma unroll
  for (int e = 0; e < 6; ++e) { pe[e] = __expf(logit[e] - mx); sum += pe[e]; }
  float inv = 1.f / sum;
  int i1 = 0; float p1 = pe[0];
#pragma unroll
  for (int e = 1; e < 6; ++e) if (pe[e] > p1) { p1 = pe[e]; i1 = e; }
  int i2 = -1; float p2 = -1.f;
#pragma unroll
  for (int e = 0; e < 6; ++e) if (e != i1 && pe[e] > p2) { p2 = pe[e]; i2 = e; }
  if (lane < 6)
    gates[(size_t)t * 6 + lane] = (lane == i1) ? p1 * inv : ((lane == i2) ? p2 * inv : 0.f);
}

// ---------------------------------------------------------------------------
// Scatter: build per-expert token lists (block-aggregated atomics)
// ---------------------------------------------------------------------------
__global__ __launch_bounds__(256) void scatter_kernel(const float* __restrict__ gates,
                                                      int* __restrict__ cnt, int* __restrict__ idx) {
  __shared__ int lcnt[6], lbase[6];
  const int t = blockIdx.x * 256 + threadIdx.x;
  if (threadIdx.x < 6) lcnt[threadIdx.x] = 0;
  __syncthreads();
  float g[6]; int lpos[6];
#pragma unroll
  for (int e = 0; e < 6; ++e) {
    g[e] = gates[(size_t)t * 6 + e];
    if (g[e] > 0.f) lpos[e] = atomicAdd(&lcnt[e], 1);
  }
  __syncthreads();
  if (threadIdx.x < 6) lbase[threadIdx.x] = atomicAdd(&cnt[threadIdx.x], lcnt[threadIdx.x]);
  __syncthreads();
#pragma unroll
  for (int e = 0; e < 6; ++e)
    if (g[e] > 0.f) idx[(size_t)e * T_TOK + lbase[e] + lpos[e]] = t;
}

// exclusive prefix over the 6 expert counts -> segment bases in h/slot buffer
__global__ void prefix6_kernel(const int* __restrict__ cnt, int* __restrict__ base) {
  if (threadIdx.x == 0) {
    int s = 0;
#pragma unroll
    for (int e = 0; e < 6; ++e) { base[e] = s; s += cnt[e]; }
  }
}

// token -> its 2 slot positions in the concatenated expert segments
__global__ __launch_bounds__(256) void slotmap_kernel(const int* __restrict__ idx,
    const int* __restrict__ cnt, const int* __restrict__ base,
    int* __restrict__ nslot, int* __restrict__ invslot) {
  const int e = blockIdx.y;
  const int p = blockIdx.x * 256 + threadIdx.x;
  if (p < cnt[e]) {
    int t = idx[(size_t)e * T_TOK + p];
    int j = atomicAdd(&nslot[t], 1);
    invslot[(size_t)t * 2 + j] = base[e] + p;
  }
}

// ---------------------------------------------------------------------------
// Mean-pool over tokens, then classifier head (fp32)
// ---------------------------------------------------------------------------
__global__ __launch_bounds__(256) void pool_kernel(const float* __restrict__ x2, float* __restrict__ pooled) {
  int b = blockIdx.x, e = threadIdx.x;
  float s = 0.f;
  for (int n = 0; n < 196; ++n) s += x2[((size_t)b * 196 + n) * 256 + e];
  pooled[(size_t)b * 256 + e] = s * (1.f / 196.f);
}

__global__ __launch_bounds__(256) void head_kernel(const float* __restrict__ pooled,
    const float* __restrict__ hw, const float* __restrict__ hb, float* __restrict__ out) {
  __shared__ float p[256];
  int b = blockIdx.x;
  p[threadIdx.x] = pooled[(size_t)b * 256 + threadIdx.x];
  __syncthreads();
  for (int cls = threadIdx.x; cls < 1000; cls += 256) {
    const float* w = hw + (size_t)cls * 256;
    float s = hb[cls];
    for (int k = 0; k < 256; k += 4)
      s += p[k] * w[k] + p[k + 1] * w[k + 1] + p[k + 2] * w[k + 2] + p[k + 3] * w[k + 3];
    out[(size_t)b * 1000 + cls] = s;
  }
}

// ---------------------------------------------------------------------------
// Weight prep: f32 -> hi/lo bf16; batched transpose+split ([R,C] -> [C,R])
// ---------------------------------------------------------------------------
__global__ void cast_split_kernel(const float* __restrict__ in,
                                  u16* __restrict__ oh, u16* __restrict__ ol, int n4) {
  int id = blockIdx.x * 256 + threadIdx.x;
  if (id >= n4) return;
  float4 v = ((const float4*)in)[id];
  u16 h0, l0, h1, l1, h2, l2, h3, l3;
  fsplit(v.x, h0, l0); fsplit(v.y, h1, l1); fsplit(v.z, h2, l2); fsplit(v.w, h3, l3);
  ((ushort4*)oh)[id] = make_ushort4(h0, h1, h2, h3);
  ((ushort4*)ol)[id] = make_ushort4(l0, l1, l2, l3);
}

__global__ __launch_bounds__(256) void transpose_split(const float* __restrict__ in,
    u16* __restrict__ oh, u16* __restrict__ ol, int R, int C) {
  __shared__ float tile[32][33];
  const int e = blockIdx.z;
  const int bc = blockIdx.x * 32, br = blockIdx.y * 32;
  const int tx = threadIdx.x & 31, ty = threadIdx.x >> 5;
  const float* src = in + (size_t)e * R * C;
#pragma unroll
  for (int i = 0; i < 32; i += 8)
    tile[ty + i][tx] = src[(size_t)(br + ty + i) * C + bc + tx];
  __syncthreads();
#pragma unroll
  for (int i = 0; i < 32; i += 8) {
    float v = tile[tx][ty + i];
    u16 h, l; fsplit(v, h, l);
    size_t di = (size_t)e * R * C + (size_t)(bc + ty + i) * R + br + tx;
    oh[di] = h; ol[di] = l;
  }
}

// ---------------------------------------------------------------------------
extern "C" void kernel_launch(void* const* d_in, const int* in_sizes, int n_in,
                              void* d_out, int out_size, void* d_ws, size_t ws_size,
                              hipStream_t stream) {
  (void)in_sizes; (void)n_in; (void)out_size; (void)ws_size;
  const float* x      = (const float*)d_in[0];
  const float* conv_w = (const float*)d_in[1];
  const float* conv_b = (const float*)d_in[2];
  const float* pos    = (const float*)d_in[3];
  const float* ln1_g  = (const float*)d_in[4];
  const float* ln1_b  = (const float*)d_in[5];
  const float* wqkv   = (const float*)d_in[6];
  const float* bqkv   = (const float*)d_in[7];
  const float* wo     = (const float*)d_in[8];
  const float* bo     = (const float*)d_in[9];
  const float* rw     = (const float*)d_in[10];
  const float* rb     = (const float*)d_in[11];
  const float* w1     = (const float*)d_in[12];
  const float* b1     = (const float*)d_in[13];
  const float* w2     = (const float*)d_in[14];
  const float* b2     = (const float*)d_in[15];
  const float* ln2_g  = (const float*)d_in[16];
  const float* ln2_b  = (const float*)d_in[17];
  const float* hw     = (const float*)d_in[18];
  const float* hb     = (const float*)d_in[19];
  float* out = (float*)d_out;

  const int T = T_TOK, E = 256, HID = 1024;
  char* ws = (char*)d_ws;
  size_t off = 0;
  auto alloc = [&](size_t bytes) -> void* {
    void* p = ws + off;
    off += (bytes + 255) & ~(size_t)255;
    return p;
  };
  // region 0: Aph+Apl+tok+xnh+qkvb (154 MB) -> reused as hbuf [2T,1024]bf16 (103 MB), then x2
  u16*   Aph    = (u16*)  alloc((size_t)T * 768 * 2);
  u16*   Apl    = (u16*)  alloc((size_t)T * 768 * 2);
  float* tok    = (float*)alloc((size_t)T * 256 * 4);
  u16*   xnh    = (u16*)  alloc((size_t)T * 256 * 2);
  u16*   qkvb   = (u16*)  alloc((size_t)T * 768 * 2);
  // region 1: aoh+aol+x1f == exactly [2T,256] f32 (51.4 MB) -> reused as yslot
  u16*   aoh    = (u16*)  alloc((size_t)T * 256 * 2);
  u16*   aol    = (u16*)  alloc((size_t)T * 256 * 2);
  float* x1f    = (float*)alloc((size_t)T * 256 * 4);
  u16*   x1h    = (u16*)  alloc((size_t)T * 256 * 2);
  float* gates  = (float*)alloc((size_t)T * 6 * 4);
  int*   idx    = (int*)  alloc((size_t)6 * T * 4);
  int*   cnt    = (int*)  alloc(256);
  int*   base   = (int*)  alloc(256);
  int*   nslot  = (int*)  alloc((size_t)T * 4);
  int*   invslot= (int*)  alloc((size_t)2 * T * 4);
  float* pooled = (float*)alloc((size_t)128 * 256 * 4);
  u16*   cwh    = (u16*)  alloc((size_t)196608 * 2);
  u16*   cwl    = (u16*)  alloc((size_t)196608 * 2);
  u16*   wqh    = (u16*)  alloc((size_t)196608 * 2);
  u16*   wql    = (u16*)  alloc((size_t)196608 * 2);
  u16*   woh    = (u16*)  alloc((size_t)65536 * 2);
  u16*   wol    = (u16*)  alloc((size_t)65536 * 2);
  u16*   w1th   = (u16*)  alloc((size_t)6 * 262144 * 2);
  u16*   w1tl   = (u16*)  alloc((size_t)6 * 262144 * 2);
  u16*   w2th   = (u16*)  alloc((size_t)6 * 262144 * 2);
  u16*   w2tl   = (u16*)  alloc((size_t)6 * 262144 * 2);
  // aliases (lifetimes disjoint):
  u16*   hbuf  = (u16*)ws;      // [2T,1024] bf16 expert h (region 0; inputs dead)
  float* yslot = (float*)aoh;   // [2T,256] f32 (region 1 aoh+aol+x1f; exact fit)
  float* x2    = (float*)ws;    // [T,256] f32 (over hbuf, dead after GEMM2)

  // --- weight prep (all weights hi+lo split) ---
  cast_split_kernel<<<192, 256, 0, stream>>>(conv_w, cwh, cwl, 49152);
  cast_split_kernel<<<192, 256, 0, stream>>>(wqkv, wqh, wql, 49152);
  cast_split_kernel<<<64, 256, 0, stream>>>(wo, woh, wol, 16384);
  transpose_split<<<dim3(32, 8, 6), 256, 0, stream>>>(w1, w1th, w1tl, 256, 1024);  // [e][n][k]
  transpose_split<<<dim3(8, 32, 6), 256, 0, stream>>>(w2, w2th, w2tl, 1024, 256);  // [e][n][k]

  // --- patch embedding (split A: router-input path) ---
  im2col_split<<<18816, 256, 0, stream>>>(x, Aph, Apl);
  gemm_bs<1, 0, true><<<dim3(196, 2), 256, 0, stream>>>(Aph, Apl, cwh, cwl, T, 256, 768,
      conv_b, pos, tok, nullptr, nullptr, nullptr, nullptr, 0, 0);

  // --- attention block (xn bf16: qkv output is bf16 anyway) ---
  ln_kernel<<<6272, 256, 0, stream>>>(tok, ln1_g, ln1_b, xnh);
  gemm_bs<5, 0, false><<<dim3(196, 6), 256, 0, stream>>>(xnh, nullptr, wqh, wql, T, 768, 256,
      bqkv, nullptr, nullptr, qkvb, nullptr, nullptr, nullptr, 0, 0);
  attn_mfma<<<1024, 256, 0, stream>>>(qkvb, aoh, aol);
  gemm_bs<2, 0, true><<<dim3(196, 2), 256, 0, stream>>>(aoh, aol, woh, wol, T, 256, 256,
      bo, tok, x1f, x1h, nullptr, nullptr, nullptr, 0, 0);

  // --- MoE (top-2 sparse, experts batched via grid.z, atomic-free slot combine) ---
  router_kernel<<<6272, 256, 0, stream>>>(x1f, rw, rb, gates);
  hipMemsetAsync(cnt, 0, 256, stream);
  scatter_kernel<<<98, 256, 0, stream>>>(gates, cnt, idx);
  prefix6_kernel<<<1, 64, 0, stream>>>(cnt, base);
  hipMemsetAsync(nslot, 0, (size_t)T * 4, stream);
  slotmap_kernel<<<dim3(98, 6), 256, 0, stream>>>(idx, cnt, base, nslot, invslot);
  gemm_bs<3, 1, false><<<dim3(196, 8, 6), 256, 0, stream>>>(x1h, nullptr, w1th, w1tl,
      T, 1024, 256, b1, nullptr, nullptr, hbuf, idx, cnt, base, (size_t)262144, 1024);
  gemm_bs<4, 2, false><<<dim3(196, 2, 6), 256, 0, stream>>>(hbuf, nullptr, w2th, w2tl,
      T, 256, 1024, b2, gates, yslot, nullptr, idx, cnt, base, (size_t)262144, 256);

  // --- final norm (fused slot combine), pool, head ---
  ln2_combine<<<6272, 256, 0, stream>>>(yslot, invslot, ln2_g, ln2_b, x2);
  pool_kernel<<<128, 256, 0, stream>>>(x2, pooled);
  head_kernel<<<128, 256, 0, stream>>>(pooled, hw, hb, out);
}

// Round 8
// 519.508 us; speedup vs baseline: 2.6798x; 1.1132x over previous
//
#include <hip/hip_runtime.h>
#include <hip/hip_bf16.h>

typedef unsigned short u16;
typedef short short8 __attribute__((ext_vector_type(8)));
typedef float f32x4 __attribute__((ext_vector_type(4)));

#define T_TOK 25088   // 128*196
#define NTOK 196

__device__ __forceinline__ u16 bfbits(float v) {
  __hip_bfloat16 h = __float2bfloat16(v);
  return *reinterpret_cast<u16*>(&h);
}
__device__ __forceinline__ float b2f(u16 u) {
  __hip_bfloat16 h = *reinterpret_cast<__hip_bfloat16*>(&u);
  return __bfloat162float(h);
}
// near-fp32 as hi+lo bf16 pair (Ootomo split)
__device__ __forceinline__ void fsplit(float v, u16& hi, u16& lo) {
  hi = bfbits(v);
  lo = bfbits(v - b2f(hi));
}

// ---------------------------------------------------------------------------
// GEMM: C[M,N] = A[M,K] @ (Bh+Bl)[N,K]^T + bias.  (dense path only now)
// A split (Ah+Al, 3 MFMA/frag) when SPLITA — router-input path (patch, wo).
// 128x128 tile, BK=32, 256 threads (4 waves 2x2), reg-staged 1-deep prefetch.
// EPI: 1 +pos->f32 | 2 +resid->f32+bf16 | 5 ->bf16
// ---------------------------------------------------------------------------
template<int EPI, bool SPLITA>
__global__ __launch_bounds__(256) void gemm_bs(
    const u16* __restrict__ A, const u16* __restrict__ Al,
    const u16* __restrict__ Bh, const u16* __restrict__ Bl,
    int M, int N, int K,
    const float* __restrict__ bias, const float* __restrict__ extra,
    float* __restrict__ outf, u16* __restrict__ obh)
{
  __shared__ u16 As[128][40];                      // +8 pad: 2-way banks
  __shared__ u16 Asl[SPLITA ? 128 : 1][40];
  __shared__ u16 Bsh[128][40], Bsl[128][40];
  const int tid = threadIdx.x;
  const int lane = tid & 63, wave = tid >> 6;
  const int wm = wave >> 1, wn = wave & 1;
  const int row0 = blockIdx.x * 128, col0 = blockIdx.y * 128;

  const int r0 = tid >> 2, r1 = r0 + 64, co = (tid & 3) * 8;
  const int ar0 = row0 + r0, ar1 = row0 + r1;

  f32x4 acc[4][4];
  const f32x4 zero = {0.f, 0.f, 0.f, 0.f};
#pragma unroll
  for (int i = 0; i < 4; ++i)
#pragma unroll
    for (int j = 0; j < 4; ++j) acc[i][j] = zero;

  const int rsel = lane & 15, ksel = (lane >> 4) * 8;

  short8 ra0, ra1, rl0, rl1, rb0, rb1, rc0, rc1;
  auto issue = [&](int k0) {
    ra0 = *(const short8*)(A + (size_t)ar0 * K + k0 + co);
    ra1 = *(const short8*)(A + (size_t)ar1 * K + k0 + co);
    if constexpr (SPLITA) {
      rl0 = *(const short8*)(Al + (size_t)ar0 * K + k0 + co);
      rl1 = *(const short8*)(Al + (size_t)ar1 * K + k0 + co);
    }
    rb0 = *(const short8*)(Bh + (size_t)(col0 + r0) * K + k0 + co);
    rb1 = *(const short8*)(Bh + (size_t)(col0 + r1) * K + k0 + co);
    rc0 = *(const short8*)(Bl + (size_t)(col0 + r0) * K + k0 + co);
    rc1 = *(const short8*)(Bl + (size_t)(col0 + r1) * K + k0 + co);
  };
  auto commit = [&]() {
    *(short8*)&As[r0][co] = ra0;
    *(short8*)&As[r1][co] = ra1;
    if constexpr (SPLITA) {
      *(short8*)&Asl[r0][co] = rl0;
      *(short8*)&Asl[r1][co] = rl1;
    }
    *(short8*)&Bsh[r0][co] = rb0;
    *(short8*)&Bsh[r1][co] = rb1;
    *(short8*)&Bsl[r0][co] = rc0;
    *(short8*)&Bsl[r1][co] = rc1;
  };

  issue(0);
  commit();
  __syncthreads();

  for (int k0 = 0;;) {
    const bool more = (k0 + 32 < K);
    if (more) issue(k0 + 32);
    short8 af[4], al4[4], bh4[4], bl4[4];
#pragma unroll
    for (int i = 0; i < 4; ++i) {
      af[i] = *(const short8*)&As[wm * 64 + i * 16 + rsel][ksel];
      if constexpr (SPLITA) al4[i] = *(const short8*)&Asl[wm * 64 + i * 16 + rsel][ksel];
    }
#pragma unroll
    for (int j = 0; j < 4; ++j) {
      bh4[j] = *(const short8*)&Bsh[wn * 64 + j * 16 + rsel][ksel];
      bl4[j] = *(const short8*)&Bsl[wn * 64 + j * 16 + rsel][ksel];
    }
#pragma unroll
    for (int i = 0; i < 4; ++i)
#pragma unroll
      for (int j = 0; j < 4; ++j) {
        acc[i][j] = __builtin_amdgcn_mfma_f32_16x16x32_bf16(af[i], bh4[j], acc[i][j], 0, 0, 0);
        if constexpr (SPLITA)
          acc[i][j] = __builtin_amdgcn_mfma_f32_16x16x32_bf16(al4[i], bh4[j], acc[i][j], 0, 0, 0);
        acc[i][j] = __builtin_amdgcn_mfma_f32_16x16x32_bf16(af[i], bl4[j], acc[i][j], 0, 0, 0);
      }
    k0 += 32;
    if (!more) break;
    __syncthreads();
    commit();
    __syncthreads();
  }

#pragma unroll
  for (int i = 0; i < 4; ++i) {
#pragma unroll
    for (int j = 0; j < 4; ++j) {
#pragma unroll
      for (int r = 0; r < 4; ++r) {
        int grow = row0 + wm * 64 + i * 16 + (lane >> 4) * 4 + r;   // token
        int gcol = col0 + wn * 64 + j * 16 + (lane & 15);           // feature
        float v = acc[i][j][r] + bias[gcol];
        size_t oi = (size_t)grow * N + gcol;
        if constexpr (EPI == 1) {
          v += extra[(size_t)(grow % NTOK) * N + gcol];   // pos_embed
          outf[oi] = v;
        } else if constexpr (EPI == 2) {
          v += extra[oi];                                  // residual
          outf[oi] = v;
          obh[oi] = bfbits(v);
        } else if constexpr (EPI == 5) {
          obh[oi] = bfbits(v);
        }
      }
    }
  }
}

// ---------------------------------------------------------------------------
// Fused MoE: per block = 128 gathered tokens of one expert (z = expert).
// X[128,256] resident in LDS; loop hc=0..7: H = gelu(X @ W1[:,hc*128:+128])
// -> LDS; Y += H @ W2[hc-chunk] in persistent regs. No h HBM round-trip.
// 512 threads (8 waves 2Mx4N). W1 staging double-buffered (1 barrier/step).
// ---------------------------------------------------------------------------
__global__ __launch_bounds__(512) void moe_fused(
    const u16* __restrict__ x1h,
    const u16* __restrict__ w1h, const u16* __restrict__ w1l,   // [6][1024][256]
    const u16* __restrict__ w2h, const u16* __restrict__ w2l,   // [6][256][1024]
    const float* __restrict__ b1, const float* __restrict__ b2,
    const float* __restrict__ gates,
    const int* __restrict__ idx_all, const int* __restrict__ cnt_all,
    const int* __restrict__ base_all,
    float* __restrict__ yslot)
{
  const int e = blockIdx.z;
  const int Meff = cnt_all[e];
  const int row0 = blockIdx.x * 128;
  if (row0 >= Meff) return;
  const int* gidx = idx_all + (size_t)e * T_TOK;
  const int hbase = base_all[e];
  const u16* W1h = w1h + (size_t)e * 262144;
  const u16* W1l = w1l + (size_t)e * 262144;
  const u16* W2h = w2h + (size_t)e * 262144;
  const u16* W2l = w2l + (size_t)e * 262144;
  const float* B1 = b1 + e * 1024;
  const float* B2 = b2 + e * 256;

  __shared__ u16 Xs[128][264];        // 67.6 KB, stride 528B -> 2-way banks
  __shared__ u16 Hs[128][136];        // 34.8 KB
  __shared__ u16 Wb[2][256][40];      // 41 KB: ph1 dbuf (hi rows 0-127, lo 128-255);
                                      //        ph2 single (Wb[0]=hi, Wb[1]=lo, 256 rows)
  const int tid = threadIdx.x, lane = tid & 63, wave = tid >> 6;
  const int wm = wave >> 2, wn = wave & 3;          // 2 x 4 wave grid
  const int rsel = lane & 15, ksel = (lane >> 4) * 8;
  const f32x4 zero = {0.f, 0.f, 0.f, 0.f};

  // ---- stage gathered X rows (once) ----
  for (int c = tid; c < 4096; c += 512) {           // 128 rows x 32 chunks of 8
    int r = c >> 5, co = (c & 31) * 8;
    int ar = gidx[min(row0 + r, Meff - 1)];
    *(short8*)&Xs[r][co] = *(const short8*)(x1h + (size_t)ar * 256 + co);
  }

  f32x4 acc2[4][4];
#pragma unroll
  for (int i = 0; i < 4; ++i)
#pragma unroll
    for (int j = 0; j < 4; ++j) acc2[i][j] = zero;

  const int wr = tid >> 2, wco = (tid & 3) * 8;     // ph1 staging slot (r 0..127)

  for (int hc = 0; hc < 8; ++hc) {
    const u16* w1ch = W1h + (size_t)(hc * 128) * 256;
    const u16* w1cl = W1l + (size_t)(hc * 128) * 256;

    f32x4 acc1[4][2];
#pragma unroll
    for (int i = 0; i < 4; ++i) {
      acc1[i][0] = zero; acc1[i][1] = zero;
    }

    // ---- phase 1: H = gelu(X @ W1chunk + b1) ----
    short8 ph = *(const short8*)(w1ch + (size_t)wr * 256 + wco);
    short8 pl = *(const short8*)(w1cl + (size_t)wr * 256 + wco);
    __syncthreads();                                 // prior readers of Wb done
    *(short8*)&Wb[0][wr][wco] = ph;
    *(short8*)&Wb[0][128 + wr][wco] = pl;
    __syncthreads();

    for (int ks = 0; ks < 8; ++ks) {
      if (ks < 7) {
        ph = *(const short8*)(w1ch + (size_t)wr * 256 + (ks + 1) * 32 + wco);
        pl = *(const short8*)(w1cl + (size_t)wr * 256 + (ks + 1) * 32 + wco);
      }
      short8 a4[4], bh2[2], bl2[2];
#pragma unroll
      for (int mi = 0; mi < 4; ++mi)
        a4[mi] = *(const short8*)&Xs[wm * 64 + mi * 16 + rsel][ks * 32 + ksel];
#pragma unroll
      for (int nj = 0; nj < 2; ++nj) {
        bh2[nj] = *(const short8*)&Wb[ks & 1][wn * 32 + nj * 16 + rsel][ksel];
        bl2[nj] = *(const short8*)&Wb[ks & 1][128 + wn * 32 + nj * 16 + rsel][ksel];
      }
#pragma unroll
      for (int mi = 0; mi < 4; ++mi)
#pragma unroll
        for (int nj = 0; nj < 2; ++nj) {
          acc1[mi][nj] = __builtin_amdgcn_mfma_f32_16x16x32_bf16(a4[mi], bh2[nj], acc1[mi][nj], 0, 0, 0);
          acc1[mi][nj] = __builtin_amdgcn_mfma_f32_16x16x32_bf16(a4[mi], bl2[nj], acc1[mi][nj], 0, 0, 0);
        }
      if (ks < 7) {
        *(short8*)&Wb[(ks + 1) & 1][wr][wco] = ph;
        *(short8*)&Wb[(ks + 1) & 1][128 + wr][wco] = pl;
      }
      __syncthreads();
    }

    // ---- H -> LDS (gelu, tanh form) ----
#pragma unroll
    for (int mi = 0; mi < 4; ++mi)
#pragma unroll
      for (int nj = 0; nj < 2; ++nj)
#pragma unroll
        for (int r = 0; r < 4; ++r) {
          int tr = wm * 64 + mi * 16 + (lane >> 4) * 4 + r;
          int tc = wn * 32 + nj * 16 + rsel;
          float v = acc1[mi][nj][r] + B1[hc * 128 + tc];
          float u = 1.5957691216057308f * (v + 0.044715f * v * v * v);  // 2*0.79788456*(...)
          float g = v / (1.f + __expf(-u));
          Hs[tr][tc] = bfbits(g);
        }
    __syncthreads();

    // ---- phase 2: Y += H @ W2chunk ----
    const int c0 = tid, c1 = tid + 512;
    const int r20 = c0 >> 2, co20 = (c0 & 3) * 8;
    const int r21 = c1 >> 2, co21 = (c1 & 3) * 8;
    int kofs = hc * 128;
    short8 q0h = *(const short8*)(W2h + (size_t)r20 * 1024 + kofs + co20);
    short8 q1h = *(const short8*)(W2h + (size_t)r21 * 1024 + kofs + co21);
    short8 q0l = *(const short8*)(W2l + (size_t)r20 * 1024 + kofs + co20);
    short8 q1l = *(const short8*)(W2l + (size_t)r21 * 1024 + kofs + co21);
    for (int ks = 0; ks < 4; ++ks) {
      __syncthreads();                               // previous readers of Wb done
      *(short8*)&Wb[0][r20][co20] = q0h;
      *(short8*)&Wb[0][r21][co21] = q1h;
      *(short8*)&Wb[1][r20][co20] = q0l;
      *(short8*)&Wb[1][r21][co21] = q1l;
      __syncthreads();
      if (ks < 3) {
        int kn = kofs + (ks + 1) * 32;
        q0h = *(const short8*)(W2h + (size_t)r20 * 1024 + kn + co20);
        q1h = *(const short8*)(W2h + (size_t)r21 * 1024 + kn + co21);
        q0l = *(const short8*)(W2l + (size_t)r20 * 1024 + kn + co20);
        q1l = *(const short8*)(W2l + (size_t)r21 * 1024 + kn + co21);
      }
      short8 a4[4];
#pragma unroll
      for (int mi = 0; mi < 4; ++mi)
        a4[mi] = *(const short8*)&Hs[wm * 64 + mi * 16 + rsel][ks * 32 + ksel];
#pragma unroll
      for (int nj = 0; nj < 4; ++nj) {
        short8 bh4 = *(const short8*)&Wb[0][wn * 64 + nj * 16 + rsel][ksel];
        short8 bl4 = *(const short8*)&Wb[1][wn * 64 + nj * 16 + rsel][ksel];
#pragma unroll
        for (int mi = 0; mi < 4; ++mi) {
          acc2[mi][nj] = __builtin_amdgcn_mfma_f32_16x16x32_bf16(a4[mi], bh4, acc2[mi][nj], 0, 0, 0);
          acc2[mi][nj] = __builtin_amdgcn_mfma_f32_16x16x32_bf16(a4[mi], bl4, acc2[mi][nj], 0, 0, 0);
        }
      }
    }
    __syncthreads();                                 // ph2 readers done before next hc
  }

  // ---- epilogue: yslot = gate * (Y + b2) ----
#pragma unroll
  for (int mi = 0; mi < 4; ++mi)
#pragma unroll
    for (int r = 0; r < 4; ++r) {
      int grow = row0 + wm * 64 + mi * 16 + (lane >> 4) * 4 + r;
      if (grow < Meff) {
        int tk = gidx[grow];
        float gt = gates[(size_t)tk * 6 + e];
#pragma unroll
        for (int nj = 0; nj < 4; ++nj) {
          int gcol = wn * 64 + nj * 16 + rsel;
          yslot[(size_t)(hbase + grow) * 256 + gcol] = gt * (acc2[mi][nj][r] + B2[gcol]);
        }
      }
    }
}

// ---------------------------------------------------------------------------
// im2col + split: x[B,3,224,224] f32 -> A_patch hi/lo [T,768]
// ---------------------------------------------------------------------------
__global__ void im2col_split(const float* __restrict__ x,
                             u16* __restrict__ Aph, u16* __restrict__ Apl) {
  int id = blockIdx.x * 256 + threadIdx.x;          // T*192 items of 4 elems
  if (id >= T_TOK * 192) return;
  int t = id / 192, kk = id - t * 192;
  int k4 = kk * 4;
  int c = k4 >> 8, rem = k4 & 255, p = rem >> 4, q = rem & 15;
  int b = t / 196, n = t - b * 196, gh = n / 14, gw = n - gh * 14;
  const float4 v = *(const float4*)(x + ((size_t)(b * 3 + c) * 224 + gh * 16 + p) * 224 + gw * 16 + q);
  u16 h0, l0, h1, l1, h2, l2, h3, l3;
  fsplit(v.x, h0, l0); fsplit(v.y, h1, l1); fsplit(v.z, h2, l2); fsplit(v.w, h3, l3);
  *(ushort4*)(Aph + (size_t)t * 768 + k4) = make_ushort4(h0, h1, h2, h3);
  *(ushort4*)(Apl + (size_t)t * 768 + k4) = make_ushort4(l0, l1, l2, l3);
}

// ---------------------------------------------------------------------------
// LayerNorm over E=256: wave per token; bf16 out
// ---------------------------------------------------------------------------
__global__ __launch_bounds__(256) void ln_kernel(const float* __restrict__ in,
    const float* __restrict__ g, const float* __restrict__ b, u16* __restrict__ oh)
{
  const int lane = threadIdx.x & 63;
  const int t = blockIdx.x * 4 + (threadIdx.x >> 6);
  const float4 v = *(const float4*)(in + (size_t)t * 256 + lane * 4);
  float s = v.x + v.y + v.z + v.w;
  float sq = v.x * v.x + v.y * v.y + v.z * v.z + v.w * v.w;
#pragma unroll
  for (int o = 32; o >= 1; o >>= 1) {
    s  += __shfl_xor(s,  o, 64);
    sq += __shfl_xor(sq, o, 64);
  }
  float mu = s * (1.f / 256.f);
  float var = sq * (1.f / 256.f) - mu * mu;
  float rstd = rsqrtf(var + 1e-5f);
  const float4 gv = *(const float4*)(g + lane * 4);
  const float4 bv = *(const float4*)(b + lane * 4);
  *(ushort4*)(oh + (size_t)t * 256 + lane * 4) = make_ushort4(
      bfbits((v.x - mu) * rstd * gv.x + bv.x), bfbits((v.y - mu) * rstd * gv.y + bv.y),
      bfbits((v.z - mu) * rstd * gv.z + bv.z), bfbits((v.w - mu) * rstd * gv.w + bv.w));
}

// ---------------------------------------------------------------------------
// Fused slot-combine + LayerNorm: moe[t] = yslot[s0]+yslot[s1]; x2 = LN(moe)
// ---------------------------------------------------------------------------
__global__ __launch_bounds__(256) void ln2_combine(const float* __restrict__ yslot,
    const int* __restrict__ invslot,
    const float* __restrict__ g, const float* __restrict__ b, float* __restrict__ outf)
{
  const int lane = threadIdx.x & 63;
  const int t = blockIdx.x * 4 + (threadIdx.x >> 6);
  const int s0 = invslot[t * 2], s1 = invslot[t * 2 + 1];
  const float4 a = *(const float4*)(yslot + (size_t)s0 * 256 + lane * 4);
  const float4 c = *(const float4*)(yslot + (size_t)s1 * 256 + lane * 4);
  float4 v = make_float4(a.x + c.x, a.y + c.y, a.z + c.z, a.w + c.w);
  float s = v.x + v.y + v.z + v.w;
  float sq = v.x * v.x + v.y * v.y + v.z * v.z + v.w * v.w;
#pragma unroll
  for (int o = 32; o >= 1; o >>= 1) {
    s  += __shfl_xor(s,  o, 64);
    sq += __shfl_xor(sq, o, 64);
  }
  float mu = s * (1.f / 256.f);
  float var = sq * (1.f / 256.f) - mu * mu;
  float rstd = rsqrtf(var + 1e-5f);
  const float4 gv = *(const float4*)(g + lane * 4);
  const float4 bv = *(const float4*)(b + lane * 4);
  *(float4*)(outf + (size_t)t * 256 + lane * 4) = make_float4(
      (v.x - mu) * rstd * gv.x + bv.x, (v.y - mu) * rstd * gv.y + bv.y,
      (v.z - mu) * rstd * gv.z + bv.z, (v.w - mu) * rstd * gv.w + bv.w);
}

// ---------------------------------------------------------------------------
// MFMA attention: one block per (b,h), 4 waves, 13 m-tiles of 16 q-rows.
// ao written split (hi+lo): feeds wo -> x1f -> router (gate precision).
// ---------------------------------------------------------------------------
__global__ __launch_bounds__(256) void attn_mfma(const u16* __restrict__ qkvb,
                                                 u16* __restrict__ aoh, u16* __restrict__ aol) {
  __shared__ u16 Qs[208][40];
  __shared__ u16 Ks[208][40];
  __shared__ u16 Vt[32][256];
  __shared__ u16 Ps[4][16][232];
  const int tid = threadIdx.x, lane = tid & 63, wave = tid >> 6;
  const int b = blockIdx.x >> 3, h = blockIdx.x & 7;
  const size_t base = (size_t)b * 196 * 768 + h * 32;
  const short8 z8 = {0, 0, 0, 0, 0, 0, 0, 0};

  for (int idx = tid; idx < 832; idx += 256) {
    int r = idx >> 2, c = (idx & 3) * 8;
    short8 q = z8, k = z8;
    if (r < 196) {
      q = *(const short8*)(qkvb + base + (size_t)r * 768 + c);
      k = *(const short8*)(qkvb + base + (size_t)r * 768 + 256 + c);
    }
    *(short8*)&Qs[r][c] = q;
    *(short8*)&Ks[r][c] = k;
  }
  for (int idx = tid; idx < 32 * 224; idx += 256) {
    int c = idx & 31, k = idx >> 5;
    u16 v = 0;
    if (k < 196) v = qkvb[base + (size_t)k * 768 + 512 + c];
    Vt[c][k ^ ((c & 7) << 3)] = v;
  }
  {
    int r = lane >> 2, c0 = 208 + (lane & 3) * 4;
    Ps[wave][r][c0] = 0; Ps[wave][r][c0 + 1] = 0; Ps[wave][r][c0 + 2] = 0; Ps[wave][r][c0 + 3] = 0;
  }
  __syncthreads();

  const int rsel = lane & 15, ksel = (lane >> 4) * 8;
  const f32x4 zero = {0.f, 0.f, 0.f, 0.f};

  for (int mt = wave; mt < 13; mt += 4) {
    short8 aq = *(const short8*)&Qs[mt * 16 + rsel][ksel];
    f32x4 sacc[13];
#pragma unroll
    for (int n = 0; n < 13; ++n)
      sacc[n] = __builtin_amdgcn_mfma_f32_16x16x32_bf16(
          aq, *(const short8*)&Ks[n * 16 + rsel][ksel], zero, 0, 0, 0);

#pragma unroll
    for (int r = 0; r < 4; ++r) {
      float mv = -1e30f;
#pragma unroll
      for (int n = 0; n < 13; ++n) {
        float sv = sacc[n][r] * 0.17677669529663687f;
        sacc[n][r] = sv;
        if (n * 16 + rsel < 196) mv = fmaxf(mv, sv);
      }
      mv = fmaxf(mv, __shfl_xor(mv, 1, 64));
      mv = fmaxf(mv, __shfl_xor(mv, 2, 64));
      mv = fmaxf(mv, __shfl_xor(mv, 4, 64));
      mv = fmaxf(mv, __shfl_xor(mv, 8, 64));
      float sm = 0.f;
#pragma unroll
      for (int n = 0; n < 13; ++n) {
        float p = (n * 16 + rsel < 196) ? __expf(sacc[n][r] - mv) : 0.f;
        sacc[n][r] = p;
        sm += p;
      }
      sm += __shfl_xor(sm, 1, 64);
      sm += __shfl_xor(sm, 2, 64);
      sm += __shfl_xor(sm, 4, 64);
      sm += __shfl_xor(sm, 8, 64);
      float inv = 1.f / sm;
      int prow = (lane >> 4) * 4 + r;
#pragma unroll
      for (int n = 0; n < 13; ++n)
        Ps[wave][prow][n * 16 + rsel] = bfbits(sacc[n][r] * inv);
    }

    f32x4 oacc[2] = {zero, zero};
#pragma unroll
    for (int kk = 0; kk < 7; ++kk) {
      short8 ap = *(const short8*)&Ps[wave][rsel][kk * 32 + ksel];
#pragma unroll
      for (int nt = 0; nt < 2; ++nt) {
        int d = nt * 16 + rsel;
        short8 bv = *(const short8*)&Vt[d][(kk * 32 + ksel) ^ ((d & 7) << 3)];
        oacc[nt] = __builtin_amdgcn_mfma_f32_16x16x32_bf16(ap, bv, oacc[nt], 0, 0, 0);
      }
    }
#pragma unroll
    for (int nt = 0; nt < 2; ++nt) {
#pragma unroll
      for (int r = 0; r < 4; ++r) {
        int row = mt * 16 + (lane >> 4) * 4 + r;
        if (row < 196) {
          size_t oi = ((size_t)b * 196 + row) * 256 + h * 32 + nt * 16 + rsel;
          u16 hh, ll; fsplit(oacc[nt][r], hh, ll);
          aoh[oi] = hh; aol[oi] = ll;
        }
      }
    }
  }
}

// ---------------------------------------------------------------------------
// Router: wave per token; 6 logits, softmax, top-2 -> dense gates [T,6]
// ---------------------------------------------------------------------------
__global__ __launch_bounds__(256) void router_kernel(const float* __restrict__ x1,
    const float* __restrict__ rw, const float* __restrict__ rb, float* __restrict__ gates)
{
  const int lane = threadIdx.x & 63;
  const int t = blockIdx.x * 4 + (threadIdx.x >> 6);
  const float4 xv = *(const float4*)(x1 + (size_t)t * 256 + lane * 4);
  float logit[6];
#pragma unroll
  for (int e = 0; e < 6; ++e) {
    const float4 wv = *(const float4*)(rw + e * 256 + lane * 4);
    float p = xv.x * wv.x + xv.y * wv.y + xv.z * wv.z + xv.w * wv.w;
#pragma unroll
    for (int o = 32; o >= 1; o >>= 1) p += __shfl_xor(p, o, 64);
    logit[e] = p + rb[e];
  }
  float mx = logit[0];
#pragma unroll
  for (int e = 1; e < 6; ++e) mx = fmaxf(mx, logit[e]);
  float pe[6], sum = 0.f;
#pragma unroll
  for (int e = 0; e < 6; ++e) { pe[e] = __expf(logit[e] - mx); sum += pe[e]; }
  float inv = 1.f / sum;
  int i1 = 0; float p1 = pe[0];
#pragma unroll
  for (int e = 1; e < 6; ++e) if (pe[e] > p1) { p1 = pe[e]; i1 = e; }
  int i2 = -1; float p2 = -1.f;
#pragma unroll
  for (int e = 0; e < 6; ++e) if (e != i1 && pe[e] > p2) { p2 = pe[e]; i2 = e; }
  if (lane < 6)
    gates[(size_t)t * 6 + lane] = (lane == i1) ? p1 * inv : ((lane == i2) ? p2 * inv : 0.f);
}

// ---------------------------------------------------------------------------
// Scatter: build per-expert token lists (block-aggregated atomics)
// ---------------------------------------------------------------------------
__global__ __launch_bounds__(256) void scatter_kernel(const float* __restrict__ gates,
                                                      int* __restrict__ cnt, int* __restrict__ idx) {
  __shared__ int lcnt[6], lbase[6];
  const int t = blockIdx.x * 256 + threadIdx.x;
  if (threadIdx.x < 6) lcnt[threadIdx.x] = 0;
  __syncthreads();
  float g[6]; int lpos[6];
#pragma unroll
  for (int e = 0; e < 6; ++e) {
    g[e] = gates[(size_t)t * 6 + e];
    if (g[e] > 0.f) lpos[e] = atomicAdd(&lcnt[e], 1);
  }
  __syncthreads();
  if (threadIdx.x < 6) lbase[threadIdx.x] = atomicAdd(&cnt[threadIdx.x], lcnt[threadIdx.x]);
  __syncthreads();
#pragma unroll
  for (int e = 0; e < 6; ++e)
    if (g[e] > 0.f) idx[(size_t)e * T_TOK + lbase[e] + lpos[e]] = t;
}

// exclusive prefix over the 6 expert counts -> segment bases in slot buffer
__global__ void prefix6_kernel(const int* __restrict__ cnt, int* __restrict__ base) {
  if (threadIdx.x == 0) {
    int s = 0;
#pragma unroll
    for (int e = 0; e < 6; ++e) { base[e] = s; s += cnt[e]; }
  }
}

// token -> its 2 slot positions in the concatenated expert segments
__global__ __launch_bounds__(256) void slotmap_kernel(const int* __restrict__ idx,
    const int* __restrict__ cnt, const int* __restrict__ base,
    int* __restrict__ nslot, int* __restrict__ invslot) {
  const int e = blockIdx.y;
  const int p = blockIdx.x * 256 + threadIdx.x;
  if (p < cnt[e]) {
    int t = idx[(size_t)e * T_TOK + p];
    int j = atomicAdd(&nslot[t], 1);
    invslot[(size_t)t * 2 + j] = base[e] + p;
  }
}

// ---------------------------------------------------------------------------
// Mean-pool over tokens, then classifier head (fp32)
// ---------------------------------------------------------------------------
__global__ __launch_bounds__(256) void pool_kernel(const float* __restrict__ x2, float* __restrict__ pooled) {
  int b = blockIdx.x, e = threadIdx.x;
  float s = 0.f;
  for (int n = 0; n < 196; ++n) s += x2[((size_t)b * 196 + n) * 256 + e];
  pooled[(size_t)b * 256 + e] = s * (1.f / 196.f);
}

__global__ __launch_bounds__(256) void head_kernel(const float* __restrict__ pooled,
    const float* __restrict__ hw, const float* __restrict__ hb, float* __restrict__ out) {
  __shared__ float p[256];
  int b = blockIdx.x;
  p[threadIdx.x] = pooled[(size_t)b * 256 + threadIdx.x];
  __syncthreads();
  for (int cls = threadIdx.x; cls < 1000; cls += 256) {
    const float* w = hw + (size_t)cls * 256;
    float s = hb[cls];
    for (int k = 0; k < 256; k += 4)
      s += p[k] * w[k] + p[k + 1] * w[k + 1] + p[k + 2] * w[k + 2] + p[k + 3] * w[k + 3];
    out[(size_t)b * 1000 + cls] = s;
  }
}

// ---------------------------------------------------------------------------
// Weight prep: f32 -> hi/lo bf16; batched transpose+split ([R,C] -> [C,R])
// ---------------------------------------------------------------------------
__global__ void cast_split_kernel(const float* __restrict__ in,
                                  u16* __restrict__ oh, u16* __restrict__ ol, int n4) {
  int id = blockIdx.x * 256 + threadIdx.x;
  if (id >= n4) return;
  float4 v = ((const float4*)in)[id];
  u16 h0, l0, h1, l1, h2, l2, h3, l3;
  fsplit(v.x, h0, l0); fsplit(v.y, h1, l1); fsplit(v.z, h2, l2); fsplit(v.w, h3, l3);
  ((ushort4*)oh)[id] = make_ushort4(h0, h1, h2, h3);
  ((ushort4*)ol)[id] = make_ushort4(l0, l1, l2, l3);
}

__global__ __launch_bounds__(256) void transpose_split(const float* __restrict__ in,
    u16* __restrict__ oh, u16* __restrict__ ol, int R, int C) {
  __shared__ float tile[32][33];
  const int e = blockIdx.z;
  const int bc = blockIdx.x * 32, br = blockIdx.y * 32;
  const int tx = threadIdx.x & 31, ty = threadIdx.x >> 5;
  const float* src = in + (size_t)e * R * C;
#pragma unroll
  for (int i = 0; i < 32; i += 8)
    tile[ty + i][tx] = src[(size_t)(br + ty + i) * C + bc + tx];
  __syncthreads();
#pragma unroll
  for (int i = 0; i < 32; i += 8) {
    float v = tile[tx][ty + i];
    u16 h, l; fsplit(v, h, l);
    size_t di = (size_t)e * R * C + (size_t)(bc + ty + i) * R + br + tx;
    oh[di] = h; ol[di] = l;
  }
}

// ---------------------------------------------------------------------------
extern "C" void kernel_launch(void* const* d_in, const int* in_sizes, int n_in,
                              void* d_out, int out_size, void* d_ws, size_t ws_size,
                              hipStream_t stream) {
  (void)in_sizes; (void)n_in; (void)out_size; (void)ws_size;
  const float* x      = (const float*)d_in[0];
  const float* conv_w = (const float*)d_in[1];
  const float* conv_b = (const float*)d_in[2];
  const float* pos    = (const float*)d_in[3];
  const float* ln1_g  = (const float*)d_in[4];
  const float* ln1_b  = (const float*)d_in[5];
  const float* wqkv   = (const float*)d_in[6];
  const float* bqkv   = (const float*)d_in[7];
  const float* wo     = (const float*)d_in[8];
  const float* bo     = (const float*)d_in[9];
  const float* rw     = (const float*)d_in[10];
  const float* rb     = (const float*)d_in[11];
  const float* w1     = (const float*)d_in[12];
  const float* b1     = (const float*)d_in[13];
  const float* w2     = (const float*)d_in[14];
  const float* b2     = (const float*)d_in[15];
  const float* ln2_g  = (const float*)d_in[16];
  const float* ln2_b  = (const float*)d_in[17];
  const float* hw     = (const float*)d_in[18];
  const float* hb     = (const float*)d_in[19];
  float* out = (float*)d_out;

  const int T = T_TOK;
  char* ws = (char*)d_ws;
  size_t off = 0;
  auto alloc = [&](size_t bytes) -> void* {
    void* p = ws + off;
    off += (bytes + 255) & ~(size_t)255;
    return p;
  };
  // region 0: Aph+Apl+tok+xnh+qkvb -> reused as x2 after qkv consumed
  u16*   Aph    = (u16*)  alloc((size_t)T * 768 * 2);
  u16*   Apl    = (u16*)  alloc((size_t)T * 768 * 2);
  float* tok    = (float*)alloc((size_t)T * 256 * 4);
  u16*   xnh    = (u16*)  alloc((size_t)T * 256 * 2);
  u16*   qkvb   = (u16*)  alloc((size_t)T * 768 * 2);
  // region 1: aoh+aol+x1f == exactly [2T,256] f32 -> reused as yslot
  u16*   aoh    = (u16*)  alloc((size_t)T * 256 * 2);
  u16*   aol    = (u16*)  alloc((size_t)T * 256 * 2);
  float* x1f    = (float*)alloc((size_t)T * 256 * 4);
  u16*   x1h    = (u16*)  alloc((size_t)T * 256 * 2);
  float* gates  = (float*)alloc((size_t)T * 6 * 4);
  int*   idx    = (int*)  alloc((size_t)6 * T * 4);
  int*   cnt    = (int*)  alloc(256);
  int*   base   = (int*)  alloc(256);
  int*   nslot  = (int*)  alloc((size_t)T * 4);
  int*   invslot= (int*)  alloc((size_t)2 * T * 4);
  float* pooled = (float*)alloc((size_t)128 * 256 * 4);
  u16*   cwh    = (u16*)  alloc((size_t)196608 * 2);
  u16*   cwl    = (u16*)  alloc((size_t)196608 * 2);
  u16*   wqh    = (u16*)  alloc((size_t)196608 * 2);
  u16*   wql    = (u16*)  alloc((size_t)196608 * 2);
  u16*   woh    = (u16*)  alloc((size_t)65536 * 2);
  u16*   wol    = (u16*)  alloc((size_t)65536 * 2);
  u16*   w1th   = (u16*)  alloc((size_t)6 * 262144 * 2);
  u16*   w1tl   = (u16*)  alloc((size_t)6 * 262144 * 2);
  u16*   w2th   = (u16*)  alloc((size_t)6 * 262144 * 2);
  u16*   w2tl   = (u16*)  alloc((size_t)6 * 262144 * 2);
  // aliases (lifetimes disjoint):
  float* yslot = (float*)aoh;   // [2T,256] f32 (region 1; exact fit)
  float* x2    = (float*)ws;    // [T,256] f32 (region 0; inputs dead by then)

  // --- weight prep (all weights hi+lo split) ---
  cast_split_kernel<<<192, 256, 0, stream>>>(conv_w, cwh, cwl, 49152);
  cast_split_kernel<<<192, 256, 0, stream>>>(wqkv, wqh, wql, 49152);
  cast_split_kernel<<<64, 256, 0, stream>>>(wo, woh, wol, 16384);
  transpose_split<<<dim3(32, 8, 6), 256, 0, stream>>>(w1, w1th, w1tl, 256, 1024);  // [e][n][k]
  transpose_split<<<dim3(8, 32, 6), 256, 0, stream>>>(w2, w2th, w2tl, 1024, 256);  // [e][n][k]

  // --- patch embedding (split A: router-input path) ---
  im2col_split<<<18816, 256, 0, stream>>>(x, Aph, Apl);
  gemm_bs<1, true><<<dim3(196, 2), 256, 0, stream>>>(Aph, Apl, cwh, cwl, T, 256, 768,
      conv_b, pos, tok, nullptr);

  // --- attention block ---
  ln_kernel<<<6272, 256, 0, stream>>>(tok, ln1_g, ln1_b, xnh);
  gemm_bs<5, false><<<dim3(196, 6), 256, 0, stream>>>(xnh, nullptr, wqh, wql, T, 768, 256,
      bqkv, nullptr, nullptr, qkvb);
  attn_mfma<<<1024, 256, 0, stream>>>(qkvb, aoh, aol);
  gemm_bs<2, true><<<dim3(196, 2), 256, 0, stream>>>(aoh, aol, woh, wol, T, 256, 256,
      bo, tok, x1f, x1h);

  // --- MoE (top-2 sparse, fused GEMM1+gelu+GEMM2, atomic-free slot combine) ---
  router_kernel<<<6272, 256, 0, stream>>>(x1f, rw, rb, gates);
  hipMemsetAsync(cnt, 0, 256, stream);
  scatter_kernel<<<98, 256, 0, stream>>>(gates, cnt, idx);
  prefix6_kernel<<<1, 64, 0, stream>>>(cnt, base);
  hipMemsetAsync(nslot, 0, (size_t)T * 4, stream);
  slotmap_kernel<<<dim3(98, 6), 256, 0, stream>>>(idx, cnt, base, nslot, invslot);
  moe_fused<<<dim3(196, 1, 6), 512, 0, stream>>>(x1h, w1th, w1tl, w2th, w2tl,
      b1, b2, gates, idx, cnt, base, yslot);

  // --- final norm (fused slot combine), pool, head ---
  ln2_combine<<<6272, 256, 0, stream>>>(yslot, invslot, ln2_g, ln2_b, x2);
  pool_kernel<<<128, 256, 0, stream>>>(x2, pooled);
  head_kernel<<<128, 256, 0, stream>>>(pooled, hw, hb, out);
}

// Round 9
// 429.248 us; speedup vs baseline: 3.2433x; 1.2103x over previous
//
#include <hip/hip_runtime.h>
#include <hip/hip_bf16.h>

typedef unsigned short u16;
typedef short short8 __attribute__((ext_vector_type(8)));
typedef float f32x4 __attribute__((ext_vector_type(4)));

#define T_TOK 25088   // 128*196
#define NTOK 196
// chunk-XOR swizzle (T2-style): spreads row-aligned 16B chunks across banks
#define SWZ(r, c) ((((((c) >> 3) ^ ((r) & 7)) << 3)) | ((c) & 7))

__device__ __forceinline__ u16 bfbits(float v) {
  __hip_bfloat16 h = __float2bfloat16(v);
  return *reinterpret_cast<u16*>(&h);
}
__device__ __forceinline__ float b2f(u16 u) {
  __hip_bfloat16 h = *reinterpret_cast<__hip_bfloat16*>(&u);
  return __bfloat162float(h);
}
// near-fp32 as hi+lo bf16 pair (Ootomo split)
__device__ __forceinline__ void fsplit(float v, u16& hi, u16& lo) {
  hi = bfbits(v);
  lo = bfbits(v - b2f(hi));
}

// ---------------------------------------------------------------------------
// GEMM: C[M,N] = A[M,K] @ (Bh+Bl)[N,K]^T + bias.  (dense path)
// A split (3 MFMA/frag) when SPLITA — router-input path (patch, wo).
// 128x128 tile, BK=32, 256 threads (4 waves 2x2), reg-staged 1-deep prefetch.
// EPI: 1 +pos->f32 | 2 +resid->f32+bf16 | 5 ->bf16
// ---------------------------------------------------------------------------
template<int EPI, bool SPLITA>
__global__ __launch_bounds__(256) void gemm_bs(
    const u16* __restrict__ A, const u16* __restrict__ Al,
    const u16* __restrict__ Bh, const u16* __restrict__ Bl,
    int M, int N, int K,
    const float* __restrict__ bias, const float* __restrict__ extra,
    float* __restrict__ outf, u16* __restrict__ obh)
{
  __shared__ u16 As[128][40];                      // +8 pad: 2-way banks
  __shared__ u16 Asl[SPLITA ? 128 : 1][40];
  __shared__ u16 Bsh[128][40], Bsl[128][40];
  const int tid = threadIdx.x;
  const int lane = tid & 63, wave = tid >> 6;
  const int wm = wave >> 1, wn = wave & 1;
  const int row0 = blockIdx.x * 128, col0 = blockIdx.y * 128;

  const int r0 = tid >> 2, r1 = r0 + 64, co = (tid & 3) * 8;
  const int ar0 = row0 + r0, ar1 = row0 + r1;

  f32x4 acc[4][4];
  const f32x4 zero = {0.f, 0.f, 0.f, 0.f};
#pragma unroll
  for (int i = 0; i < 4; ++i)
#pragma unroll
    for (int j = 0; j < 4; ++j) acc[i][j] = zero;

  const int rsel = lane & 15, ksel = (lane >> 4) * 8;

  short8 ra0, ra1, rl0, rl1, rb0, rb1, rc0, rc1;
  auto issue = [&](int k0) {
    ra0 = *(const short8*)(A + (size_t)ar0 * K + k0 + co);
    ra1 = *(const short8*)(A + (size_t)ar1 * K + k0 + co);
    if constexpr (SPLITA) {
      rl0 = *(const short8*)(Al + (size_t)ar0 * K + k0 + co);
      rl1 = *(const short8*)(Al + (size_t)ar1 * K + k0 + co);
    }
    rb0 = *(const short8*)(Bh + (size_t)(col0 + r0) * K + k0 + co);
    rb1 = *(const short8*)(Bh + (size_t)(col0 + r1) * K + k0 + co);
    rc0 = *(const short8*)(Bl + (size_t)(col0 + r0) * K + k0 + co);
    rc1 = *(const short8*)(Bl + (size_t)(col0 + r1) * K + k0 + co);
  };
  auto commit = [&]() {
    *(short8*)&As[r0][co] = ra0;
    *(short8*)&As[r1][co] = ra1;
    if constexpr (SPLITA) {
      *(short8*)&Asl[r0][co] = rl0;
      *(short8*)&Asl[r1][co] = rl1;
    }
    *(short8*)&Bsh[r0][co] = rb0;
    *(short8*)&Bsh[r1][co] = rb1;
    *(short8*)&Bsl[r0][co] = rc0;
    *(short8*)&Bsl[r1][co] = rc1;
  };

  issue(0);
  commit();
  __syncthreads();

  for (int k0 = 0;;) {
    const bool more = (k0 + 32 < K);
    if (more) issue(k0 + 32);
    short8 af[4], al4[4], bh4[4], bl4[4];
#pragma unroll
    for (int i = 0; i < 4; ++i) {
      af[i] = *(const short8*)&As[wm * 64 + i * 16 + rsel][ksel];
      if constexpr (SPLITA) al4[i] = *(const short8*)&Asl[wm * 64 + i * 16 + rsel][ksel];
    }
#pragma unroll
    for (int j = 0; j < 4; ++j) {
      bh4[j] = *(const short8*)&Bsh[wn * 64 + j * 16 + rsel][ksel];
      bl4[j] = *(const short8*)&Bsl[wn * 64 + j * 16 + rsel][ksel];
    }
#pragma unroll
    for (int i = 0; i < 4; ++i)
#pragma unroll
      for (int j = 0; j < 4; ++j) {
        acc[i][j] = __builtin_amdgcn_mfma_f32_16x16x32_bf16(af[i], bh4[j], acc[i][j], 0, 0, 0);
        if constexpr (SPLITA)
          acc[i][j] = __builtin_amdgcn_mfma_f32_16x16x32_bf16(al4[i], bh4[j], acc[i][j], 0, 0, 0);
        acc[i][j] = __builtin_amdgcn_mfma_f32_16x16x32_bf16(af[i], bl4[j], acc[i][j], 0, 0, 0);
      }
    k0 += 32;
    if (!more) break;
    __syncthreads();
    commit();
    __syncthreads();
  }

#pragma unroll
  for (int i = 0; i < 4; ++i) {
#pragma unroll
    for (int j = 0; j < 4; ++j) {
#pragma unroll
      for (int r = 0; r < 4; ++r) {
        int grow = row0 + wm * 64 + i * 16 + (lane >> 4) * 4 + r;   // token
        int gcol = col0 + wn * 64 + j * 16 + (lane & 15);           // feature
        float v = acc[i][j][r] + bias[gcol];
        size_t oi = (size_t)grow * N + gcol;
        if constexpr (EPI == 1) {
          v += extra[(size_t)(grow % NTOK) * N + gcol];   // pos_embed
          outf[oi] = v;
        } else if constexpr (EPI == 2) {
          v += extra[oi];                                  // residual
          outf[oi] = v;
          obh[oi] = bfbits(v);
        } else if constexpr (EPI == 5) {
          obh[oi] = bfbits(v);
        }
      }
    }
  }
}

// ---------------------------------------------------------------------------
// Fused MoE v2: 64-token tiles, hi-only weights, 80 KB LDS -> 2 blocks/CU.
// Per block (z = expert): X[64,256] LDS-resident (swizzled); loop hc=0..7:
//   H = gelu(X @ W1[hc-chunk]) -> LDS;  Y += H @ W2[hc-chunk] (persistent regs)
// 512 threads = 8 waves (2M x 4N). BK=64, named-reg prefetch, 9 barriers/hc.
// ---------------------------------------------------------------------------
__global__ __launch_bounds__(512, 4) void moe_fused(
    const u16* __restrict__ x1h,
    const u16* __restrict__ w1, const u16* __restrict__ w2,
    const float* __restrict__ b1, const float* __restrict__ b2,
    const float* __restrict__ gates,
    const int* __restrict__ idx_all, const int* __restrict__ cnt_all,
    const int* __restrict__ base_all,
    float* __restrict__ yslot)
{
  const int e = blockIdx.z;
  const int Meff = cnt_all[e];
  const int row0 = blockIdx.x * 64;
  if (row0 >= Meff) return;
  const int* gidx = idx_all + (size_t)e * T_TOK;
  const int hbase = base_all[e];
  const u16* W1 = w1 + (size_t)e * 262144;   // [1024][256] (n,k)
  const u16* W2 = w2 + (size_t)e * 262144;   // [256][1024] (n,k)
  const float* B1 = b1 + e * 1024;
  const float* B2 = b2 + e * 256;

  __shared__ u16 Xs[64][256];       // 32 KB, swizzled
  __shared__ u16 Hs[64][128];       // 16 KB, swizzled
  __shared__ u16 Ws[2 * 128 * 64];  // 32 KB: ph1 dbuf 2x[128][64]; ph2 flat [256][64]

  const int tid = threadIdx.x, lane = tid & 63, wave = tid >> 6;
  const int wm = wave >> 2, wn = wave & 3;
  const int rsel = lane & 15, ksel = (lane >> 4) * 8;
  const f32x4 zero = {0.f, 0.f, 0.f, 0.f};

  // staging slots: W1 tile [128][64] = 1024 chunks -> 2/thread
  const int w1r = tid >> 2, w1c = ((2 * tid) & 7) * 8;
  // W2 tile [256][64] = 2048 chunks -> 4/thread
  const int w2r = tid >> 1, w2c = ((4 * tid) & 7) * 8;

  // issue W1 st0 (hc=0) early, then stage X (gathered, swizzled)
  short8 w1a = *(const short8*)(W1 + (size_t)w1r * 256 + w1c);
  short8 w1b = *(const short8*)(W1 + (size_t)w1r * 256 + w1c + 8);
  for (int ch = tid; ch < 2048; ch += 512) {
    int r = ch >> 5, c = (ch & 31) * 8;
    int ar = gidx[min(row0 + r, Meff - 1)];
    *(short8*)&Xs[r][SWZ(r, c)] = *(const short8*)(x1h + (size_t)ar * 256 + c);
  }

  f32x4 acc2[2][4];
#pragma unroll
  for (int i = 0; i < 2; ++i)
#pragma unroll
    for (int j = 0; j < 4; ++j) acc2[i][j] = zero;

  f32x4 acc1[2][2];

  auto ph1 = [&](int st, int buf) {
#pragma unroll
    for (int kk = 0; kk < 2; ++kk) {
      int ra0 = wm * 32 + rsel, ra1 = ra0 + 16;
      int kc = st * 64 + kk * 32 + ksel;
      short8 a0 = *(const short8*)&Xs[ra0][SWZ(ra0, kc)];
      short8 a1 = *(const short8*)&Xs[ra1][SWZ(ra1, kc)];
      int rb0 = wn * 32 + rsel, rb1 = rb0 + 16;
      int wc = kk * 32 + ksel;
      short8 b0 = *(const short8*)&Ws[buf * 8192 + rb0 * 64 + SWZ(rb0, wc)];
      short8 b1 = *(const short8*)&Ws[buf * 8192 + rb1 * 64 + SWZ(rb1, wc)];
      acc1[0][0] = __builtin_amdgcn_mfma_f32_16x16x32_bf16(a0, b0, acc1[0][0], 0, 0, 0);
      acc1[0][1] = __builtin_amdgcn_mfma_f32_16x16x32_bf16(a0, b1, acc1[0][1], 0, 0, 0);
      acc1[1][0] = __builtin_amdgcn_mfma_f32_16x16x32_bf16(a1, b0, acc1[1][0], 0, 0, 0);
      acc1[1][1] = __builtin_amdgcn_mfma_f32_16x16x32_bf16(a1, b1, acc1[1][1], 0, 0, 0);
    }
  };
  auto ph2 = [&](int st) {
#pragma unroll
    for (int kk = 0; kk < 2; ++kk) {
      int ra0 = wm * 32 + rsel, ra1 = ra0 + 16;
      int kc = st * 64 + kk * 32 + ksel;
      short8 a0 = *(const short8*)&Hs[ra0][SWZ(ra0, kc)];
      short8 a1 = *(const short8*)&Hs[ra1][SWZ(ra1, kc)];
      int wc = kk * 32 + ksel;
#pragma unroll
      for (int nj = 0; nj < 4; ++nj) {
        int nr = wn * 64 + nj * 16 + rsel;
        short8 b = *(const short8*)&Ws[nr * 64 + SWZ(nr, wc)];
        acc2[0][nj] = __builtin_amdgcn_mfma_f32_16x16x32_bf16(a0, b, acc2[0][nj], 0, 0, 0);
        acc2[1][nj] = __builtin_amdgcn_mfma_f32_16x16x32_bf16(a1, b, acc2[1][nj], 0, 0, 0);
      }
    }
  };

  for (int hc = 0; hc < 8; ++hc) {
    const u16* W1c = W1 + (size_t)hc * 128 * 256;
    const u16* W2c = W2 + hc * 128;
    // W2 st0 loads (latency hidden under all of phase 1)
    short8 q0 = *(const short8*)(W2c + (size_t)w2r * 1024 + w2c);
    short8 q1 = *(const short8*)(W2c + (size_t)w2r * 1024 + w2c + 8);
    short8 q2 = *(const short8*)(W2c + (size_t)w2r * 1024 + w2c + 16);
    short8 q3 = *(const short8*)(W2c + (size_t)w2r * 1024 + w2c + 24);

#pragma unroll
    for (int i = 0; i < 2; ++i) {
      acc1[i][0] = zero; acc1[i][1] = zero;
    }

    // ---- phase 1: 4 steps of BK=64, dbuf ----
    *(short8*)&Ws[w1r * 64 + SWZ(w1r, w1c)] = w1a;
    *(short8*)&Ws[w1r * 64 + SWZ(w1r, w1c + 8)] = w1b;
    short8 p0 = *(const short8*)(W1c + (size_t)w1r * 256 + 64 + w1c);
    short8 p1 = *(const short8*)(W1c + (size_t)w1r * 256 + 64 + w1c + 8);
    __syncthreads();                                           // B1
    short8 r0 = *(const short8*)(W1c + (size_t)w1r * 256 + 128 + w1c);
    short8 r1 = *(const short8*)(W1c + (size_t)w1r * 256 + 128 + w1c + 8);
    ph1(0, 0);
    *(short8*)&Ws[8192 + w1r * 64 + SWZ(w1r, w1c)] = p0;
    *(short8*)&Ws[8192 + w1r * 64 + SWZ(w1r, w1c + 8)] = p1;
    __syncthreads();                                           // B2
    p0 = *(const short8*)(W1c + (size_t)w1r * 256 + 192 + w1c);
    p1 = *(const short8*)(W1c + (size_t)w1r * 256 + 192 + w1c + 8);
    ph1(1, 1);
    *(short8*)&Ws[w1r * 64 + SWZ(w1r, w1c)] = r0;
    *(short8*)&Ws[w1r * 64 + SWZ(w1r, w1c + 8)] = r1;
    __syncthreads();                                           // B3
    ph1(2, 0);
    *(short8*)&Ws[8192 + w1r * 64 + SWZ(w1r, w1c)] = p0;
    *(short8*)&Ws[8192 + w1r * 64 + SWZ(w1r, w1c + 8)] = p1;
    __syncthreads();                                           // B4
    ph1(3, 1);

    // ---- gelu -> Hs (tanh/sigmoid form) ----
#pragma unroll
    for (int mi = 0; mi < 2; ++mi)
#pragma unroll
      for (int nj = 0; nj < 2; ++nj)
#pragma unroll
        for (int r = 0; r < 4; ++r) {
          int tr = wm * 32 + mi * 16 + (lane >> 4) * 4 + r;
          int tc = wn * 32 + nj * 16 + rsel;
          float v = acc1[mi][nj][r] + B1[hc * 128 + tc];
          float u = 1.5957691216057308f * (v + 0.044715f * v * v * v);
          Hs[tr][SWZ(tr, tc)] = bfbits(v / (1.f + __expf(-u)));
        }
    __syncthreads();                                           // B5 (Ws free + Hs ready)

    // ---- phase 2: 2 steps of BK=64, Ws reused flat [256][64] ----
    *(short8*)&Ws[w2r * 64 + SWZ(w2r, w2c)] = q0;
    *(short8*)&Ws[w2r * 64 + SWZ(w2r, w2c + 8)] = q1;
    *(short8*)&Ws[w2r * 64 + SWZ(w2r, w2c + 16)] = q2;
    *(short8*)&Ws[w2r * 64 + SWZ(w2r, w2c + 24)] = q3;
    q0 = *(const short8*)(W2c + (size_t)w2r * 1024 + 64 + w2c);
    q1 = *(const short8*)(W2c + (size_t)w2r * 1024 + 64 + w2c + 8);
    q2 = *(const short8*)(W2c + (size_t)w2r * 1024 + 64 + w2c + 16);
    q3 = *(const short8*)(W2c + (size_t)w2r * 1024 + 64 + w2c + 24);
    __syncthreads();                                           // B6
    ph2(0);
    __syncthreads();                                           // B7
    *(short8*)&Ws[w2r * 64 + SWZ(w2r, w2c)] = q0;
    *(short8*)&Ws[w2r * 64 + SWZ(w2r, w2c + 8)] = q1;
    *(short8*)&Ws[w2r * 64 + SWZ(w2r, w2c + 16)] = q2;
    *(short8*)&Ws[w2r * 64 + SWZ(w2r, w2c + 24)] = q3;
    if (hc < 7) {   // next-hc W1 st0 loads hide under phase-2 st1
      w1a = *(const short8*)(W1 + (size_t)((hc + 1) * 128 + w1r) * 256 + w1c);
      w1b = *(const short8*)(W1 + (size_t)((hc + 1) * 128 + w1r) * 256 + w1c + 8);
    }
    __syncthreads();                                           // B8
    ph2(1);
    __syncthreads();                                           // B9 (Ws+Hs free)
  }

  // ---- epilogue: yslot = gate * (Y + b2) ----
#pragma unroll
  for (int mi = 0; mi < 2; ++mi)
#pragma unroll
    for (int r = 0; r < 4; ++r) {
      int grow = row0 + wm * 32 + mi * 16 + (lane >> 4) * 4 + r;
      if (grow < Meff) {
        int tk = gidx[grow];
        float gt = gates[(size_t)tk * 6 + e];
#pragma unroll
        for (int nj = 0; nj < 4; ++nj) {
          int gcol = wn * 64 + nj * 16 + rsel;
          yslot[(size_t)(hbase + grow) * 256 + gcol] = gt * (acc2[mi][nj][r] + B2[gcol]);
        }
      }
    }
}

// ---------------------------------------------------------------------------
// im2col + split: x[B,3,224,224] f32 -> A_patch hi/lo [T,768]
// ---------------------------------------------------------------------------
__global__ void im2col_split(const float* __restrict__ x,
                             u16* __restrict__ Aph, u16* __restrict__ Apl) {
  int id = blockIdx.x * 256 + threadIdx.x;          // T*192 items of 4 elems
  if (id >= T_TOK * 192) return;
  int t = id / 192, kk = id - t * 192;
  int k4 = kk * 4;
  int c = k4 >> 8, rem = k4 & 255, p = rem >> 4, q = rem & 15;
  int b = t / 196, n = t - b * 196, gh = n / 14, gw = n - gh * 14;
  const float4 v = *(const float4*)(x + ((size_t)(b * 3 + c) * 224 + gh * 16 + p) * 224 + gw * 16 + q);
  u16 h0, l0, h1, l1, h2, l2, h3, l3;
  fsplit(v.x, h0, l0); fsplit(v.y, h1, l1); fsplit(v.z, h2, l2); fsplit(v.w, h3, l3);
  *(ushort4*)(Aph + (size_t)t * 768 + k4) = make_ushort4(h0, h1, h2, h3);
  *(ushort4*)(Apl + (size_t)t * 768 + k4) = make_ushort4(l0, l1, l2, l3);
}

// ---------------------------------------------------------------------------
// LayerNorm over E=256: wave per token; bf16 out
// ---------------------------------------------------------------------------
__global__ __launch_bounds__(256) void ln_kernel(const float* __restrict__ in,
    const float* __restrict__ g, const float* __restrict__ b, u16* __restrict__ oh)
{
  const int lane = threadIdx.x & 63;
  const int t = blockIdx.x * 4 + (threadIdx.x >> 6);
  const float4 v = *(const float4*)(in + (size_t)t * 256 + lane * 4);
  float s = v.x + v.y + v.z + v.w;
  float sq = v.x * v.x + v.y * v.y + v.z * v.z + v.w * v.w;
#pragma unroll
  for (int o = 32; o >= 1; o >>= 1) {
    s  += __shfl_xor(s,  o, 64);
    sq += __shfl_xor(sq, o, 64);
  }
  float mu = s * (1.f / 256.f);
  float var = sq * (1.f / 256.f) - mu * mu;
  float rstd = rsqrtf(var + 1e-5f);
  const float4 gv = *(const float4*)(g + lane * 4);
  const float4 bv = *(const float4*)(b + lane * 4);
  *(ushort4*)(oh + (size_t)t * 256 + lane * 4) = make_ushort4(
      bfbits((v.x - mu) * rstd * gv.x + bv.x), bfbits((v.y - mu) * rstd * gv.y + bv.y),
      bfbits((v.z - mu) * rstd * gv.z + bv.z), bfbits((v.w - mu) * rstd * gv.w + bv.w));
}

// ---------------------------------------------------------------------------
// Fused slot-combine + LayerNorm: moe[t] = yslot[s0]+yslot[s1]; x2 = LN(moe)
// ---------------------------------------------------------------------------
__global__ __launch_bounds__(256) void ln2_combine(const float* __restrict__ yslot,
    const int* __restrict__ invslot,
    const float* __restrict__ g, const float* __restrict__ b, float* __restrict__ outf)
{
  const int lane = threadIdx.x & 63;
  const int t = blockIdx.x * 4 + (threadIdx.x >> 6);
  const int s0 = invslot[t * 2], s1 = invslot[t * 2 + 1];
  const float4 a = *(const float4*)(yslot + (size_t)s0 * 256 + lane * 4);
  const float4 c = *(const float4*)(yslot + (size_t)s1 * 256 + lane * 4);
  float4 v = make_float4(a.x + c.x, a.y + c.y, a.z + c.z, a.w + c.w);
  float s = v.x + v.y + v.z + v.w;
  float sq = v.x * v.x + v.y * v.y + v.z * v.z + v.w * v.w;
#pragma unroll
  for (int o = 32; o >= 1; o >>= 1) {
    s  += __shfl_xor(s,  o, 64);
    sq += __shfl_xor(sq, o, 64);
  }
  float mu = s * (1.f / 256.f);
  float var = sq * (1.f / 256.f) - mu * mu;
  float rstd = rsqrtf(var + 1e-5f);
  const float4 gv = *(const float4*)(g + lane * 4);
  const float4 bv = *(const float4*)(b + lane * 4);
  *(float4*)(outf + (size_t)t * 256 + lane * 4) = make_float4(
      (v.x - mu) * rstd * gv.x + bv.x, (v.y - mu) * rstd * gv.y + bv.y,
      (v.z - mu) * rstd * gv.z + bv.z, (v.w - mu) * rstd * gv.w + bv.w);
}

// ---------------------------------------------------------------------------
// MFMA attention: one block per (b,h), 4 waves, 13 m-tiles of 16 q-rows.
// ao written split (hi+lo): feeds wo -> x1f -> router (gate precision).
// ---------------------------------------------------------------------------
__global__ __launch_bounds__(256) void attn_mfma(const u16* __restrict__ qkvb,
                                                 u16* __restrict__ aoh, u16* __restrict__ aol) {
  __shared__ u16 Qs[208][40];
  __shared__ u16 Ks[208][40];
  __shared__ u16 Vt[32][256];
  __shared__ u16 Ps[4][16][232];
  const int tid = threadIdx.x, lane = tid & 63, wave = tid >> 6;
  const int b = blockIdx.x >> 3, h = blockIdx.x & 7;
  const size_t base = (size_t)b * 196 * 768 + h * 32;
  const short8 z8 = {0, 0, 0, 0, 0, 0, 0, 0};

  for (int idx = tid; idx < 832; idx += 256) {
    int r = idx >> 2, c = (idx & 3) * 8;
    short8 q = z8, k = z8;
    if (r < 196) {
      q = *(const short8*)(qkvb + base + (size_t)r * 768 + c);
      k = *(const short8*)(qkvb + base + (size_t)r * 768 + 256 + c);
    }
    *(short8*)&Qs[r][c] = q;
    *(short8*)&Ks[r][c] = k;
  }
  for (int idx = tid; idx < 32 * 224; idx += 256) {
    int c = idx & 31, k = idx >> 5;
    u16 v = 0;
    if (k < 196) v = qkvb[base + (size_t)k * 768 + 512 + c];
    Vt[c][k ^ ((c & 7) << 3)] = v;
  }
  {
    int r = lane >> 2, c0 = 208 + (lane & 3) * 4;
    Ps[wave][r][c0] = 0; Ps[wave][r][c0 + 1] = 0; Ps[wave][r][c0 + 2] = 0; Ps[wave][r][c0 + 3] = 0;
  }
  __syncthreads();

  const int rsel = lane & 15, ksel = (lane >> 4) * 8;
  const f32x4 zero = {0.f, 0.f, 0.f, 0.f};

  for (int mt = wave; mt < 13; mt += 4) {
    short8 aq = *(const short8*)&Qs[mt * 16 + rsel][ksel];
    f32x4 sacc[13];
#pragma unroll
    for (int n = 0; n < 13; ++n)
      sacc[n] = __builtin_amdgcn_mfma_f32_16x16x32_bf16(
          aq, *(const short8*)&Ks[n * 16 + rsel][ksel], zero, 0, 0, 0);

#pragma unroll
    for (int r = 0; r < 4; ++r) {
      float mv = -1e30f;
#pragma unroll
      for (int n = 0; n < 13; ++n) {
        float sv = sacc[n][r] * 0.17677669529663687f;
        sacc[n][r] = sv;
        if (n * 16 + rsel < 196) mv = fmaxf(mv, sv);
      }
      mv = fmaxf(mv, __shfl_xor(mv, 1, 64));
      mv = fmaxf(mv, __shfl_xor(mv, 2, 64));
      mv = fmaxf(mv, __shfl_xor(mv, 4, 64));
      mv = fmaxf(mv, __shfl_xor(mv, 8, 64));
      float sm = 0.f;
#pragma unroll
      for (int n = 0; n < 13; ++n) {
        float p = (n * 16 + rsel < 196) ? __expf(sacc[n][r] - mv) : 0.f;
        sacc[n][r] = p;
        sm += p;
      }
      sm += __shfl_xor(sm, 1, 64);
      sm += __shfl_xor(sm, 2, 64);
      sm += __shfl_xor(sm, 4, 64);
      sm += __shfl_xor(sm, 8, 64);
      float inv = 1.f / sm;
      int prow = (lane >> 4) * 4 + r;
#pragma unroll
      for (int n = 0; n < 13; ++n)
        Ps[wave][prow][n * 16 + rsel] = bfbits(sacc[n][r] * inv);
    }

    f32x4 oacc[2] = {zero, zero};
#pragma unroll
    for (int kk = 0; kk < 7; ++kk) {
      short8 ap = *(const short8*)&Ps[wave][rsel][kk * 32 + ksel];
#pragma unroll
      for (int nt = 0; nt < 2; ++nt) {
        int d = nt * 16 + rsel;
        short8 bv = *(const short8*)&Vt[d][(kk * 32 + ksel) ^ ((d & 7) << 3)];
        oacc[nt] = __builtin_amdgcn_mfma_f32_16x16x32_bf16(ap, bv, oacc[nt], 0, 0, 0);
      }
    }
#pragma unroll
    for (int nt = 0; nt < 2; ++nt) {
#pragma unroll
      for (int r = 0; r < 4; ++r) {
        int row = mt * 16 + (lane >> 4) * 4 + r;
        if (row < 196) {
          size_t oi = ((size_t)b * 196 + row) * 256 + h * 32 + nt * 16 + rsel;
          u16 hh, ll; fsplit(oacc[nt][r], hh, ll);
          aoh[oi] = hh; aol[oi] = ll;
        }
      }
    }
  }
}

// ---------------------------------------------------------------------------
// Router: wave per token; 6 logits, softmax, top-2 -> dense gates [T,6]
// ---------------------------------------------------------------------------
__global__ __launch_bounds__(256) void router_kernel(const float* __restrict__ x1,
    const float* __restrict__ rw, const float* __restrict__ rb, float* __restrict__ gates)
{
  const int lane = threadIdx.x & 63;
  const int t = blockIdx.x * 4 + (threadIdx.x >> 6);
  const float4 xv = *(const float4*)(x1 + (size_t)t * 256 + lane * 4);
  float logit[6];
#pragma unroll
  for (int e = 0; e < 6; ++e) {
    const float4 wv = *(const float4*)(rw + e * 256 + lane * 4);
    float p = xv.x * wv.x + xv.y * wv.y + xv.z * wv.z + xv.w * wv.w;
#pragma unroll
    for (int o = 32; o >= 1; o >>= 1) p += __shfl_xor(p, o, 64);
    logit[e] = p + rb[e];
  }
  float mx = logit[0];
#pragma unroll
  for (int e = 1; e < 6; ++e) mx = fmaxf(mx, logit[e]);
  float pe[6], sum = 0.f;
#pragma unroll
  for (int e = 0; e < 6; ++e) { pe[e] = __expf(logit[e] - mx); sum += pe[e]; }
  float inv = 1.f / sum;
  int i1 = 0; float p1 = pe[0];
#pragma unroll
  for (int e = 1; e < 6; ++e) if (pe[e] > p1) { p1 = pe[e]; i1 = e; }
  int i2 = -1; float p2 = -1.f;
#pragma unroll
  for (int e = 0; e < 6; ++e) if (e != i1 && pe[e] > p2) { p2 = pe[e]; i2 = e; }
  if (lane < 6)
    gates[(size_t)t * 6 + lane] = (lane == i1) ? p1 * inv : ((lane == i2) ? p2 * inv : 0.f);
}

// ---------------------------------------------------------------------------
// Scatter: build per-expert token lists (block-aggregated atomics)
// ---------------------------------------------------------------------------
__global__ __launch_bounds__(256) void scatter_kernel(const float* __restrict__ gates,
                                                      int* __restrict__ cnt, int* __restrict__ idx) {
  __shared__ int lcnt[6], lbase[6];
  const int t = blockIdx.x * 256 + threadIdx.x;
  if (threadIdx.x < 6) lcnt[threadIdx.x] = 0;
  __syncthreads();
  float g[6]; int lpos[6];
#pragma unroll
  for (int e = 0; e < 6; ++e) {
    g[e] = gates[(size_t)t * 6 + e];
    if (g[e] > 0.f) lpos[e] = atomicAdd(&lcnt[e], 1);
  }
  __syncthreads();
  if (threadIdx.x < 6) lbase[threadIdx.x] = atomicAdd(&cnt[threadIdx.x], lcnt[threadIdx.x]);
  __syncthreads();
#pragma unroll
  for (int e = 0; e < 6; ++e)
    if (g[e] > 0.f) idx[(size_t)e * T_TOK + lbase[e] + lpos[e]] = t;
}

// exclusive prefix over the 6 expert counts -> segment bases in slot buffer
__global__ void prefix6_kernel(const int* __restrict__ cnt, int* __restrict__ base) {
  if (threadIdx.x == 0) {
    int s = 0;
#pragma unroll
    for (int e = 0; e < 6; ++e) { base[e] = s; s += cnt[e]; }
  }
}

// token -> its 2 slot positions in the concatenated expert segments
__global__ __launch_bounds__(256) void slotmap_kernel(const int* __restrict__ idx,
    const int* __restrict__ cnt, const int* __restrict__ base,
    int* __restrict__ nslot, int* __restrict__ invslot) {
  const int e = blockIdx.y;
  const int p = blockIdx.x * 256 + threadIdx.x;
  if (p < cnt[e]) {
    int t = idx[(size_t)e * T_TOK + p];
    int j = atomicAdd(&nslot[t], 1);
    invslot[(size_t)t * 2 + j] = base[e] + p;
  }
}

// ---------------------------------------------------------------------------
// Mean-pool over tokens, then classifier head (fp32)
// ---------------------------------------------------------------------------
__global__ __launch_bounds__(256) void pool_kernel(const float* __restrict__ x2, float* __restrict__ pooled) {
  int b = blockIdx.x, e = threadIdx.x;
  float s = 0.f;
  for (int n = 0; n < 196; ++n) s += x2[((size_t)b * 196 + n) * 256 + e];
  pooled[(size_t)b * 256 + e] = s * (1.f / 196.f);
}

__global__ __launch_bounds__(256) void head_kernel(const float* __restrict__ pooled,
    const float* __restrict__ hw, const float* __restrict__ hb, float* __restrict__ out) {
  __shared__ float p[256];
  int b = blockIdx.x;
  p[threadIdx.x] = pooled[(size_t)b * 256 + threadIdx.x];
  __syncthreads();
  for (int cls = threadIdx.x; cls < 1000; cls += 256) {
    const float* w = hw + (size_t)cls * 256;
    float s = hb[cls];
    for (int k = 0; k < 256; k += 4)
      s += p[k] * w[k] + p[k + 1] * w[k + 1] + p[k + 2] * w[k + 2] + p[k + 3] * w[k + 3];
    out[(size_t)b * 1000 + cls] = s;
  }
}

// ---------------------------------------------------------------------------
// Weight prep: f32 -> hi/lo bf16 split; transpose+cast (hi-only) for MoE
// ---------------------------------------------------------------------------
__global__ void cast_split_kernel(const float* __restrict__ in,
                                  u16* __restrict__ oh, u16* __restrict__ ol, int n4) {
  int id = blockIdx.x * 256 + threadIdx.x;
  if (id >= n4) return;
  float4 v = ((const float4*)in)[id];
  u16 h0, l0, h1, l1, h2, l2, h3, l3;
  fsplit(v.x, h0, l0); fsplit(v.y, h1, l1); fsplit(v.z, h2, l2); fsplit(v.w, h3, l3);
  ((ushort4*)oh)[id] = make_ushort4(h0, h1, h2, h3);
  ((ushort4*)ol)[id] = make_ushort4(l0, l1, l2, l3);
}

__global__ __launch_bounds__(256) void transpose_cast(const float* __restrict__ in,
    u16* __restrict__ oh, int R, int C) {
  __shared__ float tile[32][33];
  const int e = blockIdx.z;
  const int bc = blockIdx.x * 32, br = blockIdx.y * 32;
  const int tx = threadIdx.x & 31, ty = threadIdx.x >> 5;
  const float* src = in + (size_t)e * R * C;
#pragma unroll
  for (int i = 0; i < 32; i += 8)
    tile[ty + i][tx] = src[(size_t)(br + ty + i) * C + bc + tx];
  __syncthreads();
#pragma unroll
  for (int i = 0; i < 32; i += 8) {
    size_t di = (size_t)e * R * C + (size_t)(bc + ty + i) * R + br + tx;
    oh[di] = bfbits(tile[tx][ty + i]);
  }
}

// ---------------------------------------------------------------------------
extern "C" void kernel_launch(void* const* d_in, const int* in_sizes, int n_in,
                              void* d_out, int out_size, void* d_ws, size_t ws_size,
                              hipStream_t stream) {
  (void)in_sizes; (void)n_in; (void)out_size; (void)ws_size;
  const float* x      = (const float*)d_in[0];
  const float* conv_w = (const float*)d_in[1];
  const float* conv_b = (const float*)d_in[2];
  const float* pos    = (const float*)d_in[3];
  const float* ln1_g  = (const float*)d_in[4];
  const float* ln1_b  = (const float*)d_in[5];
  const float* wqkv   = (const float*)d_in[6];
  const float* bqkv   = (const float*)d_in[7];
  const float* wo     = (const float*)d_in[8];
  const float* bo     = (const float*)d_in[9];
  const float* rw     = (const float*)d_in[10];
  const float* rb     = (const float*)d_in[11];
  const float* w1     = (const float*)d_in[12];
  const float* b1     = (const float*)d_in[13];
  const float* w2     = (const float*)d_in[14];
  const float* b2     = (const float*)d_in[15];
  const float* ln2_g  = (const float*)d_in[16];
  const float* ln2_b  = (const float*)d_in[17];
  const float* hw     = (const float*)d_in[18];
  const float* hb     = (const float*)d_in[19];
  float* out = (float*)d_out;

  const int T = T_TOK;
  char* ws = (char*)d_ws;
  size_t off = 0;
  auto alloc = [&](size_t bytes) -> void* {
    void* p = ws + off;
    off += (bytes + 255) & ~(size_t)255;
    return p;
  };
  // region 0: Aph+Apl+tok+xnh+qkvb -> reused as x2 after qkv consumed
  u16*   Aph    = (u16*)  alloc((size_t)T * 768 * 2);
  u16*   Apl    = (u16*)  alloc((size_t)T * 768 * 2);
  float* tok    = (float*)alloc((size_t)T * 256 * 4);
  u16*   xnh    = (u16*)  alloc((size_t)T * 256 * 2);
  u16*   qkvb   = (u16*)  alloc((size_t)T * 768 * 2);
  // region 1: aoh+aol+x1f == exactly [2T,256] f32 -> reused as yslot
  u16*   aoh    = (u16*)  alloc((size_t)T * 256 * 2);
  u16*   aol    = (u16*)  alloc((size_t)T * 256 * 2);
  float* x1f    = (float*)alloc((size_t)T * 256 * 4);
  u16*   x1h    = (u16*)  alloc((size_t)T * 256 * 2);
  float* gates  = (float*)alloc((size_t)T * 6 * 4);
  int*   idx    = (int*)  alloc((size_t)6 * T * 4);
  int*   cnt    = (int*)  alloc(256);
  int*   base   = (int*)  alloc(256);
  int*   nslot  = (int*)  alloc((size_t)T * 4);
  int*   invslot= (int*)  alloc((size_t)2 * T * 4);
  float* pooled = (float*)alloc((size_t)128 * 256 * 4);
  u16*   cwh    = (u16*)  alloc((size_t)196608 * 2);
  u16*   cwl    = (u16*)  alloc((size_t)196608 * 2);
  u16*   wqh    = (u16*)  alloc((size_t)196608 * 2);
  u16*   wql    = (u16*)  alloc((size_t)196608 * 2);
  u16*   woh    = (u16*)  alloc((size_t)65536 * 2);
  u16*   wol    = (u16*)  alloc((size_t)65536 * 2);
  u16*   w1th   = (u16*)  alloc((size_t)6 * 262144 * 2);
  u16*   w2th   = (u16*)  alloc((size_t)6 * 262144 * 2);
  // aliases (lifetimes disjoint):
  float* yslot = (float*)aoh;   // [2T,256] f32 (region 1; exact fit)
  float* x2    = (float*)ws;    // [T,256] f32 (region 0; inputs dead by then)

  // --- weight prep (router-path weights hi+lo; MoE weights hi-only) ---
  cast_split_kernel<<<192, 256, 0, stream>>>(conv_w, cwh, cwl, 49152);
  cast_split_kernel<<<192, 256, 0, stream>>>(wqkv, wqh, wql, 49152);
  cast_split_kernel<<<64, 256, 0, stream>>>(wo, woh, wol, 16384);
  transpose_cast<<<dim3(32, 8, 6), 256, 0, stream>>>(w1, w1th, 256, 1024);  // [e][n][k]
  transpose_cast<<<dim3(8, 32, 6), 256, 0, stream>>>(w2, w2th, 1024, 256);  // [e][n][k]

  // --- patch embedding (split A: router-input path) ---
  im2col_split<<<18816, 256, 0, stream>>>(x, Aph, Apl);
  gemm_bs<1, true><<<dim3(196, 2), 256, 0, stream>>>(Aph, Apl, cwh, cwl, T, 256, 768,
      conv_b, pos, tok, nullptr);

  // --- attention block ---
  ln_kernel<<<6272, 256, 0, stream>>>(tok, ln1_g, ln1_b, xnh);
  gemm_bs<5, false><<<dim3(196, 6), 256, 0, stream>>>(xnh, nullptr, wqh, wql, T, 768, 256,
      bqkv, nullptr, nullptr, qkvb);
  attn_mfma<<<1024, 256, 0, stream>>>(qkvb, aoh, aol);
  gemm_bs<2, true><<<dim3(196, 2), 256, 0, stream>>>(aoh, aol, woh, wol, T, 256, 256,
      bo, tok, x1f, x1h);

  // --- MoE (top-2 sparse, fused GEMM1+gelu+GEMM2, 2 blocks/CU) ---
  router_kernel<<<6272, 256, 0, stream>>>(x1f, rw, rb, gates);
  hipMemsetAsync(cnt, 0, 256, stream);
  scatter_kernel<<<98, 256, 0, stream>>>(gates, cnt, idx);
  prefix6_kernel<<<1, 64, 0, stream>>>(cnt, base);
  hipMemsetAsync(nslot, 0, (size_t)T * 4, stream);
  slotmap_kernel<<<dim3(98, 6), 256, 0, stream>>>(idx, cnt, base, nslot, invslot);
  moe_fused<<<dim3(392, 1, 6), 512, 0, stream>>>(x1h, w1th, w2th,
      b1, b2, gates, idx, cnt, base, yslot);

  // --- final norm (fused slot combine), pool, head ---
  ln2_combine<<<6272, 256, 0, stream>>>(yslot, invslot, ln2_g, ln2_b, x2);
  pool_kernel<<<128, 256, 0, stream>>>(x2, pooled);
  head_kernel<<<128, 256, 0, stream>>>(pooled, hw, hb, out);
}